// Round 6
// baseline (3228.865 us; speedup 1.0000x reference)
//
#include <hip/hip_runtime.h>
#include <hip/hip_bf16.h>
#include <math.h>

typedef short s16x8 __attribute__((ext_vector_type(8)));
typedef float f32x4 __attribute__((ext_vector_type(4)));
typedef __hip_bfloat16 bf16;

#define NTOK 4096
#define S_LEN 2048
#define HID_C 1024
#define E_C 8
#define INTER_C 2816
#define WIN_C 64
#define CAP 4096
#define NQKV 1536
#define OUT0_N ((size_t)NTOK*HID_C)

static __device__ __forceinline__ float b2f(bf16 v){ return __bfloat162float(v); }
static __device__ __forceinline__ bf16  f2b(float v){ return __float2bfloat16(v); }
static __device__ __forceinline__ short f2bs(float v){ bf16 h = __float2bfloat16(v); return *reinterpret_cast<short*>(&h); }
struct SplitBF { short hi; short lo; };
static __device__ __forceinline__ SplitBF splitf(float x){
    SplitBF r;
    bf16 bh = __float2bfloat16(x);
    r.hi = *reinterpret_cast<short*>(&bh);
    float rem = x - __bfloat162float(bh);
    bf16 bl = __float2bfloat16(rem);
    r.lo = *reinterpret_cast<short*>(&bl);
    return r;
}

// ================= PREPASS: transposes =================
// src f32 [1024][N] -> dst hi/lo bf16 [row_off+N][1024]
__global__ __launch_bounds__(256) void tsplit_k(const float* __restrict__ src,
                                                short* __restrict__ dhi, short* __restrict__ dlo,
                                                int N, int row_off){
    __shared__ float tile[32][33];
    const int n0 = blockIdx.x*32, k0 = blockIdx.y*32;
    const int tx = threadIdx.x & 31, ty = threadIdx.x >> 5;   // ty 0..7
    #pragma unroll
    for (int i = 0; i < 4; ++i)
        tile[ty + i*8][tx] = src[(size_t)(k0 + ty + i*8)*N + n0 + tx];
    __syncthreads();
    #pragma unroll
    for (int i = 0; i < 4; ++i){
        int nn = ty + i*8;
        SplitBF s = splitf(tile[tx][nn]);
        size_t d = (size_t)(row_off + n0 + nn)*1024 + k0 + tx;
        dhi[d] = s.hi; dlo[d] = s.lo;
    }
}

// src f32 [e][K][N] -> dst bf16 [e][N][K]
__global__ __launch_bounds__(256) void tbf16_k(const float* __restrict__ src0,
                                               short* __restrict__ dst0, int K, int N){
    const int e = blockIdx.z;
    const float* src = src0 + (size_t)e*K*N;
    short* dst = dst0 + (size_t)e*N*K;
    __shared__ float tile[32][33];
    const int n0 = blockIdx.x*32, k0 = blockIdx.y*32;
    const int tx = threadIdx.x & 31, ty = threadIdx.x >> 5;
    #pragma unroll
    for (int i = 0; i < 4; ++i)
        tile[ty + i*8][tx] = src[(size_t)(k0 + ty + i*8)*N + n0 + tx];
    __syncthreads();
    #pragma unroll
    for (int i = 0; i < 4; ++i){
        int nn = ty + i*8;
        dst[(size_t)(n0 + nn)*K + k0 + tx] = f2bs(tile[tx][nn]);
    }
}

// ================= RMSNorm variants =================
// norm1: f32 in -> split hi/lo bf16 out
__global__ __launch_bounds__(256) void rmsn1_k(const float* __restrict__ xin,
                                               const float* __restrict__ w,
                                               short* __restrict__ oh, short* __restrict__ ol){
    const int t = blockIdx.x, tid = threadIdx.x;
    float4 v = *(const float4*)(xin + (size_t)t*HID_C + tid*4);
    float x[4] = {v.x, v.y, v.z, v.w};
    float s = x[0]*x[0]+x[1]*x[1]+x[2]*x[2]+x[3]*x[3];
    #pragma unroll
    for (int off=32; off; off>>=1) s += __shfl_xor(s, off);
    __shared__ float red[4];
    if ((tid&63)==0) red[tid>>6] = s;
    __syncthreads();
    float tot = red[0]+red[1]+red[2]+red[3];
    float sc = rsqrtf(tot*(1.0f/HID_C) + 1e-8f);
    float4 wv = *(const float4*)(w + tid*4);
    float o[4] = { x[0]*sc*wv.x, x[1]*sc*wv.y, x[2]*sc*wv.z, x[3]*sc*wv.w };
    __align__(8) short th[4], tl[4];
    #pragma unroll
    for (int i=0;i<4;++i){ SplitBF sp = splitf(o[i]); th[i]=sp.hi; tl[i]=sp.lo; }
    *(uint2*)(oh + (size_t)t*HID_C + tid*4) = *(uint2*)th;
    *(uint2*)(ol + (size_t)t*HID_C + tid*4) = *(uint2*)tl;
}

// norm2: f32 in -> f32 out + bf16 out
__global__ __launch_bounds__(256) void rmsn2_k(const float* __restrict__ xin,
                                               const float* __restrict__ w,
                                               float* __restrict__ outf, bf16* __restrict__ outb){
    const int t = blockIdx.x, tid = threadIdx.x;
    float4 v = *(const float4*)(xin + (size_t)t*HID_C + tid*4);
    float x[4] = {v.x, v.y, v.z, v.w};
    float s = x[0]*x[0]+x[1]*x[1]+x[2]*x[2]+x[3]*x[3];
    #pragma unroll
    for (int off=32; off; off>>=1) s += __shfl_xor(s, off);
    __shared__ float red[4];
    if ((tid&63)==0) red[tid>>6] = s;
    __syncthreads();
    float tot = red[0]+red[1]+red[2]+red[3];
    float sc = rsqrtf(tot*(1.0f/HID_C) + 1e-8f);
    float4 wv = *(const float4*)(w + tid*4);
    float o[4] = { x[0]*sc*wv.x, x[1]*sc*wv.y, x[2]*sc*wv.z, x[3]*sc*wv.w };
    *(float4*)(outf + (size_t)t*HID_C + tid*4) = make_float4(o[0],o[1],o[2],o[3]);
    __align__(8) bf16 tmp[4] = { f2b(o[0]), f2b(o[1]), f2b(o[2]), f2b(o[3]) };
    *(uint2*)(outb + (size_t)t*HID_C + tid*4) = *(uint2*)tmp;
}

// ============ split GEMM, all operands pre-split bf16 [.][K] (B transposed), 128x128 BK=32 ============
template<bool RESID>
__global__ __launch_bounds__(256) void sgemm2_k(const short* __restrict__ Ah, const short* __restrict__ Al,
                                                const short* __restrict__ Bh, const short* __restrict__ Bl,
                                                float* __restrict__ C, const float* __restrict__ resid,
                                                int N, int K){
    __shared__ __align__(16) short lAh[128*40];
    __shared__ __align__(16) short lAl[128*40];
    __shared__ __align__(16) short lBh[128*40];
    __shared__ __align__(16) short lBl[128*40];
    const int tid = threadIdx.x;
    const int bm0 = blockIdx.x*128, bn0 = blockIdx.y*128;
    const int l = tid & 63, w = tid >> 6, wr = w >> 1, wc = w & 1;
    f32x4 acc[4][4] = {};
    for (int kt = 0; kt < K/32; ++kt){
        #pragma unroll
        for (int i = 0; i < 2; ++i){
            int u = tid + i*256;
            int r = u >> 2, c8 = (u & 3)*8;
            size_t ga = (size_t)(bm0 + r)*K + kt*32 + c8;
            size_t gb = (size_t)(bn0 + r)*K + kt*32 + c8;
            *(s16x8*)(&lAh[r*40 + c8]) = *(const s16x8*)(Ah + ga);
            *(s16x8*)(&lAl[r*40 + c8]) = *(const s16x8*)(Al + ga);
            *(s16x8*)(&lBh[r*40 + c8]) = *(const s16x8*)(Bh + gb);
            *(s16x8*)(&lBl[r*40 + c8]) = *(const s16x8*)(Bl + gb);
        }
        __syncthreads();
        s16x8 ah[4], al[4], bh[4], bl[4];
        #pragma unroll
        for (int mi = 0; mi < 4; ++mi){
            int r = wr*64 + mi*16 + (l&15);
            ah[mi] = *(const s16x8*)(&lAh[r*40 + (l>>4)*8]);
            al[mi] = *(const s16x8*)(&lAl[r*40 + (l>>4)*8]);
        }
        #pragma unroll
        for (int ni = 0; ni < 4; ++ni){
            int n = wc*64 + ni*16 + (l&15);
            bh[ni] = *(const s16x8*)(&lBh[n*40 + (l>>4)*8]);
            bl[ni] = *(const s16x8*)(&lBl[n*40 + (l>>4)*8]);
        }
        #pragma unroll
        for (int mi = 0; mi < 4; ++mi)
            #pragma unroll
            for (int ni = 0; ni < 4; ++ni){
                acc[mi][ni] = __builtin_amdgcn_mfma_f32_16x16x32_bf16(ah[mi], bh[ni], acc[mi][ni], 0,0,0);
                acc[mi][ni] = __builtin_amdgcn_mfma_f32_16x16x32_bf16(ah[mi], bl[ni], acc[mi][ni], 0,0,0);
                acc[mi][ni] = __builtin_amdgcn_mfma_f32_16x16x32_bf16(al[mi], bh[ni], acc[mi][ni], 0,0,0);
            }
        __syncthreads();
    }
    #pragma unroll
    for (int mi = 0; mi < 4; ++mi)
        #pragma unroll
        for (int ni = 0; ni < 4; ++ni)
            #pragma unroll
            for (int rr = 0; rr < 4; ++rr){
                int row = bm0 + wr*64 + mi*16 + (l>>4)*4 + rr;
                int col = bn0 + wc*64 + ni*16 + (l&15);
                float vv = acc[mi][ni][rr];
                if (RESID) vv += resid[(size_t)row*N + col];
                C[(size_t)row*N + col] = vv;
            }
}

// ================ RoPE on packed qkv f32 [tok][1536] ================
__global__ __launch_bounds__(256) void rope2_k(float* __restrict__ qkv,
                                               const float* __restrict__ cosb, const float* __restrict__ sinb){
    int idx = blockIdx.x*256 + threadIdx.x;      // 4096*640
    int t = idx / 640;
    int r = idx - t*640;
    int hs = r >> 5, tp = r & 31;
    int s = t & (S_LEN-1);
    float c  = cosb[s*32+tp];
    float sn = sinb[s*32+tp];
    float* base;
    if (hs < 16) base = qkv + (size_t)t*NQKV + hs*64 + 2*tp;
    else         base = qkv + (size_t)t*NQKV + 1024 + (hs-16)*64 + 2*tp;
    float2 v = *(float2*)base;
    *(float2*)base = make_float2(v.x*c - v.y*sn, v.x*sn + v.y*c);
}

// ======== sliding-window GQA attn on packed qkv, split hi/lo output ========
__global__ __launch_bounds__(64) void attn2_k(const float* __restrict__ qkv,
                                              short* __restrict__ oh, short* __restrict__ ol){
    const int l = threadIdx.x;
    const int bs = blockIdx.x;
    const int h = blockIdx.y, hk = h >> 2;
    const int sq = bs & (S_LEN-1);
    __shared__ float qs[64];
    __shared__ float ps[65];
    qs[l] = qkv[(size_t)bs*NQKV + h*64 + l];
    __syncthreads();
    const int j0 = (sq - WIN_C) > 0 ? (sq - WIN_C) : 0;
    const int nk = sq - j0 + 1;
    const int tokbase = bs - sq;
    float sc[2] = {-1e9f, -1e9f};
    #pragma unroll
    for (int it = 0; it < 2; ++it){
        int jj = l + it*64;
        if (jj < nk){
            const float* kp = qkv + (size_t)(tokbase + j0 + jj)*NQKV + 1024 + hk*64;
            float d = 0.f;
            #pragma unroll
            for (int c = 0; c < 16; ++c){
                float4 kv = *(const float4*)(kp + c*4);
                d += qs[c*4+0]*kv.x + qs[c*4+1]*kv.y + qs[c*4+2]*kv.z + qs[c*4+3]*kv.w;
            }
            sc[it] = d*0.125f;
        }
    }
    float m = fmaxf(sc[0], sc[1]);
    #pragma unroll
    for (int off=32; off; off>>=1) m = fmaxf(m, __shfl_xor(m, off));
    float e0 = (l      < nk) ? __expf(sc[0]-m) : 0.f;
    float e1 = (l + 64 < nk) ? __expf(sc[1]-m) : 0.f;
    float s = e0 + e1;
    #pragma unroll
    for (int off=32; off; off>>=1) s += __shfl_xor(s, off);
    float inv = 1.f/s;
    if (l      < nk) ps[l]    = e0*inv;
    if (l + 64 < nk) ps[l+64] = e1*inv;
    __syncthreads();
    float acc = 0.f;
    for (int jj = 0; jj < nk; ++jj)
        acc += ps[jj]*qkv[(size_t)(tokbase + j0 + jj)*NQKV + 1280 + hk*64 + l];
    SplitBF sp = splitf(acc);
    oh[(size_t)bs*HID_C + h*64 + l] = sp.hi;
    ol[(size_t)bs*HID_C + h*64 + l] = sp.lo;
}

// ================= router (f32) =================
__global__ __launch_bounds__(64) void router_k(const float* __restrict__ h2f, const float* __restrict__ rw,
                                               int* __restrict__ lists, float* __restrict__ wl,
                                               int* __restrict__ cnt, float* __restrict__ psum){
    const int t = blockIdx.x, l = threadIdx.x;
    float lg[8] = {0,0,0,0,0,0,0,0};
    for (int c = 0; c < 16; ++c){
        int kidx = l + c*64;
        float x = h2f[(size_t)t*HID_C + kidx];
        float4 w0 = *(const float4*)(rw + (size_t)kidx*8);
        float4 w1 = *(const float4*)(rw + (size_t)kidx*8 + 4);
        lg[0] += x*w0.x; lg[1] += x*w0.y; lg[2] += x*w0.z; lg[3] += x*w0.w;
        lg[4] += x*w1.x; lg[5] += x*w1.y; lg[6] += x*w1.z; lg[7] += x*w1.w;
    }
    #pragma unroll
    for (int e = 0; e < 8; ++e)
        #pragma unroll
        for (int off=32; off; off>>=1) lg[e] += __shfl_xor(lg[e], off);
    if (l == 0){
        float m = lg[0];
        #pragma unroll
        for (int e = 1; e < 8; ++e) m = fmaxf(m, lg[e]);
        float p[8]; float s = 0.f;
        #pragma unroll
        for (int e = 0; e < 8; ++e){ p[e] = __expf(lg[e]-m); s += p[e]; }
        float invs = 1.f/s;
        #pragma unroll
        for (int e = 0; e < 8; ++e){ p[e] *= invs; atomicAdd(&psum[e], p[e]); }
        float best = -1e30f, sec = -1e30f; int bi = 0, si = 0;
        #pragma unroll
        for (int e = 0; e < 8; ++e){
            float pv = p[e];
            if (pv > best){ sec = best; si = bi; best = pv; bi = e; }
            else if (pv > sec){ sec = pv; si = e; }
        }
        float wsum = best + sec + 1e-9f;
        int s0 = atomicAdd(&cnt[bi], 1);
        lists[bi*CAP + s0] = t; wl[bi*CAP + s0] = best/wsum;
        int s1 = atomicAdd(&cnt[si], 1);
        lists[si*CAP + s1] = t; wl[si*CAP + s1] = sec/wsum;
    }
}

__global__ void finalize_k(const int* __restrict__ cnt, const float* __restrict__ psum,
                           int* __restrict__ offs, float* __restrict__ out){
    if (threadIdx.x == 0 && blockIdx.x == 0){
        int o = 0; float loss = 0.f;
        for (int e = 0; e < 8; ++e){
            offs[e] = o; o += cnt[e];
            loss += (psum[e]*(1.0f/NTOK)) * ((float)cnt[e]*(1.0f/NTOK));
        }
        offs[8] = o;
        out[OUT0_N] = loss * (float)E_C * 0.01f;
    }
}

// ============ MoE gate/up: bf16, pre-transposed weights, 128x128 BK=64 ============
__global__ __launch_bounds__(256) void moe1_k(const bf16* __restrict__ h2b,
                                              const short* __restrict__ gate_t,
                                              const short* __restrict__ up_t,
                                              bf16* __restrict__ inter,
                                              const int* __restrict__ lists,
                                              const int* __restrict__ cnt,
                                              const int* __restrict__ offs){
    const int e = blockIdx.z;
    const int ne = cnt[e];
    const int bm0 = blockIdx.x*128;
    if (bm0 >= ne) return;
    const int bn0 = blockIdx.y*128;
    __shared__ __align__(16) short lA[128*72];
    __shared__ __align__(16) short lG[128*72];
    __shared__ __align__(16) short lU[128*72];
    const int tid = threadIdx.x;
    const int l = tid & 63, w = tid >> 6, wr = w >> 1, wc = w & 1;
    const short* Gb = gate_t + (size_t)e*INTER_C*HID_C;
    const short* Ub = up_t   + (size_t)e*INTER_C*HID_C;
    f32x4 ag[4][4] = {}; f32x4 au[4][4] = {};
    for (int kt = 0; kt < HID_C/64; ++kt){
        #pragma unroll
        for (int i = 0; i < 4; ++i){
            int u = tid + i*256;
            int r = u >> 3, c8 = (u & 7)*8;
            int slot = bm0 + r;
            s16x8 v = {};
            if (slot < ne){
                int tok = lists[e*CAP + slot];
                v = *(const s16x8*)((const short*)h2b + (size_t)tok*HID_C + kt*64 + c8);
            }
            *(s16x8*)(&lA[r*72 + c8]) = v;
        }
        #pragma unroll
        for (int i = 0; i < 4; ++i){
            int u = tid + i*256;
            int n = u >> 3, c8 = (u & 7)*8;
            size_t gi = (size_t)(bn0 + n)*HID_C + kt*64 + c8;
            *(s16x8*)(&lG[n*72 + c8]) = *(const s16x8*)(Gb + gi);
            *(s16x8*)(&lU[n*72 + c8]) = *(const s16x8*)(Ub + gi);
        }
        __syncthreads();
        #pragma unroll
        for (int kk = 0; kk < 64; kk += 32){
            s16x8 af[4], bg[4], bu[4];
            #pragma unroll
            for (int mi = 0; mi < 4; ++mi)
                af[mi] = *(const s16x8*)(&lA[(wr*64 + mi*16 + (l&15))*72 + kk + (l>>4)*8]);
            #pragma unroll
            for (int ni = 0; ni < 4; ++ni){
                int n = wc*64 + ni*16 + (l&15);
                bg[ni] = *(const s16x8*)(&lG[n*72 + kk + (l>>4)*8]);
                bu[ni] = *(const s16x8*)(&lU[n*72 + kk + (l>>4)*8]);
            }
            #pragma unroll
            for (int mi = 0; mi < 4; ++mi)
                #pragma unroll
                for (int ni = 0; ni < 4; ++ni){
                    ag[mi][ni] = __builtin_amdgcn_mfma_f32_16x16x32_bf16(af[mi], bg[ni], ag[mi][ni], 0,0,0);
                    au[mi][ni] = __builtin_amdgcn_mfma_f32_16x16x32_bf16(af[mi], bu[ni], au[mi][ni], 0,0,0);
                }
        }
        __syncthreads();
    }
    const int obase = offs[e];
    #pragma unroll
    for (int mi = 0; mi < 4; ++mi)
        #pragma unroll
        for (int ni = 0; ni < 4; ++ni)
            #pragma unroll
            for (int rr = 0; rr < 4; ++rr){
                int slot = bm0 + wr*64 + mi*16 + (l>>4)*4 + rr;
                if (slot < ne){
                    int col = bn0 + wc*64 + ni*16 + (l&15);
                    float g = ag[mi][ni][rr], uu = au[mi][ni][rr];
                    float val = (g/(1.f+__expf(-g)))*uu;
                    inter[(size_t)(obase+slot)*INTER_C + col] = f2b(val);
                }
            }
}

// ============ MoE down: bf16, pre-transposed weights, 128x128 BK=64, atomic into hres ============
__global__ __launch_bounds__(256) void moe2_k(const bf16* __restrict__ inter,
                                              const short* __restrict__ down_t,
                                              float* __restrict__ hres,
                                              const float* __restrict__ wl,
                                              const int* __restrict__ lists,
                                              const int* __restrict__ cnt,
                                              const int* __restrict__ offs){
    const int e = blockIdx.z;
    const int ne = cnt[e];
    const int bm0 = blockIdx.x*128;
    if (bm0 >= ne) return;
    const int bn0 = blockIdx.y*128;
    __shared__ __align__(16) short lA[128*72];
    __shared__ __align__(16) short lB[128*72];
    const int tid = threadIdx.x;
    const int l = tid & 63, w = tid >> 6, wr = w >> 1, wc = w & 1;
    const int obase = offs[e];
    const short* Db = down_t + (size_t)e*HID_C*INTER_C;
    f32x4 acc[4][4] = {};
    for (int kt = 0; kt < INTER_C/64; ++kt){
        #pragma unroll
        for (int i = 0; i < 4; ++i){
            int u = tid + i*256;
            int r = u >> 3, c8 = (u & 7)*8;
            int slot = bm0 + r;
            s16x8 v = {};
            if (slot < ne)
                v = *(const s16x8*)((const short*)inter + (size_t)(obase + slot)*INTER_C + kt*64 + c8);
            *(s16x8*)(&lA[r*72 + c8]) = v;
        }
        #pragma unroll
        for (int i = 0; i < 4; ++i){
            int u = tid + i*256;
            int n = u >> 3, c8 = (u & 7)*8;
            *(s16x8*)(&lB[n*72 + c8]) = *(const s16x8*)(Db + (size_t)(bn0 + n)*INTER_C + kt*64 + c8);
        }
        __syncthreads();
        #pragma unroll
        for (int kk = 0; kk < 64; kk += 32){
            s16x8 af[4], bfr[4];
            #pragma unroll
            for (int mi = 0; mi < 4; ++mi)
                af[mi] = *(const s16x8*)(&lA[(wr*64 + mi*16 + (l&15))*72 + kk + (l>>4)*8]);
            #pragma unroll
            for (int ni = 0; ni < 4; ++ni){
                int n = wc*64 + ni*16 + (l&15);
                bfr[ni] = *(const s16x8*)(&lB[n*72 + kk + (l>>4)*8]);
            }
            #pragma unroll
            for (int mi = 0; mi < 4; ++mi)
                #pragma unroll
                for (int ni = 0; ni < 4; ++ni)
                    acc[mi][ni] = __builtin_amdgcn_mfma_f32_16x16x32_bf16(af[mi], bfr[ni], acc[mi][ni], 0,0,0);
        }
        __syncthreads();
    }
    #pragma unroll
    for (int mi = 0; mi < 4; ++mi)
        #pragma unroll
        for (int ni = 0; ni < 4; ++ni)
            #pragma unroll
            for (int rr = 0; rr < 4; ++rr){
                int slot = bm0 + wr*64 + mi*16 + (l>>4)*4 + rr;
                if (slot < ne){
                    int col = bn0 + wc*64 + ni*16 + (l&15);
                    int tok = lists[e*CAP + slot];
                    float wgt = wl[e*CAP + slot];
                    atomicAdd(&hres[(size_t)tok*HID_C + col], acc[mi][ni][rr]*wgt);
                }
            }
}

__global__ __launch_bounds__(256) void final_k(const float* __restrict__ hres,
                                               float* __restrict__ out){
    const int t = blockIdx.x, c = threadIdx.x*4;
    float4 hv = *(const float4*)(hres + (size_t)t*HID_C + c);
    *(float4*)(out + (size_t)t*HID_C + c) = hv;
}

// ======================= FALLBACK PATH (round-5, ws-lean) =======================
template<bool ALSO_BF16>
__global__ __launch_bounds__(256) void rmsnorm_f(const float* __restrict__ xin, const float* __restrict__ w,
                                                 float* __restrict__ outf, bf16* __restrict__ outb){
    const int t = blockIdx.x, tid = threadIdx.x;
    float4 v = *(const float4*)(xin + (size_t)t*HID_C + tid*4);
    float x[4] = {v.x, v.y, v.z, v.w};
    float s = x[0]*x[0]+x[1]*x[1]+x[2]*x[2]+x[3]*x[3];
    #pragma unroll
    for (int off=32; off; off>>=1) s += __shfl_xor(s, off);
    __shared__ float red[4];
    if ((tid&63)==0) red[tid>>6] = s;
    __syncthreads();
    float tot = red[0]+red[1]+red[2]+red[3];
    float sc = rsqrtf(tot*(1.0f/HID_C) + 1e-8f);
    float4 wv = *(const float4*)(w + tid*4);
    float o[4] = { x[0]*sc*wv.x, x[1]*sc*wv.y, x[2]*sc*wv.z, x[3]*sc*wv.w };
    *(float4*)(outf + (size_t)t*HID_C + tid*4) = make_float4(o[0],o[1],o[2],o[3]);
    if (ALSO_BF16){
        __align__(8) bf16 tmp[4] = { f2b(o[0]), f2b(o[1]), f2b(o[2]), f2b(o[3]) };
        *(uint2*)(outb + (size_t)t*HID_C + tid*4) = *(uint2*)tmp;
    }
}

template<bool RESID>
__global__ __launch_bounds__(256) void sgemm_f(const float* __restrict__ A, const float* __restrict__ B,
                                               float* __restrict__ C, const float* __restrict__ resid,
                                               int N, int K){
    __shared__ __align__(16) short lAh[128*40];
    __shared__ __align__(16) short lAl[128*40];
    __shared__ __align__(16) short lBh[128*40];
    __shared__ __align__(16) short lBl[128*40];
    const int tid = threadIdx.x;
    const int bm0 = blockIdx.x*128, bn0 = blockIdx.y*128;
    const int l = tid & 63, w = tid >> 6, wr = w >> 1, wc = w & 1;
    f32x4 acc[4][4] = {};
    for (int kt = 0; kt < K/32; ++kt){
        #pragma unroll
        for (int i = 0; i < 4; ++i){
            int u = tid + i*256;
            int r = u >> 3, c4 = (u & 7)*4;
            float4 v = *(const float4*)(A + (size_t)(bm0+r)*K + kt*32 + c4);
            SplitBF s0 = splitf(v.x), s1 = splitf(v.y), s2 = splitf(v.z), s3 = splitf(v.w);
            __align__(8) short hv[4] = { s0.hi, s1.hi, s2.hi, s3.hi };
            __align__(8) short lv[4] = { s0.lo, s1.lo, s2.lo, s3.lo };
            *(uint2*)(&lAh[r*40 + c4]) = *(uint2*)hv;
            *(uint2*)(&lAl[r*40 + c4]) = *(uint2*)lv;
        }
        #pragma unroll
        for (int i = 0; i < 4; ++i){
            int u = tid + i*256;
            int k = u >> 5, n0 = (u & 31)*4;
            float4 v = *(const float4*)(B + (size_t)(kt*32 + k)*N + bn0 + n0);
            SplitBF s0 = splitf(v.x), s1 = splitf(v.y), s2 = splitf(v.z), s3 = splitf(v.w);
            lBh[(n0+0)*40+k]=s0.hi; lBh[(n0+1)*40+k]=s1.hi; lBh[(n0+2)*40+k]=s2.hi; lBh[(n0+3)*40+k]=s3.hi;
            lBl[(n0+0)*40+k]=s0.lo; lBl[(n0+1)*40+k]=s1.lo; lBl[(n0+2)*40+k]=s2.lo; lBl[(n0+3)*40+k]=s3.lo;
        }
        __syncthreads();
        s16x8 ah[4], al[4], bh[4], bl[4];
        #pragma unroll
        for (int mi = 0; mi < 4; ++mi){
            int r = wr*64 + mi*16 + (l&15);
            ah[mi] = *(const s16x8*)(&lAh[r*40 + (l>>4)*8]);
            al[mi] = *(const s16x8*)(&lAl[r*40 + (l>>4)*8]);
        }
        #pragma unroll
        for (int ni = 0; ni < 4; ++ni){
            int n = wc*64 + ni*16 + (l&15);
            bh[ni] = *(const s16x8*)(&lBh[n*40 + (l>>4)*8]);
            bl[ni] = *(const s16x8*)(&lBl[n*40 + (l>>4)*8]);
        }
        #pragma unroll
        for (int mi = 0; mi < 4; ++mi)
            #pragma unroll
            for (int ni = 0; ni < 4; ++ni){
                acc[mi][ni] = __builtin_amdgcn_mfma_f32_16x16x32_bf16(ah[mi], bh[ni], acc[mi][ni], 0,0,0);
                acc[mi][ni] = __builtin_amdgcn_mfma_f32_16x16x32_bf16(ah[mi], bl[ni], acc[mi][ni], 0,0,0);
                acc[mi][ni] = __builtin_amdgcn_mfma_f32_16x16x32_bf16(al[mi], bh[ni], acc[mi][ni], 0,0,0);
            }
        __syncthreads();
    }
    #pragma unroll
    for (int mi = 0; mi < 4; ++mi)
        #pragma unroll
        for (int ni = 0; ni < 4; ++ni)
            #pragma unroll
            for (int rr = 0; rr < 4; ++rr){
                int row = bm0 + wr*64 + mi*16 + (l>>4)*4 + rr;
                int col = bn0 + wc*64 + ni*16 + (l&15);
                float vv = acc[mi][ni][rr];
                if (RESID) vv += resid[(size_t)row*N + col];
                C[(size_t)row*N + col] = vv;
            }
}

__global__ __launch_bounds__(256) void rope_f(float* __restrict__ qb, float* __restrict__ kb,
                                              const float* __restrict__ cosb, const float* __restrict__ sinb){
    int idx = blockIdx.x*256 + threadIdx.x;
    int t = idx / 640;
    int r = idx - t*640;
    int hs = r >> 5, tp = r & 31;
    int s = t & (S_LEN-1);
    float c  = cosb[s*32+tp];
    float sn = sinb[s*32+tp];
    float* base;
    if (hs < 16) base = qb + (size_t)t*1024 + hs*64 + 2*tp;
    else         base = kb + (size_t)t*256 + (hs-16)*64 + 2*tp;
    float2 v = *(float2*)base;
    *(float2*)base = make_float2(v.x*c - v.y*sn, v.x*sn + v.y*c);
}

__global__ __launch_bounds__(64) void attn_f(const float* __restrict__ qb, const float* __restrict__ kb,
                                             const float* __restrict__ vb, float* __restrict__ ob){
    const int l = threadIdx.x;
    const int bs = blockIdx.x;
    const int h = blockIdx.y, hk = h >> 2;
    const int sq = bs & (S_LEN-1);
    __shared__ float qs[64];
    __shared__ float ps[65];
    qs[l] = qb[(size_t)bs*1024 + h*64 + l];
    __syncthreads();
    const int j0 = (sq - WIN_C) > 0 ? (sq - WIN_C) : 0;
    const int nk = sq - j0 + 1;
    const int tokbase = bs - sq;
    float sc[2] = {-1e9f, -1e9f};
    #pragma unroll
    for (int it = 0; it < 2; ++it){
        int jj = l + it*64;
        if (jj < nk){
            const float* kp = kb + (size_t)(tokbase + j0 + jj)*256 + hk*64;
            float d = 0.f;
            #pragma unroll
            for (int c = 0; c < 16; ++c){
                float4 kv = *(const float4*)(kp + c*4);
                d += qs[c*4+0]*kv.x + qs[c*4+1]*kv.y + qs[c*4+2]*kv.z + qs[c*4+3]*kv.w;
            }
            sc[it] = d*0.125f;
        }
    }
    float m = fmaxf(sc[0], sc[1]);
    #pragma unroll
    for (int off=32; off; off>>=1) m = fmaxf(m, __shfl_xor(m, off));
    float e0 = (l      < nk) ? __expf(sc[0]-m) : 0.f;
    float e1 = (l + 64 < nk) ? __expf(sc[1]-m) : 0.f;
    float s = e0 + e1;
    #pragma unroll
    for (int off=32; off; off>>=1) s += __shfl_xor(s, off);
    float inv = 1.f/s;
    if (l      < nk) ps[l]    = e0*inv;
    if (l + 64 < nk) ps[l+64] = e1*inv;
    __syncthreads();
    float acc = 0.f;
    for (int jj = 0; jj < nk; ++jj)
        acc += ps[jj]*vb[(size_t)(tokbase + j0 + jj)*256 + hk*64 + l];
    ob[(size_t)bs*1024 + h*64 + l] = acc;
}

__global__ __launch_bounds__(256) void moe_mlp1_f(const bf16* __restrict__ h2b,
                                                  const float* __restrict__ gateW,
                                                  const float* __restrict__ upW,
                                                  bf16* __restrict__ inter,
                                                  const int* __restrict__ lists,
                                                  const int* __restrict__ cnt,
                                                  const int* __restrict__ offs){
    const int e = blockIdx.z;
    const int ne = cnt[e];
    const int bm0 = blockIdx.x*128;
    if (bm0 >= ne) return;
    const int bn0 = blockIdx.y*64;
    __shared__ __align__(16) short lA[128*72];
    __shared__ __align__(16) short lG[64*72];
    __shared__ __align__(16) short lU[64*72];
    const int tid = threadIdx.x;
    const int l = tid & 63, w = tid >> 6, wr = w >> 1, wc = w & 1;
    const size_t ebase = (size_t)e*HID_C*INTER_C;
    f32x4 ag[4][2] = {}; f32x4 au[4][2] = {};
    for (int kt = 0; kt < HID_C/64; ++kt){
        #pragma unroll
        for (int i = 0; i < 4; ++i){
            int u = tid + i*256;
            int r = u >> 3, cu = u & 7;
            int slot = bm0 + r;
            s16x8 v = {};
            if (slot < ne){
                int tok = lists[e*CAP + slot];
                v = *(const s16x8*)((const short*)h2b + (size_t)tok*HID_C + kt*64 + cu*8);
            }
            *(s16x8*)(&lA[r*72 + cu*8]) = v;
        }
        #pragma unroll
        for (int i = 0; i < 2; ++i){
            int u = tid + i*256;
            int k = u >> 3, n0 = (u & 7)*8;
            size_t gidx = ebase + (size_t)(kt*64 + k)*INTER_C + bn0 + n0;
            const float* gp = gateW + gidx;
            const float* up = upW + gidx;
            float4 ga = *(const float4*)gp, gb = *(const float4*)(gp+4);
            float4 ua = *(const float4*)up, ub = *(const float4*)(up+4);
            lG[(n0+0)*72+k]=f2bs(ga.x); lG[(n0+1)*72+k]=f2bs(ga.y); lG[(n0+2)*72+k]=f2bs(ga.z); lG[(n0+3)*72+k]=f2bs(ga.w);
            lG[(n0+4)*72+k]=f2bs(gb.x); lG[(n0+5)*72+k]=f2bs(gb.y); lG[(n0+6)*72+k]=f2bs(gb.z); lG[(n0+7)*72+k]=f2bs(gb.w);
            lU[(n0+0)*72+k]=f2bs(ua.x); lU[(n0+1)*72+k]=f2bs(ua.y); lU[(n0+2)*72+k]=f2bs(ua.z); lU[(n0+3)*72+k]=f2bs(ua.w);
            lU[(n0+4)*72+k]=f2bs(ub.x); lU[(n0+5)*72+k]=f2bs(ub.y); lU[(n0+6)*72+k]=f2bs(ub.z); lU[(n0+7)*72+k]=f2bs(ub.w);
        }
        __syncthreads();
        #pragma unroll
        for (int kk = 0; kk < 64; kk += 32){
            s16x8 af[4], bg[2], bu[2];
            #pragma unroll
            for (int mi = 0; mi < 4; ++mi)
                af[mi] = *(const s16x8*)(&lA[(wr*64 + mi*16 + (l&15))*72 + kk + (l>>4)*8]);
            #pragma unroll
            for (int ni = 0; ni < 2; ++ni){
                int n = wc*32 + ni*16 + (l&15);
                bg[ni] = *(const s16x8*)(&lG[n*72 + kk + (l>>4)*8]);
                bu[ni] = *(const s16x8*)(&lU[n*72 + kk + (l>>4)*8]);
            }
            #pragma unroll
            for (int mi = 0; mi < 4; ++mi)
                #pragma unroll
                for (int ni = 0; ni < 2; ++ni){
                    ag[mi][ni] = __builtin_amdgcn_mfma_f32_16x16x32_bf16(af[mi], bg[ni], ag[mi][ni], 0,0,0);
                    au[mi][ni] = __builtin_amdgcn_mfma_f32_16x16x32_bf16(af[mi], bu[ni], au[mi][ni], 0,0,0);
                }
        }
        __syncthreads();
    }
    const int obase = offs[e];
    #pragma unroll
    for (int mi = 0; mi < 4; ++mi)
        #pragma unroll
        for (int ni = 0; ni < 2; ++ni)
            #pragma unroll
            for (int rr = 0; rr < 4; ++rr){
                int slot = bm0 + wr*64 + mi*16 + (l>>4)*4 + rr;
                if (slot < ne){
                    int col = bn0 + wc*32 + ni*16 + (l&15);
                    float g = ag[mi][ni][rr], uu = au[mi][ni][rr];
                    float val = (g/(1.f+__expf(-g)))*uu;
                    inter[(size_t)(obase+slot)*INTER_C + col] = f2b(val);
                }
            }
}

__global__ __launch_bounds__(256) void moe_mlp2_f(const bf16* __restrict__ inter,
                                                  const float* __restrict__ downW,
                                                  float* __restrict__ hres,
                                                  const float* __restrict__ wl,
                                                  const int* __restrict__ lists,
                                                  const int* __restrict__ cnt,
                                                  const int* __restrict__ offs){
    const int e = blockIdx.z;
    const int ne = cnt[e];
    const int bm0 = blockIdx.x*128;
    if (bm0 >= ne) return;
    const int bn0 = blockIdx.y*128;
    __shared__ __align__(16) short lA[128*72];
    __shared__ __align__(16) short lB[128*72];
    const int tid = threadIdx.x;
    const int l = tid & 63, w = tid >> 6, wr = w >> 1, wc = w & 1;
    const int obase = offs[e];
    const size_t ebase = (size_t)e*INTER_C*HID_C;
    f32x4 acc[4][4] = {};
    for (int kt = 0; kt < INTER_C/64; ++kt){
        #pragma unroll
        for (int i = 0; i < 4; ++i){
            int u = tid + i*256;
            int r = u >> 3, cu = u & 7;
            int slot = bm0 + r;
            s16x8 v = {};
            if (slot < ne)
                v = *(const s16x8*)((const short*)inter + (size_t)(obase + slot)*INTER_C + kt*64 + cu*8);
            *(s16x8*)(&lA[r*72 + cu*8]) = v;
        }
        #pragma unroll
        for (int i = 0; i < 4; ++i){
            int u = tid + i*256;
            int k = u >> 4, n0 = (u & 15)*8;
            const float* bp = downW + ebase + (size_t)(kt*64 + k)*HID_C + bn0 + n0;
            float4 a = *(const float4*)bp, b = *(const float4*)(bp+4);
            lB[(n0+0)*72+k]=f2bs(a.x); lB[(n0+1)*72+k]=f2bs(a.y); lB[(n0+2)*72+k]=f2bs(a.z); lB[(n0+3)*72+k]=f2bs(a.w);
            lB[(n0+4)*72+k]=f2bs(b.x); lB[(n0+5)*72+k]=f2bs(b.y); lB[(n0+6)*72+k]=f2bs(b.z); lB[(n0+7)*72+k]=f2bs(b.w);
        }
        __syncthreads();
        #pragma unroll
        for (int kk = 0; kk < 64; kk += 32){
            s16x8 af[4], bfr[4];
            #pragma unroll
            for (int mi = 0; mi < 4; ++mi)
                af[mi] = *(const s16x8*)(&lA[(wr*64 + mi*16 + (l&15))*72 + kk + (l>>4)*8]);
            #pragma unroll
            for (int ni = 0; ni < 4; ++ni){
                int n = wc*64 + ni*16 + (l&15);
                bfr[ni] = *(const s16x8*)(&lB[n*72 + kk + (l>>4)*8]);
            }
            #pragma unroll
            for (int mi = 0; mi < 4; ++mi)
                #pragma unroll
                for (int ni = 0; ni < 4; ++ni)
                    acc[mi][ni] = __builtin_amdgcn_mfma_f32_16x16x32_bf16(af[mi], bfr[ni], acc[mi][ni], 0,0,0);
        }
        __syncthreads();
    }
    #pragma unroll
    for (int mi = 0; mi < 4; ++mi)
        #pragma unroll
        for (int ni = 0; ni < 4; ++ni)
            #pragma unroll
            for (int rr = 0; rr < 4; ++rr){
                int slot = bm0 + wr*64 + mi*16 + (l>>4)*4 + rr;
                if (slot < ne){
                    int col = bn0 + wc*64 + ni*16 + (l&15);
                    int tok = lists[e*CAP + slot];
                    float wgt = wl[e*CAP + slot];
                    atomicAdd(&hres[(size_t)tok*HID_C + col], acc[mi][ni][rr]*wgt);
                }
            }
}

// ======================= HOST =======================
extern "C" void kernel_launch(void* const* d_in, const int* in_sizes, int n_in,
                              void* d_out, int out_size, void* d_ws, size_t ws_size,
                              hipStream_t stream){
    const float* hidden  = (const float*)d_in[0];
    const float* fcos    = (const float*)d_in[1];
    const float* fsin    = (const float*)d_in[2];
    const float* wq      = (const float*)d_in[3];
    const float* wk      = (const float*)d_in[4];
    const float* wv      = (const float*)d_in[5];
    const float* wo      = (const float*)d_in[6];
    const float* routerw = (const float*)d_in[7];
    const float* gatew   = (const float*)d_in[8];
    const float* upw     = (const float*)d_in[9];
    const float* downw   = (const float*)d_in[10];
    const float* n1w     = (const float*)d_in[11];
    const float* n2w     = (const float*)d_in[12];

    char* p = (char*)d_ws;
    size_t off = 0;
    auto alloc = [&](size_t b)->void*{ void* r = p + off; off = (off + b + 255) & ~(size_t)255; return r; };

    // ---- big-path layout ----
    int*   cnt    = (int*)alloc(64);
    float* psum   = (float*)alloc(64);
    int*   offs   = (int*)alloc(64);
    int*   lists  = (int*)alloc((size_t)E_C*CAP*4);
    float* wl     = (float*)alloc((size_t)E_C*CAP*4);
    short* wqkvh  = (short*)alloc((size_t)NQKV*HID_C*2);
    short* wqkvl  = (short*)alloc((size_t)NQKV*HID_C*2);
    short* woh    = (short*)alloc((size_t)HID_C*HID_C*2);
    short* wol    = (short*)alloc((size_t)HID_C*HID_C*2);
    short* gate_t = (short*)alloc((size_t)E_C*INTER_C*HID_C*2);
    short* up_t   = (short*)alloc((size_t)E_C*INTER_C*HID_C*2);
    short* down_t = (short*)alloc((size_t)E_C*HID_C*INTER_C*2);
    short* h1h    = (short*)alloc((size_t)NTOK*HID_C*2);     // later oh
    short* h1l    = (short*)alloc((size_t)NTOK*HID_C*2);     // later ol
    float* qkvf   = (float*)alloc((size_t)NTOK*NQKV*4);      // later h2f + h2b
    float* hres   = (float*)alloc((size_t)NTOK*HID_C*4);
    bf16*  inter  = (bf16*)alloc((size_t)2*NTOK*INTER_C*2);
    size_t need_big = off;

    if (ws_size >= need_big){
        short* ohB = h1h;
        short* olB = h1l;
        float* h2f = qkvf;                                    // 16.8 MB
        bf16*  h2b = (bf16*)(qkvf + (size_t)NTOK*HID_C);      // next 8.4 MB (within qkvf's 25.2)

        (void)hipMemsetAsync(cnt, 0, 64, stream);
        (void)hipMemsetAsync(psum, 0, 64, stream);

        // prepass transposes
        tsplit_k<<<dim3(32,32), 256, 0, stream>>>(wq, wqkvh, wqkvl, 1024, 0);
        tsplit_k<<<dim3(8,32),  256, 0, stream>>>(wk, wqkvh, wqkvl, 256, 1024);
        tsplit_k<<<dim3(8,32),  256, 0, stream>>>(wv, wqkvh, wqkvl, 256, 1280);
        tsplit_k<<<dim3(32,32), 256, 0, stream>>>(wo, woh, wol, 1024, 0);
        tbf16_k<<<dim3(88,32,8), 256, 0, stream>>>(gatew, gate_t, 1024, 2816);
        tbf16_k<<<dim3(88,32,8), 256, 0, stream>>>(upw,   up_t,   1024, 2816);
        tbf16_k<<<dim3(32,88,8), 256, 0, stream>>>(downw, down_t, 2816, 1024);

        rmsn1_k<<<NTOK, 256, 0, stream>>>(hidden, n1w, h1h, h1l);
        sgemm2_k<false><<<dim3(32,12), 256, 0, stream>>>(h1h, h1l, wqkvh, wqkvl, qkvf, nullptr, NQKV, 1024);
        rope2_k<<<10240, 256, 0, stream>>>(qkvf, fcos, fsin);
        attn2_k<<<dim3(NTOK,16), 64, 0, stream>>>(qkvf, ohB, olB);
        sgemm2_k<true><<<dim3(32,8), 256, 0, stream>>>(ohB, olB, woh, wol, hres, hidden, 1024, 1024);
        rmsn2_k<<<NTOK, 256, 0, stream>>>(hres, n2w, h2f, h2b);
        router_k<<<NTOK, 64, 0, stream>>>(h2f, routerw, lists, wl, cnt, psum);
        finalize_k<<<1, 64, 0, stream>>>(cnt, psum, offs, (float*)d_out);
        moe1_k<<<dim3(32,22,8), 256, 0, stream>>>(h2b, gate_t, up_t, inter, lists, cnt, offs);
        moe2_k<<<dim3(32,8,8), 256, 0, stream>>>(inter, down_t, hres, wl, lists, cnt, offs);
        final_k<<<NTOK, 256, 0, stream>>>(hres, (float*)d_out);
        return;
    }

    // ---- fallback (round-5) layout ----
    off = 0;
    cnt    = (int*)alloc(64);
    psum   = (float*)alloc(64);
    offs   = (int*)alloc(64);
    lists  = (int*)alloc((size_t)E_C*CAP*4);
    wl     = (float*)alloc((size_t)E_C*CAP*4);
    float* h1  = (float*)alloc((size_t)NTOK*HID_C*4);
    float* qb  = (float*)alloc((size_t)NTOK*HID_C*4);
    float* kb  = (float*)alloc((size_t)NTOK*256*4);
    float* vb  = (float*)alloc((size_t)NTOK*256*4);
    float* hresF = (float*)alloc((size_t)NTOK*HID_C*4);
    bf16*  h2bF  = (bf16*)alloc((size_t)NTOK*HID_C*2);
    bf16*  interF= (bf16*)alloc((size_t)2*NTOK*INTER_C*2);
    float* attnb = h1;
    float* h2fF  = qb;

    (void)hipMemsetAsync(cnt, 0, 64, stream);
    (void)hipMemsetAsync(psum, 0, 64, stream);

    rmsnorm_f<false><<<NTOK, 256, 0, stream>>>(hidden, n1w, h1, nullptr);
    sgemm_f<false><<<dim3(32, 8), 256, 0, stream>>>(h1, wq, qb, nullptr, 1024, 1024);
    sgemm_f<false><<<dim3(32, 2), 256, 0, stream>>>(h1, wk, kb, nullptr, 256, 1024);
    sgemm_f<false><<<dim3(32, 2), 256, 0, stream>>>(h1, wv, vb, nullptr, 256, 1024);
    rope_f<<<10240, 256, 0, stream>>>(qb, kb, fcos, fsin);
    attn_f<<<dim3(NTOK, 16), 64, 0, stream>>>(qb, kb, vb, attnb);
    sgemm_f<true><<<dim3(32, 8), 256, 0, stream>>>(attnb, wo, hresF, hidden, 1024, 1024);
    rmsnorm_f<true><<<NTOK, 256, 0, stream>>>(hresF, n2w, h2fF, h2bF);
    router_k<<<NTOK, 64, 0, stream>>>(h2fF, routerw, lists, wl, cnt, psum);
    finalize_k<<<1, 64, 0, stream>>>(cnt, psum, offs, (float*)d_out);
    moe_mlp1_f<<<dim3(32, 44, 8), 256, 0, stream>>>(h2bF, gatew, upw, interF, lists, cnt, offs);
    moe_mlp2_f<<<dim3(32, 8, 8), 256, 0, stream>>>(interF, downw, hresF, wl, lists, cnt, offs);
    final_k<<<NTOK, 256, 0, stream>>>(hresF, (float*)d_out);
}

// Round 7
// 2110.183 us; speedup vs baseline: 1.5301x; 1.5301x over previous
//
#include <hip/hip_runtime.h>
#include <hip/hip_bf16.h>
#include <math.h>

typedef short s16x8 __attribute__((ext_vector_type(8)));
typedef float f32x4 __attribute__((ext_vector_type(4)));
typedef __hip_bfloat16 bf16;

#define NTOK 4096
#define S_LEN 2048
#define HID_C 1024
#define E_C 8
#define INTER_C 2816
#define WIN_C 64
#define CAP 4096
#define NQKV 1536
#define OUT0_N ((size_t)NTOK*HID_C)

static __device__ __forceinline__ float b2f(bf16 v){ return __bfloat162float(v); }
static __device__ __forceinline__ bf16  f2b(float v){ return __float2bfloat16(v); }
static __device__ __forceinline__ short f2bs(float v){ bf16 h = __float2bfloat16(v); return *reinterpret_cast<short*>(&h); }
struct SplitBF { short hi; short lo; };
static __device__ __forceinline__ SplitBF splitf(float x){
    SplitBF r;
    bf16 bh = __float2bfloat16(x);
    r.hi = *reinterpret_cast<short*>(&bh);
    float rem = x - __bfloat162float(bh);
    bf16 bl = __float2bfloat16(rem);
    r.lo = *reinterpret_cast<short*>(&bl);
    return r;
}

// ================= PREPASS: transposes =================
// src f32 [1024][N] -> dst hi/lo bf16 [row_off+N][1024]
__global__ __launch_bounds__(256) void tsplit_k(const float* __restrict__ src,
                                                short* __restrict__ dhi, short* __restrict__ dlo,
                                                int N, int row_off){
    __shared__ float tile[32][33];
    const int n0 = blockIdx.x*32, k0 = blockIdx.y*32;
    const int tx = threadIdx.x & 31, ty = threadIdx.x >> 5;   // ty 0..7
    #pragma unroll
    for (int i = 0; i < 4; ++i)
        tile[ty + i*8][tx] = src[(size_t)(k0 + ty + i*8)*N + n0 + tx];
    __syncthreads();
    #pragma unroll
    for (int i = 0; i < 4; ++i){
        int nn = ty + i*8;
        SplitBF s = splitf(tile[tx][nn]);
        size_t d = (size_t)(row_off + n0 + nn)*1024 + k0 + tx;
        dhi[d] = s.hi; dlo[d] = s.lo;
    }
}

// src f32 [e][K][N] -> dst bf16 [e][N][K]
__global__ __launch_bounds__(256) void tbf16_k(const float* __restrict__ src0,
                                               short* __restrict__ dst0, int K, int N){
    const int e = blockIdx.z;
    const float* src = src0 + (size_t)e*K*N;
    short* dst = dst0 + (size_t)e*N*K;
    __shared__ float tile[32][33];
    const int n0 = blockIdx.x*32, k0 = blockIdx.y*32;
    const int tx = threadIdx.x & 31, ty = threadIdx.x >> 5;
    #pragma unroll
    for (int i = 0; i < 4; ++i)
        tile[ty + i*8][tx] = src[(size_t)(k0 + ty + i*8)*N + n0 + tx];
    __syncthreads();
    #pragma unroll
    for (int i = 0; i < 4; ++i){
        int nn = ty + i*8;
        dst[(size_t)(n0 + nn)*K + k0 + tx] = f2bs(tile[tx][nn]);
    }
}

// ================= RMSNorm variants =================
__global__ __launch_bounds__(256) void rmsn1_k(const float* __restrict__ xin,
                                               const float* __restrict__ w,
                                               short* __restrict__ oh, short* __restrict__ ol){
    const int t = blockIdx.x, tid = threadIdx.x;
    float4 v = *(const float4*)(xin + (size_t)t*HID_C + tid*4);
    float x[4] = {v.x, v.y, v.z, v.w};
    float s = x[0]*x[0]+x[1]*x[1]+x[2]*x[2]+x[3]*x[3];
    #pragma unroll
    for (int off=32; off; off>>=1) s += __shfl_xor(s, off);
    __shared__ float red[4];
    if ((tid&63)==0) red[tid>>6] = s;
    __syncthreads();
    float tot = red[0]+red[1]+red[2]+red[3];
    float sc = rsqrtf(tot*(1.0f/HID_C) + 1e-8f);
    float4 wv = *(const float4*)(w + tid*4);
    float o[4] = { x[0]*sc*wv.x, x[1]*sc*wv.y, x[2]*sc*wv.z, x[3]*sc*wv.w };
    __align__(8) short th[4], tl[4];
    #pragma unroll
    for (int i=0;i<4;++i){ SplitBF sp = splitf(o[i]); th[i]=sp.hi; tl[i]=sp.lo; }
    *(uint2*)(oh + (size_t)t*HID_C + tid*4) = *(uint2*)th;
    *(uint2*)(ol + (size_t)t*HID_C + tid*4) = *(uint2*)tl;
}

__global__ __launch_bounds__(256) void rmsn2_k(const float* __restrict__ xin,
                                               const float* __restrict__ w,
                                               float* __restrict__ outf, bf16* __restrict__ outb){
    const int t = blockIdx.x, tid = threadIdx.x;
    float4 v = *(const float4*)(xin + (size_t)t*HID_C + tid*4);
    float x[4] = {v.x, v.y, v.z, v.w};
    float s = x[0]*x[0]+x[1]*x[1]+x[2]*x[2]+x[3]*x[3];
    #pragma unroll
    for (int off=32; off; off>>=1) s += __shfl_xor(s, off);
    __shared__ float red[4];
    if ((tid&63)==0) red[tid>>6] = s;
    __syncthreads();
    float tot = red[0]+red[1]+red[2]+red[3];
    float sc = rsqrtf(tot*(1.0f/HID_C) + 1e-8f);
    float4 wv = *(const float4*)(w + tid*4);
    float o[4] = { x[0]*sc*wv.x, x[1]*sc*wv.y, x[2]*sc*wv.z, x[3]*sc*wv.w };
    *(float4*)(outf + (size_t)t*HID_C + tid*4) = make_float4(o[0],o[1],o[2],o[3]);
    __align__(8) bf16 tmp[4] = { f2b(o[0]), f2b(o[1]), f2b(o[2]), f2b(o[3]) };
    *(uint2*)(outb + (size_t)t*HID_C + tid*4) = *(uint2*)tmp;
}

// ============ split GEMM, pre-split bf16 operands (B transposed), 128x128 BK=32 ============
template<bool RESID>
__global__ __launch_bounds__(256) void sgemm2_k(const short* __restrict__ Ah, const short* __restrict__ Al,
                                                const short* __restrict__ Bh, const short* __restrict__ Bl,
                                                float* __restrict__ C, const float* __restrict__ resid,
                                                int N, int K){
    __shared__ __align__(16) short lAh[128*40];
    __shared__ __align__(16) short lAl[128*40];
    __shared__ __align__(16) short lBh[128*40];
    __shared__ __align__(16) short lBl[128*40];
    const int tid = threadIdx.x;
    const int bm0 = blockIdx.x*128, bn0 = blockIdx.y*128;
    const int l = tid & 63, w = tid >> 6, wr = w >> 1, wc = w & 1;
    f32x4 acc[4][4] = {};
    for (int kt = 0; kt < K/32; ++kt){
        #pragma unroll
        for (int i = 0; i < 2; ++i){
            int u = tid + i*256;
            int r = u >> 2, c8 = (u & 3)*8;
            size_t ga = (size_t)(bm0 + r)*K + kt*32 + c8;
            size_t gb = (size_t)(bn0 + r)*K + kt*32 + c8;
            *(s16x8*)(&lAh[r*40 + c8]) = *(const s16x8*)(Ah + ga);
            *(s16x8*)(&lAl[r*40 + c8]) = *(const s16x8*)(Al + ga);
            *(s16x8*)(&lBh[r*40 + c8]) = *(const s16x8*)(Bh + gb);
            *(s16x8*)(&lBl[r*40 + c8]) = *(const s16x8*)(Bl + gb);
        }
        __syncthreads();
        s16x8 ah[4], al[4], bh[4], bl[4];
        #pragma unroll
        for (int mi = 0; mi < 4; ++mi){
            int r = wr*64 + mi*16 + (l&15);
            ah[mi] = *(const s16x8*)(&lAh[r*40 + (l>>4)*8]);
            al[mi] = *(const s16x8*)(&lAl[r*40 + (l>>4)*8]);
        }
        #pragma unroll
        for (int ni = 0; ni < 4; ++ni){
            int n = wc*64 + ni*16 + (l&15);
            bh[ni] = *(const s16x8*)(&lBh[n*40 + (l>>4)*8]);
            bl[ni] = *(const s16x8*)(&lBl[n*40 + (l>>4)*8]);
        }
        #pragma unroll
        for (int mi = 0; mi < 4; ++mi)
            #pragma unroll
            for (int ni = 0; ni < 4; ++ni){
                acc[mi][ni] = __builtin_amdgcn_mfma_f32_16x16x32_bf16(ah[mi], bh[ni], acc[mi][ni], 0,0,0);
                acc[mi][ni] = __builtin_amdgcn_mfma_f32_16x16x32_bf16(ah[mi], bl[ni], acc[mi][ni], 0,0,0);
                acc[mi][ni] = __builtin_amdgcn_mfma_f32_16x16x32_bf16(al[mi], bh[ni], acc[mi][ni], 0,0,0);
            }
        __syncthreads();
    }
    #pragma unroll
    for (int mi = 0; mi < 4; ++mi)
        #pragma unroll
        for (int ni = 0; ni < 4; ++ni)
            #pragma unroll
            for (int rr = 0; rr < 4; ++rr){
                int row = bm0 + wr*64 + mi*16 + (l>>4)*4 + rr;
                int col = bn0 + wc*64 + ni*16 + (l&15);
                float vv = acc[mi][ni][rr];
                if (RESID) vv += resid[(size_t)row*N + col];
                C[(size_t)row*N + col] = vv;
            }
}

// ================ RoPE on packed qkv f32 [tok][1536] ================
__global__ __launch_bounds__(256) void rope2_k(float* __restrict__ qkv,
                                               const float* __restrict__ cosb, const float* __restrict__ sinb){
    int idx = blockIdx.x*256 + threadIdx.x;
    int t = idx / 640;
    int r = idx - t*640;
    int hs = r >> 5, tp = r & 31;
    int s = t & (S_LEN-1);
    float c  = cosb[s*32+tp];
    float sn = sinb[s*32+tp];
    float* base;
    if (hs < 16) base = qkv + (size_t)t*NQKV + hs*64 + 2*tp;
    else         base = qkv + (size_t)t*NQKV + 1024 + (hs-16)*64 + 2*tp;
    float2 v = *(float2*)base;
    *(float2*)base = make_float2(v.x*c - v.y*sn, v.x*sn + v.y*c);
}

// ======== sliding-window GQA attn on packed qkv, split hi/lo output ========
__global__ __launch_bounds__(64) void attn2_k(const float* __restrict__ qkv,
                                              short* __restrict__ oh, short* __restrict__ ol){
    const int l = threadIdx.x;
    const int bs = blockIdx.x;
    const int h = blockIdx.y, hk = h >> 2;
    const int sq = bs & (S_LEN-1);
    __shared__ float qs[64];
    __shared__ float ps[65];
    qs[l] = qkv[(size_t)bs*NQKV + h*64 + l];
    __syncthreads();
    const int j0 = (sq - WIN_C) > 0 ? (sq - WIN_C) : 0;
    const int nk = sq - j0 + 1;
    const int tokbase = bs - sq;
    float sc[2] = {-1e9f, -1e9f};
    #pragma unroll
    for (int it = 0; it < 2; ++it){
        int jj = l + it*64;
        if (jj < nk){
            const float* kp = qkv + (size_t)(tokbase + j0 + jj)*NQKV + 1024 + hk*64;
            float d = 0.f;
            #pragma unroll
            for (int c = 0; c < 16; ++c){
                float4 kv = *(const float4*)(kp + c*4);
                d += qs[c*4+0]*kv.x + qs[c*4+1]*kv.y + qs[c*4+2]*kv.z + qs[c*4+3]*kv.w;
            }
            sc[it] = d*0.125f;
        }
    }
    float m = fmaxf(sc[0], sc[1]);
    #pragma unroll
    for (int off=32; off; off>>=1) m = fmaxf(m, __shfl_xor(m, off));
    float e0 = (l      < nk) ? __expf(sc[0]-m) : 0.f;
    float e1 = (l + 64 < nk) ? __expf(sc[1]-m) : 0.f;
    float s = e0 + e1;
    #pragma unroll
    for (int off=32; off; off>>=1) s += __shfl_xor(s, off);
    float inv = 1.f/s;
    if (l      < nk) ps[l]    = e0*inv;
    if (l + 64 < nk) ps[l+64] = e1*inv;
    __syncthreads();
    float acc = 0.f;
    for (int jj = 0; jj < nk; ++jj)
        acc += ps[jj]*qkv[(size_t)(tokbase + j0 + jj)*NQKV + 1280 + hk*64 + l];
    SplitBF sp = splitf(acc);
    oh[(size_t)bs*HID_C + h*64 + l] = sp.hi;
    ol[(size_t)bs*HID_C + h*64 + l] = sp.lo;
}

// ================= router (f32) =================
__global__ __launch_bounds__(64) void router_k(const float* __restrict__ h2f, const float* __restrict__ rw,
                                               int* __restrict__ lists, float* __restrict__ wl,
                                               int* __restrict__ cnt, float* __restrict__ psum){
    const int t = blockIdx.x, l = threadIdx.x;
    float lg[8] = {0,0,0,0,0,0,0,0};
    for (int c = 0; c < 16; ++c){
        int kidx = l + c*64;
        float x = h2f[(size_t)t*HID_C + kidx];
        float4 w0 = *(const float4*)(rw + (size_t)kidx*8);
        float4 w1 = *(const float4*)(rw + (size_t)kidx*8 + 4);
        lg[0] += x*w0.x; lg[1] += x*w0.y; lg[2] += x*w0.z; lg[3] += x*w0.w;
        lg[4] += x*w1.x; lg[5] += x*w1.y; lg[6] += x*w1.z; lg[7] += x*w1.w;
    }
    #pragma unroll
    for (int e = 0; e < 8; ++e)
        #pragma unroll
        for (int off=32; off; off>>=1) lg[e] += __shfl_xor(lg[e], off);
    if (l == 0){
        float m = lg[0];
        #pragma unroll
        for (int e = 1; e < 8; ++e) m = fmaxf(m, lg[e]);
        float p[8]; float s = 0.f;
        #pragma unroll
        for (int e = 0; e < 8; ++e){ p[e] = __expf(lg[e]-m); s += p[e]; }
        float invs = 1.f/s;
        #pragma unroll
        for (int e = 0; e < 8; ++e){ p[e] *= invs; atomicAdd(&psum[e], p[e]); }
        float best = -1e30f, sec = -1e30f; int bi = 0, si = 0;
        #pragma unroll
        for (int e = 0; e < 8; ++e){
            float pv = p[e];
            if (pv > best){ sec = best; si = bi; best = pv; bi = e; }
            else if (pv > sec){ sec = pv; si = e; }
        }
        float wsum = best + sec + 1e-9f;
        int s0 = atomicAdd(&cnt[bi], 1);
        lists[bi*CAP + s0] = t; wl[bi*CAP + s0] = best/wsum;
        int s1 = atomicAdd(&cnt[si], 1);
        lists[si*CAP + s1] = t; wl[si*CAP + s1] = sec/wsum;
    }
}

__global__ void finalize_k(const int* __restrict__ cnt, const float* __restrict__ psum,
                           int* __restrict__ offs, float* __restrict__ out){
    if (threadIdx.x == 0 && blockIdx.x == 0){
        int o = 0; float loss = 0.f;
        for (int e = 0; e < 8; ++e){
            offs[e] = o; o += cnt[e];
            loss += (psum[e]*(1.0f/NTOK)) * ((float)cnt[e]*(1.0f/NTOK));
        }
        offs[8] = o;
        out[OUT0_N] = loss * (float)E_C * 0.01f;
    }
}

// ============ MoE gate/up fused: BN=64, BK=64, pre-transposed bf16 weights ============
// LDS = 128*72 + 2*64*72 shorts = 36.9 KB -> 4 blocks/CU; acc 16*f32x4 = 64 VGPR.
__global__ __launch_bounds__(256) void moe1_k(const bf16* __restrict__ h2b,
                                              const short* __restrict__ gate_t,
                                              const short* __restrict__ up_t,
                                              bf16* __restrict__ inter,
                                              const int* __restrict__ lists,
                                              const int* __restrict__ cnt,
                                              const int* __restrict__ offs){
    const int e = blockIdx.z;
    const int ne = cnt[e];
    const int bm0 = blockIdx.x*128;
    if (bm0 >= ne) return;
    const int bn0 = blockIdx.y*64;
    __shared__ __align__(16) short lA[128*72];
    __shared__ __align__(16) short lG[64*72];
    __shared__ __align__(16) short lU[64*72];
    const int tid = threadIdx.x;
    const int l = tid & 63, w = tid >> 6, wr = w >> 1, wc = w & 1;
    const short* Gb = gate_t + (size_t)e*INTER_C*HID_C;
    const short* Ub = up_t   + (size_t)e*INTER_C*HID_C;
    f32x4 ag[4][2] = {}; f32x4 au[4][2] = {};
    for (int kt = 0; kt < HID_C/64; ++kt){
        #pragma unroll
        for (int i = 0; i < 4; ++i){                 // A gather: 128 rows x 64 k
            int u = tid + i*256;
            int r = u >> 3, c8 = (u & 7)*8;
            int slot = bm0 + r;
            s16x8 v = {};
            if (slot < ne){
                int tok = lists[e*CAP + slot];
                v = *(const s16x8*)((const short*)h2b + (size_t)tok*HID_C + kt*64 + c8);
            }
            *(s16x8*)(&lA[r*72 + c8]) = v;
        }
        #pragma unroll
        for (int i = 0; i < 2; ++i){                 // G,U: 64 rows(n) x 64 k, vector
            int u = tid + i*256;
            int n = u >> 3, c8 = (u & 7)*8;
            size_t gi = (size_t)(bn0 + n)*HID_C + kt*64 + c8;
            *(s16x8*)(&lG[n*72 + c8]) = *(const s16x8*)(Gb + gi);
            *(s16x8*)(&lU[n*72 + c8]) = *(const s16x8*)(Ub + gi);
        }
        __syncthreads();
        #pragma unroll
        for (int kk = 0; kk < 64; kk += 32){
            s16x8 af[4], bg[2], bu[2];
            #pragma unroll
            for (int mi = 0; mi < 4; ++mi)
                af[mi] = *(const s16x8*)(&lA[(wr*64 + mi*16 + (l&15))*72 + kk + (l>>4)*8]);
            #pragma unroll
            for (int ni = 0; ni < 2; ++ni){
                int n = wc*32 + ni*16 + (l&15);
                bg[ni] = *(const s16x8*)(&lG[n*72 + kk + (l>>4)*8]);
                bu[ni] = *(const s16x8*)(&lU[n*72 + kk + (l>>4)*8]);
            }
            #pragma unroll
            for (int mi = 0; mi < 4; ++mi)
                #pragma unroll
                for (int ni = 0; ni < 2; ++ni){
                    ag[mi][ni] = __builtin_amdgcn_mfma_f32_16x16x32_bf16(af[mi], bg[ni], ag[mi][ni], 0,0,0);
                    au[mi][ni] = __builtin_amdgcn_mfma_f32_16x16x32_bf16(af[mi], bu[ni], au[mi][ni], 0,0,0);
                }
        }
        __syncthreads();
    }
    const int obase = offs[e];
    #pragma unroll
    for (int mi = 0; mi < 4; ++mi)
        #pragma unroll
        for (int ni = 0; ni < 2; ++ni)
            #pragma unroll
            for (int rr = 0; rr < 4; ++rr){
                int slot = bm0 + wr*64 + mi*16 + (l>>4)*4 + rr;
                if (slot < ne){
                    int col = bn0 + wc*32 + ni*16 + (l&15);
                    float g = ag[mi][ni][rr], uu = au[mi][ni][rr];
                    float val = (g/(1.f+__expf(-g)))*uu;
                    inter[(size_t)(obase+slot)*INTER_C + col] = f2b(val);
                }
            }
}

// ============ MoE down: bf16, pre-transposed weights, 128x128 BK=64, atomic into hres ============
__global__ __launch_bounds__(256) void moe2_k(const bf16* __restrict__ inter,
                                              const short* __restrict__ down_t,
                                              float* __restrict__ hres,
                                              const float* __restrict__ wl,
                                              const int* __restrict__ lists,
                                              const int* __restrict__ cnt,
                                              const int* __restrict__ offs){
    const int e = blockIdx.z;
    const int ne = cnt[e];
    const int bm0 = blockIdx.x*128;
    if (bm0 >= ne) return;
    const int bn0 = blockIdx.y*128;
    __shared__ __align__(16) short lA[128*72];
    __shared__ __align__(16) short lB[128*72];
    const int tid = threadIdx.x;
    const int l = tid & 63, w = tid >> 6, wr = w >> 1, wc = w & 1;
    const int obase = offs[e];
    const short* Db = down_t + (size_t)e*HID_C*INTER_C;
    f32x4 acc[4][4] = {};
    for (int kt = 0; kt < INTER_C/64; ++kt){
        #pragma unroll
        for (int i = 0; i < 4; ++i){
            int u = tid + i*256;
            int r = u >> 3, c8 = (u & 7)*8;
            int slot = bm0 + r;
            s16x8 v = {};
            if (slot < ne)
                v = *(const s16x8*)((const short*)inter + (size_t)(obase + slot)*INTER_C + kt*64 + c8);
            *(s16x8*)(&lA[r*72 + c8]) = v;
        }
        #pragma unroll
        for (int i = 0; i < 4; ++i){
            int u = tid + i*256;
            int n = u >> 3, c8 = (u & 7)*8;
            *(s16x8*)(&lB[n*72 + c8]) = *(const s16x8*)(Db + (size_t)(bn0 + n)*INTER_C + kt*64 + c8);
        }
        __syncthreads();
        #pragma unroll
        for (int kk = 0; kk < 64; kk += 32){
            s16x8 af[4], bfr[4];
            #pragma unroll
            for (int mi = 0; mi < 4; ++mi)
                af[mi] = *(const s16x8*)(&lA[(wr*64 + mi*16 + (l&15))*72 + kk + (l>>4)*8]);
            #pragma unroll
            for (int ni = 0; ni < 4; ++ni){
                int n = wc*64 + ni*16 + (l&15);
                bfr[ni] = *(const s16x8*)(&lB[n*72 + kk + (l>>4)*8]);
            }
            #pragma unroll
            for (int mi = 0; mi < 4; ++mi)
                #pragma unroll
                for (int ni = 0; ni < 4; ++ni)
                    acc[mi][ni] = __builtin_amdgcn_mfma_f32_16x16x32_bf16(af[mi], bfr[ni], acc[mi][ni], 0,0,0);
        }
        __syncthreads();
    }
    #pragma unroll
    for (int mi = 0; mi < 4; ++mi)
        #pragma unroll
        for (int ni = 0; ni < 4; ++ni)
            #pragma unroll
            for (int rr = 0; rr < 4; ++rr){
                int slot = bm0 + wr*64 + mi*16 + (l>>4)*4 + rr;
                if (slot < ne){
                    int col = bn0 + wc*64 + ni*16 + (l&15);
                    int tok = lists[e*CAP + slot];
                    float wgt = wl[e*CAP + slot];
                    atomicAdd(&hres[(size_t)tok*HID_C + col], acc[mi][ni][rr]*wgt);
                }
            }
}

__global__ __launch_bounds__(256) void final_k(const float* __restrict__ hres,
                                               float* __restrict__ out){
    const int t = blockIdx.x, c = threadIdx.x*4;
    float4 hv = *(const float4*)(hres + (size_t)t*HID_C + c);
    *(float4*)(out + (size_t)t*HID_C + c) = hv;
}

// ======================= FALLBACK PATH (round-5, ws-lean) =======================
template<bool ALSO_BF16>
__global__ __launch_bounds__(256) void rmsnorm_f(const float* __restrict__ xin, const float* __restrict__ w,
                                                 float* __restrict__ outf, bf16* __restrict__ outb){
    const int t = blockIdx.x, tid = threadIdx.x;
    float4 v = *(const float4*)(xin + (size_t)t*HID_C + tid*4);
    float x[4] = {v.x, v.y, v.z, v.w};
    float s = x[0]*x[0]+x[1]*x[1]+x[2]*x[2]+x[3]*x[3];
    #pragma unroll
    for (int off=32; off; off>>=1) s += __shfl_xor(s, off);
    __shared__ float red[4];
    if ((tid&63)==0) red[tid>>6] = s;
    __syncthreads();
    float tot = red[0]+red[1]+red[2]+red[3];
    float sc = rsqrtf(tot*(1.0f/HID_C) + 1e-8f);
    float4 wv = *(const float4*)(w + tid*4);
    float o[4] = { x[0]*sc*wv.x, x[1]*sc*wv.y, x[2]*sc*wv.z, x[3]*sc*wv.w };
    *(float4*)(outf + (size_t)t*HID_C + tid*4) = make_float4(o[0],o[1],o[2],o[3]);
    if (ALSO_BF16){
        __align__(8) bf16 tmp[4] = { f2b(o[0]), f2b(o[1]), f2b(o[2]), f2b(o[3]) };
        *(uint2*)(outb + (size_t)t*HID_C + tid*4) = *(uint2*)tmp;
    }
}

template<bool RESID>
__global__ __launch_bounds__(256) void sgemm_f(const float* __restrict__ A, const float* __restrict__ B,
                                               float* __restrict__ C, const float* __restrict__ resid,
                                               int N, int K){
    __shared__ __align__(16) short lAh[128*40];
    __shared__ __align__(16) short lAl[128*40];
    __shared__ __align__(16) short lBh[128*40];
    __shared__ __align__(16) short lBl[128*40];
    const int tid = threadIdx.x;
    const int bm0 = blockIdx.x*128, bn0 = blockIdx.y*128;
    const int l = tid & 63, w = tid >> 6, wr = w >> 1, wc = w & 1;
    f32x4 acc[4][4] = {};
    for (int kt = 0; kt < K/32; ++kt){
        #pragma unroll
        for (int i = 0; i < 4; ++i){
            int u = tid + i*256;
            int r = u >> 3, c4 = (u & 7)*4;
            float4 v = *(const float4*)(A + (size_t)(bm0+r)*K + kt*32 + c4);
            SplitBF s0 = splitf(v.x), s1 = splitf(v.y), s2 = splitf(v.z), s3 = splitf(v.w);
            __align__(8) short hv[4] = { s0.hi, s1.hi, s2.hi, s3.hi };
            __align__(8) short lv[4] = { s0.lo, s1.lo, s2.lo, s3.lo };
            *(uint2*)(&lAh[r*40 + c4]) = *(uint2*)hv;
            *(uint2*)(&lAl[r*40 + c4]) = *(uint2*)lv;
        }
        #pragma unroll
        for (int i = 0; i < 4; ++i){
            int u = tid + i*256;
            int k = u >> 5, n0 = (u & 31)*4;
            float4 v = *(const float4*)(B + (size_t)(kt*32 + k)*N + bn0 + n0);
            SplitBF s0 = splitf(v.x), s1 = splitf(v.y), s2 = splitf(v.z), s3 = splitf(v.w);
            lBh[(n0+0)*40+k]=s0.hi; lBh[(n0+1)*40+k]=s1.hi; lBh[(n0+2)*40+k]=s2.hi; lBh[(n0+3)*40+k]=s3.hi;
            lBl[(n0+0)*40+k]=s0.lo; lBl[(n0+1)*40+k]=s1.lo; lBl[(n0+2)*40+k]=s2.lo; lBl[(n0+3)*40+k]=s3.lo;
        }
        __syncthreads();
        s16x8 ah[4], al[4], bh[4], bl[4];
        #pragma unroll
        for (int mi = 0; mi < 4; ++mi){
            int r = wr*64 + mi*16 + (l&15);
            ah[mi] = *(const s16x8*)(&lAh[r*40 + (l>>4)*8]);
            al[mi] = *(const s16x8*)(&lAl[r*40 + (l>>4)*8]);
        }
        #pragma unroll
        for (int ni = 0; ni < 4; ++ni){
            int n = wc*64 + ni*16 + (l&15);
            bh[ni] = *(const s16x8*)(&lBh[n*40 + (l>>4)*8]);
            bl[ni] = *(const s16x8*)(&lBl[n*40 + (l>>4)*8]);
        }
        #pragma unroll
        for (int mi = 0; mi < 4; ++mi)
            #pragma unroll
            for (int ni = 0; ni < 4; ++ni){
                acc[mi][ni] = __builtin_amdgcn_mfma_f32_16x16x32_bf16(ah[mi], bh[ni], acc[mi][ni], 0,0,0);
                acc[mi][ni] = __builtin_amdgcn_mfma_f32_16x16x32_bf16(ah[mi], bl[ni], acc[mi][ni], 0,0,0);
                acc[mi][ni] = __builtin_amdgcn_mfma_f32_16x16x32_bf16(al[mi], bh[ni], acc[mi][ni], 0,0,0);
            }
        __syncthreads();
    }
    #pragma unroll
    for (int mi = 0; mi < 4; ++mi)
        #pragma unroll
        for (int ni = 0; ni < 4; ++ni)
            #pragma unroll
            for (int rr = 0; rr < 4; ++rr){
                int row = bm0 + wr*64 + mi*16 + (l>>4)*4 + rr;
                int col = bn0 + wc*64 + ni*16 + (l&15);
                float vv = acc[mi][ni][rr];
                if (RESID) vv += resid[(size_t)row*N + col];
                C[(size_t)row*N + col] = vv;
            }
}

__global__ __launch_bounds__(256) void rope_f(float* __restrict__ qb, float* __restrict__ kb,
                                              const float* __restrict__ cosb, const float* __restrict__ sinb){
    int idx = blockIdx.x*256 + threadIdx.x;
    int t = idx / 640;
    int r = idx - t*640;
    int hs = r >> 5, tp = r & 31;
    int s = t & (S_LEN-1);
    float c  = cosb[s*32+tp];
    float sn = sinb[s*32+tp];
    float* base;
    if (hs < 16) base = qb + (size_t)t*1024 + hs*64 + 2*tp;
    else         base = kb + (size_t)t*256 + (hs-16)*64 + 2*tp;
    float2 v = *(float2*)base;
    *(float2*)base = make_float2(v.x*c - v.y*sn, v.x*sn + v.y*c);
}

__global__ __launch_bounds__(64) void attn_f(const float* __restrict__ qb, const float* __restrict__ kb,
                                             const float* __restrict__ vb, float* __restrict__ ob){
    const int l = threadIdx.x;
    const int bs = blockIdx.x;
    const int h = blockIdx.y, hk = h >> 2;
    const int sq = bs & (S_LEN-1);
    __shared__ float qs[64];
    __shared__ float ps[65];
    qs[l] = qb[(size_t)bs*1024 + h*64 + l];
    __syncthreads();
    const int j0 = (sq - WIN_C) > 0 ? (sq - WIN_C) : 0;
    const int nk = sq - j0 + 1;
    const int tokbase = bs - sq;
    float sc[2] = {-1e9f, -1e9f};
    #pragma unroll
    for (int it = 0; it < 2; ++it){
        int jj = l + it*64;
        if (jj < nk){
            const float* kp = kb + (size_t)(tokbase + j0 + jj)*256 + hk*64;
            float d = 0.f;
            #pragma unroll
            for (int c = 0; c < 16; ++c){
                float4 kv = *(const float4*)(kp + c*4);
                d += qs[c*4+0]*kv.x + qs[c*4+1]*kv.y + qs[c*4+2]*kv.z + qs[c*4+3]*kv.w;
            }
            sc[it] = d*0.125f;
        }
    }
    float m = fmaxf(sc[0], sc[1]);
    #pragma unroll
    for (int off=32; off; off>>=1) m = fmaxf(m, __shfl_xor(m, off));
    float e0 = (l      < nk) ? __expf(sc[0]-m) : 0.f;
    float e1 = (l + 64 < nk) ? __expf(sc[1]-m) : 0.f;
    float s = e0 + e1;
    #pragma unroll
    for (int off=32; off; off>>=1) s += __shfl_xor(s, off);
    float inv = 1.f/s;
    if (l      < nk) ps[l]    = e0*inv;
    if (l + 64 < nk) ps[l+64] = e1*inv;
    __syncthreads();
    float acc = 0.f;
    for (int jj = 0; jj < nk; ++jj)
        acc += ps[jj]*vb[(size_t)(tokbase + j0 + jj)*256 + hk*64 + l];
    ob[(size_t)bs*1024 + h*64 + l] = acc;
}

__global__ __launch_bounds__(256) void moe_mlp1_f(const bf16* __restrict__ h2b,
                                                  const float* __restrict__ gateW,
                                                  const float* __restrict__ upW,
                                                  bf16* __restrict__ inter,
                                                  const int* __restrict__ lists,
                                                  const int* __restrict__ cnt,
                                                  const int* __restrict__ offs){
    const int e = blockIdx.z;
    const int ne = cnt[e];
    const int bm0 = blockIdx.x*128;
    if (bm0 >= ne) return;
    const int bn0 = blockIdx.y*64;
    __shared__ __align__(16) short lA[128*72];
    __shared__ __align__(16) short lG[64*72];
    __shared__ __align__(16) short lU[64*72];
    const int tid = threadIdx.x;
    const int l = tid & 63, w = tid >> 6, wr = w >> 1, wc = w & 1;
    const size_t ebase = (size_t)e*HID_C*INTER_C;
    f32x4 ag[4][2] = {}; f32x4 au[4][2] = {};
    for (int kt = 0; kt < HID_C/64; ++kt){
        #pragma unroll
        for (int i = 0; i < 4; ++i){
            int u = tid + i*256;
            int r = u >> 3, cu = u & 7;
            int slot = bm0 + r;
            s16x8 v = {};
            if (slot < ne){
                int tok = lists[e*CAP + slot];
                v = *(const s16x8*)((const short*)h2b + (size_t)tok*HID_C + kt*64 + cu*8);
            }
            *(s16x8*)(&lA[r*72 + cu*8]) = v;
        }
        #pragma unroll
        for (int i = 0; i < 2; ++i){
            int u = tid + i*256;
            int k = u >> 3, n0 = (u & 7)*8;
            size_t gidx = ebase + (size_t)(kt*64 + k)*INTER_C + bn0 + n0;
            const float* gp = gateW + gidx;
            const float* up = upW + gidx;
            float4 ga = *(const float4*)gp, gb = *(const float4*)(gp+4);
            float4 ua = *(const float4*)up, ub = *(const float4*)(up+4);
            lG[(n0+0)*72+k]=f2bs(ga.x); lG[(n0+1)*72+k]=f2bs(ga.y); lG[(n0+2)*72+k]=f2bs(ga.z); lG[(n0+3)*72+k]=f2bs(ga.w);
            lG[(n0+4)*72+k]=f2bs(gb.x); lG[(n0+5)*72+k]=f2bs(gb.y); lG[(n0+6)*72+k]=f2bs(gb.z); lG[(n0+7)*72+k]=f2bs(gb.w);
            lU[(n0+0)*72+k]=f2bs(ua.x); lU[(n0+1)*72+k]=f2bs(ua.y); lU[(n0+2)*72+k]=f2bs(ua.z); lU[(n0+3)*72+k]=f2bs(ua.w);
            lU[(n0+4)*72+k]=f2bs(ub.x); lU[(n0+5)*72+k]=f2bs(ub.y); lU[(n0+6)*72+k]=f2bs(ub.z); lU[(n0+7)*72+k]=f2bs(ub.w);
        }
        __syncthreads();
        #pragma unroll
        for (int kk = 0; kk < 64; kk += 32){
            s16x8 af[4], bg[2], bu[2];
            #pragma unroll
            for (int mi = 0; mi < 4; ++mi)
                af[mi] = *(const s16x8*)(&lA[(wr*64 + mi*16 + (l&15))*72 + kk + (l>>4)*8]);
            #pragma unroll
            for (int ni = 0; ni < 2; ++ni){
                int n = wc*32 + ni*16 + (l&15);
                bg[ni] = *(const s16x8*)(&lG[n*72 + kk + (l>>4)*8]);
                bu[ni] = *(const s16x8*)(&lU[n*72 + kk + (l>>4)*8]);
            }
            #pragma unroll
            for (int mi = 0; mi < 4; ++mi)
                #pragma unroll
                for (int ni = 0; ni < 2; ++ni){
                    ag[mi][ni] = __builtin_amdgcn_mfma_f32_16x16x32_bf16(af[mi], bg[ni], ag[mi][ni], 0,0,0);
                    au[mi][ni] = __builtin_amdgcn_mfma_f32_16x16x32_bf16(af[mi], bu[ni], au[mi][ni], 0,0,0);
                }
        }
        __syncthreads();
    }
    const int obase = offs[e];
    #pragma unroll
    for (int mi = 0; mi < 4; ++mi)
        #pragma unroll
        for (int ni = 0; ni < 2; ++ni)
            #pragma unroll
            for (int rr = 0; rr < 4; ++rr){
                int slot = bm0 + wr*64 + mi*16 + (l>>4)*4 + rr;
                if (slot < ne){
                    int col = bn0 + wc*32 + ni*16 + (l&15);
                    float g = ag[mi][ni][rr], uu = au[mi][ni][rr];
                    float val = (g/(1.f+__expf(-g)))*uu;
                    inter[(size_t)(obase+slot)*INTER_C + col] = f2b(val);
                }
            }
}

__global__ __launch_bounds__(256) void moe_mlp2_f(const bf16* __restrict__ inter,
                                                  const float* __restrict__ downW,
                                                  float* __restrict__ hres,
                                                  const float* __restrict__ wl,
                                                  const int* __restrict__ lists,
                                                  const int* __restrict__ cnt,
                                                  const int* __restrict__ offs){
    const int e = blockIdx.z;
    const int ne = cnt[e];
    const int bm0 = blockIdx.x*128;
    if (bm0 >= ne) return;
    const int bn0 = blockIdx.y*128;
    __shared__ __align__(16) short lA[128*72];
    __shared__ __align__(16) short lB[128*72];
    const int tid = threadIdx.x;
    const int l = tid & 63, w = tid >> 6, wr = w >> 1, wc = w & 1;
    const int obase = offs[e];
    const size_t ebase = (size_t)e*INTER_C*HID_C;
    f32x4 acc[4][4] = {};
    for (int kt = 0; kt < INTER_C/64; ++kt){
        #pragma unroll
        for (int i = 0; i < 4; ++i){
            int u = tid + i*256;
            int r = u >> 3, cu = u & 7;
            int slot = bm0 + r;
            s16x8 v = {};
            if (slot < ne)
                v = *(const s16x8*)((const short*)inter + (size_t)(obase + slot)*INTER_C + kt*64 + cu*8);
            *(s16x8*)(&lA[r*72 + cu*8]) = v;
        }
        #pragma unroll
        for (int i = 0; i < 4; ++i){
            int u = tid + i*256;
            int k = u >> 4, n0 = (u & 15)*8;
            const float* bp = downW + ebase + (size_t)(kt*64 + k)*HID_C + bn0 + n0;
            float4 a = *(const float4*)bp, b = *(const float4*)(bp+4);
            lB[(n0+0)*72+k]=f2bs(a.x); lB[(n0+1)*72+k]=f2bs(a.y); lB[(n0+2)*72+k]=f2bs(a.z); lB[(n0+3)*72+k]=f2bs(a.w);
            lB[(n0+4)*72+k]=f2bs(b.x); lB[(n0+5)*72+k]=f2bs(b.y); lB[(n0+6)*72+k]=f2bs(b.z); lB[(n0+7)*72+k]=f2bs(b.w);
        }
        __syncthreads();
        #pragma unroll
        for (int kk = 0; kk < 64; kk += 32){
            s16x8 af[4], bfr[4];
            #pragma unroll
            for (int mi = 0; mi < 4; ++mi)
                af[mi] = *(const s16x8*)(&lA[(wr*64 + mi*16 + (l&15))*72 + kk + (l>>4)*8]);
            #pragma unroll
            for (int ni = 0; ni < 4; ++ni){
                int n = wc*64 + ni*16 + (l&15);
                bfr[ni] = *(const s16x8*)(&lB[n*72 + kk + (l>>4)*8]);
            }
            #pragma unroll
            for (int mi = 0; mi < 4; ++mi)
                #pragma unroll
                for (int ni = 0; ni < 4; ++ni)
                    acc[mi][ni] = __builtin_amdgcn_mfma_f32_16x16x32_bf16(af[mi], bfr[ni], acc[mi][ni], 0,0,0);
        }
        __syncthreads();
    }
    #pragma unroll
    for (int mi = 0; mi < 4; ++mi)
        #pragma unroll
        for (int ni = 0; ni < 4; ++ni)
            #pragma unroll
            for (int rr = 0; rr < 4; ++rr){
                int slot = bm0 + wr*64 + mi*16 + (l>>4)*4 + rr;
                if (slot < ne){
                    int col = bn0 + wc*64 + ni*16 + (l&15);
                    int tok = lists[e*CAP + slot];
                    float wgt = wl[e*CAP + slot];
                    atomicAdd(&hres[(size_t)tok*HID_C + col], acc[mi][ni][rr]*wgt);
                }
            }
}

// ======================= HOST =======================
extern "C" void kernel_launch(void* const* d_in, const int* in_sizes, int n_in,
                              void* d_out, int out_size, void* d_ws, size_t ws_size,
                              hipStream_t stream){
    const float* hidden  = (const float*)d_in[0];
    const float* fcos    = (const float*)d_in[1];
    const float* fsin    = (const float*)d_in[2];
    const float* wq      = (const float*)d_in[3];
    const float* wk      = (const float*)d_in[4];
    const float* wv      = (const float*)d_in[5];
    const float* wo      = (const float*)d_in[6];
    const float* routerw = (const float*)d_in[7];
    const float* gatew   = (const float*)d_in[8];
    const float* upw     = (const float*)d_in[9];
    const float* downw   = (const float*)d_in[10];
    const float* n1w     = (const float*)d_in[11];
    const float* n2w     = (const float*)d_in[12];

    char* p = (char*)d_ws;
    size_t off = 0;
    auto alloc = [&](size_t b)->void*{ void* r = p + off; off = (off + b + 255) & ~(size_t)255; return r; };

    // ---- big-path layout ----
    int*   cnt    = (int*)alloc(64);
    float* psum   = (float*)alloc(64);
    int*   offs   = (int*)alloc(64);
    int*   lists  = (int*)alloc((size_t)E_C*CAP*4);
    float* wl     = (float*)alloc((size_t)E_C*CAP*4);
    short* wqkvh  = (short*)alloc((size_t)NQKV*HID_C*2);
    short* wqkvl  = (short*)alloc((size_t)NQKV*HID_C*2);
    short* woh    = (short*)alloc((size_t)HID_C*HID_C*2);
    short* wol    = (short*)alloc((size_t)HID_C*HID_C*2);
    short* gate_t = (short*)alloc((size_t)E_C*INTER_C*HID_C*2);
    short* up_t   = (short*)alloc((size_t)E_C*INTER_C*HID_C*2);
    short* down_t = (short*)alloc((size_t)E_C*HID_C*INTER_C*2);
    short* h1h    = (short*)alloc((size_t)NTOK*HID_C*2);     // later oh
    short* h1l    = (short*)alloc((size_t)NTOK*HID_C*2);     // later ol
    float* qkvf   = (float*)alloc((size_t)NTOK*NQKV*4);      // later h2f + h2b
    float* hres   = (float*)alloc((size_t)NTOK*HID_C*4);
    bf16*  inter  = (bf16*)alloc((size_t)2*NTOK*INTER_C*2);
    size_t need_big = off;

    if (ws_size >= need_big){
        short* ohB = h1h;
        short* olB = h1l;
        float* h2f = qkvf;
        bf16*  h2b = (bf16*)(qkvf + (size_t)NTOK*HID_C);

        (void)hipMemsetAsync(cnt, 0, 64, stream);
        (void)hipMemsetAsync(psum, 0, 64, stream);

        // prepass transposes
        tsplit_k<<<dim3(32,32), 256, 0, stream>>>(wq, wqkvh, wqkvl, 1024, 0);
        tsplit_k<<<dim3(8,32),  256, 0, stream>>>(wk, wqkvh, wqkvl, 256, 1024);
        tsplit_k<<<dim3(8,32),  256, 0, stream>>>(wv, wqkvh, wqkvl, 256, 1280);
        tsplit_k<<<dim3(32,32), 256, 0, stream>>>(wo, woh, wol, 1024, 0);
        tbf16_k<<<dim3(88,32,8), 256, 0, stream>>>(gatew, gate_t, 1024, 2816);
        tbf16_k<<<dim3(88,32,8), 256, 0, stream>>>(upw,   up_t,   1024, 2816);
        tbf16_k<<<dim3(32,88,8), 256, 0, stream>>>(downw, down_t, 2816, 1024);

        rmsn1_k<<<NTOK, 256, 0, stream>>>(hidden, n1w, h1h, h1l);
        sgemm2_k<false><<<dim3(32,12), 256, 0, stream>>>(h1h, h1l, wqkvh, wqkvl, qkvf, nullptr, NQKV, 1024);
        rope2_k<<<10240, 256, 0, stream>>>(qkvf, fcos, fsin);
        attn2_k<<<dim3(NTOK,16), 64, 0, stream>>>(qkvf, ohB, olB);
        sgemm2_k<true><<<dim3(32,8), 256, 0, stream>>>(ohB, olB, woh, wol, hres, hidden, 1024, 1024);
        rmsn2_k<<<NTOK, 256, 0, stream>>>(hres, n2w, h2f, h2b);
        router_k<<<NTOK, 64, 0, stream>>>(h2f, routerw, lists, wl, cnt, psum);
        finalize_k<<<1, 64, 0, stream>>>(cnt, psum, offs, (float*)d_out);
        moe1_k<<<dim3(32,44,8), 256, 0, stream>>>(h2b, gate_t, up_t, inter, lists, cnt, offs);
        moe2_k<<<dim3(32,8,8), 256, 0, stream>>>(inter, down_t, hres, wl, lists, cnt, offs);
        final_k<<<NTOK, 256, 0, stream>>>(hres, (float*)d_out);
        return;
    }

    // ---- fallback (round-5) layout ----
    off = 0;
    cnt    = (int*)alloc(64);
    psum   = (float*)alloc(64);
    offs   = (int*)alloc(64);
    lists  = (int*)alloc((size_t)E_C*CAP*4);
    wl     = (float*)alloc((size_t)E_C*CAP*4);
    float* h1  = (float*)alloc((size_t)NTOK*HID_C*4);
    float* qb  = (float*)alloc((size_t)NTOK*HID_C*4);
    float* kb  = (float*)alloc((size_t)NTOK*256*4);
    float* vb  = (float*)alloc((size_t)NTOK*256*4);
    float* hresF = (float*)alloc((size_t)NTOK*HID_C*4);
    bf16*  h2bF  = (bf16*)alloc((size_t)NTOK*HID_C*2);
    bf16*  interF= (bf16*)alloc((size_t)2*NTOK*INTER_C*2);
    float* attnb = h1;
    float* h2fF  = qb;

    (void)hipMemsetAsync(cnt, 0, 64, stream);
    (void)hipMemsetAsync(psum, 0, 64, stream);

    rmsnorm_f<false><<<NTOK, 256, 0, stream>>>(hidden, n1w, h1, nullptr);
    sgemm_f<false><<<dim3(32, 8), 256, 0, stream>>>(h1, wq, qb, nullptr, 1024, 1024);
    sgemm_f<false><<<dim3(32, 2), 256, 0, stream>>>(h1, wk, kb, nullptr, 256, 1024);
    sgemm_f<false><<<dim3(32, 2), 256, 0, stream>>>(h1, wv, vb, nullptr, 256, 1024);
    rope_f<<<10240, 256, 0, stream>>>(qb, kb, fcos, fsin);
    attn_f<<<dim3(NTOK, 16), 64, 0, stream>>>(qb, kb, vb, attnb);
    sgemm_f<true><<<dim3(32, 8), 256, 0, stream>>>(attnb, wo, hresF, hidden, 1024, 1024);
    rmsnorm_f<true><<<NTOK, 256, 0, stream>>>(hresF, n2w, h2fF, h2bF);
    router_k<<<NTOK, 64, 0, stream>>>(h2fF, routerw, lists, wl, cnt, psum);
    finalize_k<<<1, 64, 0, stream>>>(cnt, psum, offs, (float*)d_out);
    moe_mlp1_f<<<dim3(32, 44, 8), 256, 0, stream>>>(h2bF, gatew, upw, interF, lists, cnt, offs);
    moe_mlp2_f<<<dim3(32, 8, 8), 256, 0, stream>>>(interF, downw, hresF, wl, lists, cnt, offs);
    final_k<<<NTOK, 256, 0, stream>>>(hresF, (float*)d_out);
}

// Round 8
// 1846.030 us; speedup vs baseline: 1.7491x; 1.1431x over previous
//
#include <hip/hip_runtime.h>
#include <hip/hip_bf16.h>
#include <math.h>

typedef short s16x8 __attribute__((ext_vector_type(8)));
typedef float f32x4 __attribute__((ext_vector_type(4)));
typedef __hip_bfloat16 bf16;

#define NTOK 4096
#define S_LEN 2048
#define HID_C 1024
#define E_C 8
#define INTER_C 2816
#define WIN_C 64
#define CAP 4096
#define NQKV 1536
#define K2C 2048
#define OUT0_N ((size_t)NTOK*HID_C)

#define AS1 __attribute__((address_space(1)))
#define AS3 __attribute__((address_space(3)))

static __device__ __forceinline__ void gload16(const void* g, void* l){
    __builtin_amdgcn_global_load_lds((AS1 void*)(g), (AS3 void*)(l), 16, 0, 0);
}

static __device__ __forceinline__ float b2f(bf16 v){ return __bfloat162float(v); }
static __device__ __forceinline__ bf16  f2b(float v){ return __float2bfloat16(v); }
static __device__ __forceinline__ short f2bs(float v){ bf16 h = __float2bfloat16(v); return *reinterpret_cast<short*>(&h); }
struct SplitBF { short hi; short lo; };
static __device__ __forceinline__ SplitBF splitf(float x){
    SplitBF r;
    bf16 bh = __float2bfloat16(x);
    r.hi = *reinterpret_cast<short*>(&bh);
    float rem = x - __bfloat162float(bh);
    bf16 bl = __float2bfloat16(rem);
    r.lo = *reinterpret_cast<short*>(&bl);
    return r;
}

// ============ PREPASS: f32 [1024][N] -> combined hi/lo [row_off+n][2048] ============
// combined layout: row r, k in [0,1024): hi at r*2048 + (k>>5)*64 + (k&31), lo at +32
__global__ __launch_bounds__(256) void tsplit2_k(const float* __restrict__ src,
                                                 short* __restrict__ dst,
                                                 int N, int row_off){
    __shared__ float tile[32][33];
    const int n0 = blockIdx.x*32, k0 = blockIdx.y*32;
    const int tx = threadIdx.x & 31, ty = threadIdx.x >> 5;
    #pragma unroll
    for (int i = 0; i < 4; ++i)
        tile[ty + i*8][tx] = src[(size_t)(k0 + ty + i*8)*N + n0 + tx];
    __syncthreads();
    const int g = k0 >> 5;   // tx < 32 so group is uniform
    #pragma unroll
    for (int i = 0; i < 4; ++i){
        int nn = ty + i*8;
        SplitBF s = splitf(tile[tx][nn]);
        size_t base = (size_t)(row_off + n0 + nn)*K2C + g*64 + tx;
        dst[base] = s.hi; dst[base + 32] = s.lo;
    }
}

// f32 [e][K][N] -> bf16 [e][N][K]
__global__ __launch_bounds__(256) void tbf16_k(const float* __restrict__ src0,
                                               short* __restrict__ dst0, int K, int N){
    const int e = blockIdx.z;
    const float* src = src0 + (size_t)e*K*N;
    short* dst = dst0 + (size_t)e*N*K;
    __shared__ float tile[32][33];
    const int n0 = blockIdx.x*32, k0 = blockIdx.y*32;
    const int tx = threadIdx.x & 31, ty = threadIdx.x >> 5;
    #pragma unroll
    for (int i = 0; i < 4; ++i)
        tile[ty + i*8][tx] = src[(size_t)(k0 + ty + i*8)*N + n0 + tx];
    __syncthreads();
    #pragma unroll
    for (int i = 0; i < 4; ++i){
        int nn = ty + i*8;
        dst[(size_t)(n0 + nn)*K + k0 + tx] = f2bs(tile[tx][nn]);
    }
}

// ================= RMSNorm: f32 in -> combined hi/lo out =================
__global__ __launch_bounds__(256) void rmsn1c_k(const float* __restrict__ xin,
                                                const float* __restrict__ w,
                                                short* __restrict__ oc){
    const int t = blockIdx.x, tid = threadIdx.x;
    float4 v = *(const float4*)(xin + (size_t)t*HID_C + tid*4);
    float x[4] = {v.x, v.y, v.z, v.w};
    float s = x[0]*x[0]+x[1]*x[1]+x[2]*x[2]+x[3]*x[3];
    #pragma unroll
    for (int off=32; off; off>>=1) s += __shfl_xor(s, off);
    __shared__ float red[4];
    if ((tid&63)==0) red[tid>>6] = s;
    __syncthreads();
    float tot = red[0]+red[1]+red[2]+red[3];
    float sc = rsqrtf(tot*(1.0f/HID_C) + 1e-8f);
    float4 wv = *(const float4*)(w + tid*4);
    float o[4] = { x[0]*sc*wv.x, x[1]*sc*wv.y, x[2]*sc*wv.z, x[3]*sc*wv.w };
    __align__(8) short th[4], tl[4];
    #pragma unroll
    for (int i=0;i<4;++i){ SplitBF sp = splitf(o[i]); th[i]=sp.hi; tl[i]=sp.lo; }
    short* dst = oc + (size_t)t*K2C + (tid>>3)*64 + (tid&7)*4;
    *(uint2*)dst        = *(uint2*)th;
    *(uint2*)(dst + 32) = *(uint2*)tl;
}

// norm2: f32 in -> f32 out + bf16 out (unchanged)
__global__ __launch_bounds__(256) void rmsn2_k(const float* __restrict__ xin,
                                               const float* __restrict__ w,
                                               float* __restrict__ outf, bf16* __restrict__ outb){
    const int t = blockIdx.x, tid = threadIdx.x;
    float4 v = *(const float4*)(xin + (size_t)t*HID_C + tid*4);
    float x[4] = {v.x, v.y, v.z, v.w};
    float s = x[0]*x[0]+x[1]*x[1]+x[2]*x[2]+x[3]*x[3];
    #pragma unroll
    for (int off=32; off; off>>=1) s += __shfl_xor(s, off);
    __shared__ float red[4];
    if ((tid&63)==0) red[tid>>6] = s;
    __syncthreads();
    float tot = red[0]+red[1]+red[2]+red[3];
    float sc = rsqrtf(tot*(1.0f/HID_C) + 1e-8f);
    float4 wv = *(const float4*)(w + tid*4);
    float o[4] = { x[0]*sc*wv.x, x[1]*sc*wv.y, x[2]*sc*wv.z, x[3]*sc*wv.w };
    *(float4*)(outf + (size_t)t*HID_C + tid*4) = make_float4(o[0],o[1],o[2],o[3]);
    __align__(8) bf16 tmp[4] = { f2b(o[0]), f2b(o[1]), f2b(o[2]), f2b(o[3]) };
    *(uint2*)(outb + (size_t)t*HID_C + tid*4) = *(uint2*)tmp;
}

// ============ split GEMM via global_load_lds: combined [row][2048] operands ============
template<bool RESID>
__global__ __launch_bounds__(256) void sgemm3_k(const short* __restrict__ A2,
                                                const short* __restrict__ B2,
                                                float* __restrict__ C, const float* __restrict__ resid,
                                                int N){
    __shared__ __align__(16) short lA[128*64];
    __shared__ __align__(16) short lB[128*64];
    const int tid = threadIdx.x;
    const int bm0 = blockIdx.x*128, bn0 = blockIdx.y*128;
    const int l = tid & 63, w = tid >> 6, wr = w >> 1, wc = w & 1;
    const int lr = l >> 3, lc8 = (l & 7)*8;
    f32x4 acc[4][4] = {};
    for (int kt = 0; kt < 32; ++kt){
        #pragma unroll
        for (int j = 0; j < 4; ++j){
            int row = w*32 + j*8 + lr;
            gload16(A2 + (size_t)(bm0 + row)*K2C + kt*64 + lc8, &lA[(w*32 + j*8)*64]);
            gload16(B2 + (size_t)(bn0 + row)*K2C + kt*64 + lc8, &lB[(w*32 + j*8)*64]);
        }
        __syncthreads();
        s16x8 ah[4], al[4], bh[4], bl[4];
        #pragma unroll
        for (int mi = 0; mi < 4; ++mi){
            int r = wr*64 + mi*16 + (l&15);
            ah[mi] = *(const s16x8*)(&lA[r*64 + (l>>4)*8]);
            al[mi] = *(const s16x8*)(&lA[r*64 + 32 + (l>>4)*8]);
        }
        #pragma unroll
        for (int ni = 0; ni < 4; ++ni){
            int n = wc*64 + ni*16 + (l&15);
            bh[ni] = *(const s16x8*)(&lB[n*64 + (l>>4)*8]);
            bl[ni] = *(const s16x8*)(&lB[n*64 + 32 + (l>>4)*8]);
        }
        #pragma unroll
        for (int mi = 0; mi < 4; ++mi)
            #pragma unroll
            for (int ni = 0; ni < 4; ++ni){
                acc[mi][ni] = __builtin_amdgcn_mfma_f32_16x16x32_bf16(ah[mi], bh[ni], acc[mi][ni], 0,0,0);
                acc[mi][ni] = __builtin_amdgcn_mfma_f32_16x16x32_bf16(ah[mi], bl[ni], acc[mi][ni], 0,0,0);
                acc[mi][ni] = __builtin_amdgcn_mfma_f32_16x16x32_bf16(al[mi], bh[ni], acc[mi][ni], 0,0,0);
            }
        __syncthreads();
    }
    #pragma unroll
    for (int mi = 0; mi < 4; ++mi)
        #pragma unroll
        for (int ni = 0; ni < 4; ++ni)
            #pragma unroll
            for (int rr = 0; rr < 4; ++rr){
                int row = bm0 + wr*64 + mi*16 + (l>>4)*4 + rr;
                int col = bn0 + wc*64 + ni*16 + (l&15);
                float vv = acc[mi][ni][rr];
                if (RESID) vv += resid[(size_t)row*N + col];
                C[(size_t)row*N + col] = vv;
            }
}

// ================ RoPE on packed qkv f32 [tok][1536] ================
__global__ __launch_bounds__(256) void rope2_k(float* __restrict__ qkv,
                                               const float* __restrict__ cosb, const float* __restrict__ sinb){
    int idx = blockIdx.x*256 + threadIdx.x;
    int t = idx / 640;
    int r = idx - t*640;
    int hs = r >> 5, tp = r & 31;
    int s = t & (S_LEN-1);
    float c  = cosb[s*32+tp];
    float sn = sinb[s*32+tp];
    float* base;
    if (hs < 16) base = qkv + (size_t)t*NQKV + hs*64 + 2*tp;
    else         base = qkv + (size_t)t*NQKV + 1024 + (hs-16)*64 + 2*tp;
    float2 v = *(float2*)base;
    *(float2*)base = make_float2(v.x*c - v.y*sn, v.x*sn + v.y*c);
}

// ======== attention on packed qkv -> combined hi/lo output ========
__global__ __launch_bounds__(64) void attn2c_k(const float* __restrict__ qkv,
                                               short* __restrict__ oc){
    const int l = threadIdx.x;
    const int bs = blockIdx.x;
    const int h = blockIdx.y, hk = h >> 2;
    const int sq = bs & (S_LEN-1);
    __shared__ float qs[64];
    __shared__ float ps[65];
    qs[l] = qkv[(size_t)bs*NQKV + h*64 + l];
    __syncthreads();
    const int j0 = (sq - WIN_C) > 0 ? (sq - WIN_C) : 0;
    const int nk = sq - j0 + 1;
    const int tokbase = bs - sq;
    float sc[2] = {-1e9f, -1e9f};
    #pragma unroll
    for (int it = 0; it < 2; ++it){
        int jj = l + it*64;
        if (jj < nk){
            const float* kp = qkv + (size_t)(tokbase + j0 + jj)*NQKV + 1024 + hk*64;
            float d = 0.f;
            #pragma unroll
            for (int c = 0; c < 16; ++c){
                float4 kv = *(const float4*)(kp + c*4);
                d += qs[c*4+0]*kv.x + qs[c*4+1]*kv.y + qs[c*4+2]*kv.z + qs[c*4+3]*kv.w;
            }
            sc[it] = d*0.125f;
        }
    }
    float m = fmaxf(sc[0], sc[1]);
    #pragma unroll
    for (int off=32; off; off>>=1) m = fmaxf(m, __shfl_xor(m, off));
    float e0 = (l      < nk) ? __expf(sc[0]-m) : 0.f;
    float e1 = (l + 64 < nk) ? __expf(sc[1]-m) : 0.f;
    float s = e0 + e1;
    #pragma unroll
    for (int off=32; off; off>>=1) s += __shfl_xor(s, off);
    float inv = 1.f/s;
    if (l      < nk) ps[l]    = e0*inv;
    if (l + 64 < nk) ps[l+64] = e1*inv;
    __syncthreads();
    float acc = 0.f;
    for (int jj = 0; jj < nk; ++jj)
        acc += ps[jj]*qkv[(size_t)(tokbase + j0 + jj)*NQKV + 1280 + hk*64 + l];
    SplitBF sp = splitf(acc);
    int k = h*64 + l;
    size_t base = (size_t)bs*K2C + (k>>5)*64 + (k&31);
    oc[base] = sp.hi; oc[base + 32] = sp.lo;
}

// ================= router (f32) =================
__global__ __launch_bounds__(64) void router_k(const float* __restrict__ h2f, const float* __restrict__ rw,
                                               int* __restrict__ lists, float* __restrict__ wl,
                                               int* __restrict__ cnt, float* __restrict__ psum){
    const int t = blockIdx.x, l = threadIdx.x;
    float lg[8] = {0,0,0,0,0,0,0,0};
    for (int c = 0; c < 16; ++c){
        int kidx = l + c*64;
        float x = h2f[(size_t)t*HID_C + kidx];
        float4 w0 = *(const float4*)(rw + (size_t)kidx*8);
        float4 w1 = *(const float4*)(rw + (size_t)kidx*8 + 4);
        lg[0] += x*w0.x; lg[1] += x*w0.y; lg[2] += x*w0.z; lg[3] += x*w0.w;
        lg[4] += x*w1.x; lg[5] += x*w1.y; lg[6] += x*w1.z; lg[7] += x*w1.w;
    }
    #pragma unroll
    for (int e = 0; e < 8; ++e)
        #pragma unroll
        for (int off=32; off; off>>=1) lg[e] += __shfl_xor(lg[e], off);
    if (l == 0){
        float m = lg[0];
        #pragma unroll
        for (int e = 1; e < 8; ++e) m = fmaxf(m, lg[e]);
        float p[8]; float s = 0.f;
        #pragma unroll
        for (int e = 0; e < 8; ++e){ p[e] = __expf(lg[e]-m); s += p[e]; }
        float invs = 1.f/s;
        #pragma unroll
        for (int e = 0; e < 8; ++e){ p[e] *= invs; atomicAdd(&psum[e], p[e]); }
        float best = -1e30f, sec = -1e30f; int bi = 0, si = 0;
        #pragma unroll
        for (int e = 0; e < 8; ++e){
            float pv = p[e];
            if (pv > best){ sec = best; si = bi; best = pv; bi = e; }
            else if (pv > sec){ sec = pv; si = e; }
        }
        float wsum = best + sec + 1e-9f;
        int s0 = atomicAdd(&cnt[bi], 1);
        lists[bi*CAP + s0] = t; wl[bi*CAP + s0] = best/wsum;
        int s1 = atomicAdd(&cnt[si], 1);
        lists[si*CAP + s1] = t; wl[si*CAP + s1] = sec/wsum;
    }
}

__global__ void finalize_k(const int* __restrict__ cnt, const float* __restrict__ psum,
                           int* __restrict__ offs, float* __restrict__ out){
    if (threadIdx.x == 0 && blockIdx.x == 0){
        int o = 0; float loss = 0.f;
        for (int e = 0; e < 8; ++e){
            offs[e] = o; o += cnt[e];
            loss += (psum[e]*(1.0f/NTOK)) * ((float)cnt[e]*(1.0f/NTOK));
        }
        offs[8] = o;
        out[OUT0_N] = loss * (float)E_C * 0.01f;
    }
}

// ============ MoE gate/up: global_load_lds staging, BN=64, BK=64 ============
__global__ __launch_bounds__(256) void moe1g_k(const short* __restrict__ h2b,
                                               const short* __restrict__ gate_t,
                                               const short* __restrict__ up_t,
                                               bf16* __restrict__ inter,
                                               const int* __restrict__ lists,
                                               const int* __restrict__ cnt,
                                               const int* __restrict__ offs){
    const int e = blockIdx.z;
    const int ne = cnt[e];
    const int bm0 = blockIdx.x*128;
    if (bm0 >= ne) return;
    const int bn0 = blockIdx.y*64;
    __shared__ __align__(16) short lA[128*64];
    __shared__ __align__(16) short lG[64*64];
    __shared__ __align__(16) short lU[64*64];
    const int tid = threadIdx.x;
    const int l = tid & 63, w = tid >> 6, wr = w >> 1, wc = w & 1;
    const int lr = l >> 3, lc8 = (l & 7)*8;
    const short* Gb = gate_t + (size_t)e*INTER_C*HID_C;
    const short* Ub = up_t   + (size_t)e*INTER_C*HID_C;
    // hoist gathered token rows (clamped; OOB rows never stored)
    int tokA[4];
    #pragma unroll
    for (int j = 0; j < 4; ++j){
        int slot = bm0 + w*32 + j*8 + lr;
        if (slot >= ne) slot = ne - 1;
        tokA[j] = lists[e*CAP + slot];
    }
    f32x4 ag[4][2] = {}; f32x4 au[4][2] = {};
    for (int kt = 0; kt < 16; ++kt){
        #pragma unroll
        for (int j = 0; j < 4; ++j)
            gload16(h2b + (size_t)tokA[j]*HID_C + kt*64 + lc8, &lA[(w*32 + j*8)*64]);
        #pragma unroll
        for (int j = 0; j < 2; ++j){
            int n = w*16 + j*8 + lr;
            gload16(Gb + (size_t)(bn0 + n)*HID_C + kt*64 + lc8, &lG[(w*16 + j*8)*64]);
            gload16(Ub + (size_t)(bn0 + n)*HID_C + kt*64 + lc8, &lU[(w*16 + j*8)*64]);
        }
        __syncthreads();
        #pragma unroll
        for (int kk = 0; kk < 64; kk += 32){
            s16x8 af[4], bg[2], bu[2];
            #pragma unroll
            for (int mi = 0; mi < 4; ++mi)
                af[mi] = *(const s16x8*)(&lA[(wr*64 + mi*16 + (l&15))*64 + kk + (l>>4)*8]);
            #pragma unroll
            for (int ni = 0; ni < 2; ++ni){
                int n = wc*32 + ni*16 + (l&15);
                bg[ni] = *(const s16x8*)(&lG[n*64 + kk + (l>>4)*8]);
                bu[ni] = *(const s16x8*)(&lU[n*64 + kk + (l>>4)*8]);
            }
            #pragma unroll
            for (int mi = 0; mi < 4; ++mi)
                #pragma unroll
                for (int ni = 0; ni < 2; ++ni){
                    ag[mi][ni] = __builtin_amdgcn_mfma_f32_16x16x32_bf16(af[mi], bg[ni], ag[mi][ni], 0,0,0);
                    au[mi][ni] = __builtin_amdgcn_mfma_f32_16x16x32_bf16(af[mi], bu[ni], au[mi][ni], 0,0,0);
                }
        }
        __syncthreads();
    }
    const int obase = offs[e];
    #pragma unroll
    for (int mi = 0; mi < 4; ++mi)
        #pragma unroll
        for (int ni = 0; ni < 2; ++ni)
            #pragma unroll
            for (int rr = 0; rr < 4; ++rr){
                int slot = bm0 + wr*64 + mi*16 + (l>>4)*4 + rr;
                if (slot < ne){
                    int col = bn0 + wc*32 + ni*16 + (l&15);
                    float g = ag[mi][ni][rr], uu = au[mi][ni][rr];
                    float val = (g/(1.f+__expf(-g)))*uu;
                    inter[(size_t)(obase+slot)*INTER_C + col] = f2b(val);
                }
            }
}

// ============ MoE down: global_load_lds staging, BN=128, BK=64 ============
__global__ __launch_bounds__(256) void moe2g_k(const bf16* __restrict__ inter,
                                               const short* __restrict__ down_t,
                                               float* __restrict__ hres,
                                               const float* __restrict__ wl,
                                               const int* __restrict__ lists,
                                               const int* __restrict__ cnt,
                                               const int* __restrict__ offs){
    const int e = blockIdx.z;
    const int ne = cnt[e];
    const int bm0 = blockIdx.x*128;
    if (bm0 >= ne) return;
    const int bn0 = blockIdx.y*128;
    __shared__ __align__(16) short lA[128*64];
    __shared__ __align__(16) short lB[128*64];
    const int tid = threadIdx.x;
    const int l = tid & 63, w = tid >> 6, wr = w >> 1, wc = w & 1;
    const int lr = l >> 3, lc8 = (l & 7)*8;
    const int obase = offs[e];
    const short* Db = down_t + (size_t)e*HID_C*INTER_C;
    const short* As = (const short*)inter;
    int rowA[4];
    #pragma unroll
    for (int j = 0; j < 4; ++j){
        int slot = bm0 + w*32 + j*8 + lr;
        if (slot >= ne) slot = ne - 1;
        rowA[j] = obase + slot;
    }
    f32x4 acc[4][4] = {};
    for (int kt = 0; kt < 44; ++kt){
        #pragma unroll
        for (int j = 0; j < 4; ++j){
            gload16(As + (size_t)rowA[j]*INTER_C + kt*64 + lc8, &lA[(w*32 + j*8)*64]);
            int n = w*32 + j*8 + lr;
            gload16(Db + (size_t)(bn0 + n)*INTER_C + kt*64 + lc8, &lB[(w*32 + j*8)*64]);
        }
        __syncthreads();
        #pragma unroll
        for (int kk = 0; kk < 64; kk += 32){
            s16x8 af[4], bfr[4];
            #pragma unroll
            for (int mi = 0; mi < 4; ++mi)
                af[mi] = *(const s16x8*)(&lA[(wr*64 + mi*16 + (l&15))*64 + kk + (l>>4)*8]);
            #pragma unroll
            for (int ni = 0; ni < 4; ++ni){
                int n = wc*64 + ni*16 + (l&15);
                bfr[ni] = *(const s16x8*)(&lB[n*64 + kk + (l>>4)*8]);
            }
            #pragma unroll
            for (int mi = 0; mi < 4; ++mi)
                #pragma unroll
                for (int ni = 0; ni < 4; ++ni)
                    acc[mi][ni] = __builtin_amdgcn_mfma_f32_16x16x32_bf16(af[mi], bfr[ni], acc[mi][ni], 0,0,0);
        }
        __syncthreads();
    }
    #pragma unroll
    for (int mi = 0; mi < 4; ++mi)
        #pragma unroll
        for (int ni = 0; ni < 4; ++ni)
            #pragma unroll
            for (int rr = 0; rr < 4; ++rr){
                int slot = bm0 + wr*64 + mi*16 + (l>>4)*4 + rr;
                if (slot < ne){
                    int col = bn0 + wc*64 + ni*16 + (l&15);
                    int tok = lists[e*CAP + slot];
                    float wgt = wl[e*CAP + slot];
                    atomicAdd(&hres[(size_t)tok*HID_C + col], acc[mi][ni][rr]*wgt);
                }
            }
}

__global__ __launch_bounds__(256) void final_k(const float* __restrict__ hres,
                                               float* __restrict__ out){
    const int t = blockIdx.x, c = threadIdx.x*4;
    float4 hv = *(const float4*)(hres + (size_t)t*HID_C + c);
    *(float4*)(out + (size_t)t*HID_C + c) = hv;
}

// ======================= FALLBACK PATH (round-5, ws-lean) =======================
template<bool ALSO_BF16>
__global__ __launch_bounds__(256) void rmsnorm_f(const float* __restrict__ xin, const float* __restrict__ w,
                                                 float* __restrict__ outf, bf16* __restrict__ outb){
    const int t = blockIdx.x, tid = threadIdx.x;
    float4 v = *(const float4*)(xin + (size_t)t*HID_C + tid*4);
    float x[4] = {v.x, v.y, v.z, v.w};
    float s = x[0]*x[0]+x[1]*x[1]+x[2]*x[2]+x[3]*x[3];
    #pragma unroll
    for (int off=32; off; off>>=1) s += __shfl_xor(s, off);
    __shared__ float red[4];
    if ((tid&63)==0) red[tid>>6] = s;
    __syncthreads();
    float tot = red[0]+red[1]+red[2]+red[3];
    float sc = rsqrtf(tot*(1.0f/HID_C) + 1e-8f);
    float4 wv = *(const float4*)(w + tid*4);
    float o[4] = { x[0]*sc*wv.x, x[1]*sc*wv.y, x[2]*sc*wv.z, x[3]*sc*wv.w };
    *(float4*)(outf + (size_t)t*HID_C + tid*4) = make_float4(o[0],o[1],o[2],o[3]);
    if (ALSO_BF16){
        __align__(8) bf16 tmp[4] = { f2b(o[0]), f2b(o[1]), f2b(o[2]), f2b(o[3]) };
        *(uint2*)(outb + (size_t)t*HID_C + tid*4) = *(uint2*)tmp;
    }
}

template<bool RESID>
__global__ __launch_bounds__(256) void sgemm_f(const float* __restrict__ A, const float* __restrict__ B,
                                               float* __restrict__ C, const float* __restrict__ resid,
                                               int N, int K){
    __shared__ __align__(16) short lAh[128*40];
    __shared__ __align__(16) short lAl[128*40];
    __shared__ __align__(16) short lBh[128*40];
    __shared__ __align__(16) short lBl[128*40];
    const int tid = threadIdx.x;
    const int bm0 = blockIdx.x*128, bn0 = blockIdx.y*128;
    const int l = tid & 63, w = tid >> 6, wr = w >> 1, wc = w & 1;
    f32x4 acc[4][4] = {};
    for (int kt = 0; kt < K/32; ++kt){
        #pragma unroll
        for (int i = 0; i < 4; ++i){
            int u = tid + i*256;
            int r = u >> 3, c4 = (u & 7)*4;
            float4 v = *(const float4*)(A + (size_t)(bm0+r)*K + kt*32 + c4);
            SplitBF s0 = splitf(v.x), s1 = splitf(v.y), s2 = splitf(v.z), s3 = splitf(v.w);
            __align__(8) short hv[4] = { s0.hi, s1.hi, s2.hi, s3.hi };
            __align__(8) short lv[4] = { s0.lo, s1.lo, s2.lo, s3.lo };
            *(uint2*)(&lAh[r*40 + c4]) = *(uint2*)hv;
            *(uint2*)(&lAl[r*40 + c4]) = *(uint2*)lv;
        }
        #pragma unroll
        for (int i = 0; i < 4; ++i){
            int u = tid + i*256;
            int k = u >> 5, n0 = (u & 31)*4;
            float4 v = *(const float4*)(B + (size_t)(kt*32 + k)*N + bn0 + n0);
            SplitBF s0 = splitf(v.x), s1 = splitf(v.y), s2 = splitf(v.z), s3 = splitf(v.w);
            lBh[(n0+0)*40+k]=s0.hi; lBh[(n0+1)*40+k]=s1.hi; lBh[(n0+2)*40+k]=s2.hi; lBh[(n0+3)*40+k]=s3.hi;
            lBl[(n0+0)*40+k]=s0.lo; lBl[(n0+1)*40+k]=s1.lo; lBl[(n0+2)*40+k]=s2.lo; lBl[(n0+3)*40+k]=s3.lo;
        }
        __syncthreads();
        s16x8 ah[4], al[4], bh[4], bl[4];
        #pragma unroll
        for (int mi = 0; mi < 4; ++mi){
            int r = wr*64 + mi*16 + (l&15);
            ah[mi] = *(const s16x8*)(&lAh[r*40 + (l>>4)*8]);
            al[mi] = *(const s16x8*)(&lAl[r*40 + (l>>4)*8]);
        }
        #pragma unroll
        for (int ni = 0; ni < 4; ++ni){
            int n = wc*64 + ni*16 + (l&15);
            bh[ni] = *(const s16x8*)(&lBh[n*40 + (l>>4)*8]);
            bl[ni] = *(const s16x8*)(&lBl[n*40 + (l>>4)*8]);
        }
        #pragma unroll
        for (int mi = 0; mi < 4; ++mi)
            #pragma unroll
            for (int ni = 0; ni < 4; ++ni){
                acc[mi][ni] = __builtin_amdgcn_mfma_f32_16x16x32_bf16(ah[mi], bh[ni], acc[mi][ni], 0,0,0);
                acc[mi][ni] = __builtin_amdgcn_mfma_f32_16x16x32_bf16(ah[mi], bl[ni], acc[mi][ni], 0,0,0);
                acc[mi][ni] = __builtin_amdgcn_mfma_f32_16x16x32_bf16(al[mi], bh[ni], acc[mi][ni], 0,0,0);
            }
        __syncthreads();
    }
    #pragma unroll
    for (int mi = 0; mi < 4; ++mi)
        #pragma unroll
        for (int ni = 0; ni < 4; ++ni)
            #pragma unroll
            for (int rr = 0; rr < 4; ++rr){
                int row = bm0 + wr*64 + mi*16 + (l>>4)*4 + rr;
                int col = bn0 + wc*64 + ni*16 + (l&15);
                float vv = acc[mi][ni][rr];
                if (RESID) vv += resid[(size_t)row*N + col];
                C[(size_t)row*N + col] = vv;
            }
}

__global__ __launch_bounds__(256) void rope_f(float* __restrict__ qb, float* __restrict__ kb,
                                              const float* __restrict__ cosb, const float* __restrict__ sinb){
    int idx = blockIdx.x*256 + threadIdx.x;
    int t = idx / 640;
    int r = idx - t*640;
    int hs = r >> 5, tp = r & 31;
    int s = t & (S_LEN-1);
    float c  = cosb[s*32+tp];
    float sn = sinb[s*32+tp];
    float* base;
    if (hs < 16) base = qb + (size_t)t*1024 + hs*64 + 2*tp;
    else         base = kb + (size_t)t*256 + (hs-16)*64 + 2*tp;
    float2 v = *(float2*)base;
    *(float2*)base = make_float2(v.x*c - v.y*sn, v.x*sn + v.y*c);
}

__global__ __launch_bounds__(64) void attn_f(const float* __restrict__ qb, const float* __restrict__ kb,
                                             const float* __restrict__ vb, float* __restrict__ ob){
    const int l = threadIdx.x;
    const int bs = blockIdx.x;
    const int h = blockIdx.y, hk = h >> 2;
    const int sq = bs & (S_LEN-1);
    __shared__ float qs[64];
    __shared__ float ps[65];
    qs[l] = qb[(size_t)bs*1024 + h*64 + l];
    __syncthreads();
    const int j0 = (sq - WIN_C) > 0 ? (sq - WIN_C) : 0;
    const int nk = sq - j0 + 1;
    const int tokbase = bs - sq;
    float sc[2] = {-1e9f, -1e9f};
    #pragma unroll
    for (int it = 0; it < 2; ++it){
        int jj = l + it*64;
        if (jj < nk){
            const float* kp = kb + (size_t)(tokbase + j0 + jj)*256 + hk*64;
            float d = 0.f;
            #pragma unroll
            for (int c = 0; c < 16; ++c){
                float4 kv = *(const float4*)(kp + c*4);
                d += qs[c*4+0]*kv.x + qs[c*4+1]*kv.y + qs[c*4+2]*kv.z + qs[c*4+3]*kv.w;
            }
            sc[it] = d*0.125f;
        }
    }
    float m = fmaxf(sc[0], sc[1]);
    #pragma unroll
    for (int off=32; off; off>>=1) m = fmaxf(m, __shfl_xor(m, off));
    float e0 = (l      < nk) ? __expf(sc[0]-m) : 0.f;
    float e1 = (l + 64 < nk) ? __expf(sc[1]-m) : 0.f;
    float s = e0 + e1;
    #pragma unroll
    for (int off=32; off; off>>=1) s += __shfl_xor(s, off);
    float inv = 1.f/s;
    if (l      < nk) ps[l]    = e0*inv;
    if (l + 64 < nk) ps[l+64] = e1*inv;
    __syncthreads();
    float acc = 0.f;
    for (int jj = 0; jj < nk; ++jj)
        acc += ps[jj]*vb[(size_t)(tokbase + j0 + jj)*256 + hk*64 + l];
    ob[(size_t)bs*1024 + h*64 + l] = acc;
}

__global__ __launch_bounds__(256) void moe_mlp1_f(const bf16* __restrict__ h2b,
                                                  const float* __restrict__ gateW,
                                                  const float* __restrict__ upW,
                                                  bf16* __restrict__ inter,
                                                  const int* __restrict__ lists,
                                                  const int* __restrict__ cnt,
                                                  const int* __restrict__ offs){
    const int e = blockIdx.z;
    const int ne = cnt[e];
    const int bm0 = blockIdx.x*128;
    if (bm0 >= ne) return;
    const int bn0 = blockIdx.y*64;
    __shared__ __align__(16) short lA[128*72];
    __shared__ __align__(16) short lG[64*72];
    __shared__ __align__(16) short lU[64*72];
    const int tid = threadIdx.x;
    const int l = tid & 63, w = tid >> 6, wr = w >> 1, wc = w & 1;
    const size_t ebase = (size_t)e*HID_C*INTER_C;
    f32x4 ag[4][2] = {}; f32x4 au[4][2] = {};
    for (int kt = 0; kt < HID_C/64; ++kt){
        #pragma unroll
        for (int i = 0; i < 4; ++i){
            int u = tid + i*256;
            int r = u >> 3, cu = u & 7;
            int slot = bm0 + r;
            s16x8 v = {};
            if (slot < ne){
                int tok = lists[e*CAP + slot];
                v = *(const s16x8*)((const short*)h2b + (size_t)tok*HID_C + kt*64 + cu*8);
            }
            *(s16x8*)(&lA[r*72 + cu*8]) = v;
        }
        #pragma unroll
        for (int i = 0; i < 2; ++i){
            int u = tid + i*256;
            int k = u >> 3, n0 = (u & 7)*8;
            size_t gidx = ebase + (size_t)(kt*64 + k)*INTER_C + bn0 + n0;
            const float* gp = gateW + gidx;
            const float* up = upW + gidx;
            float4 ga = *(const float4*)gp, gb = *(const float4*)(gp+4);
            float4 ua = *(const float4*)up, ub = *(const float4*)(up+4);
            lG[(n0+0)*72+k]=f2bs(ga.x); lG[(n0+1)*72+k]=f2bs(ga.y); lG[(n0+2)*72+k]=f2bs(ga.z); lG[(n0+3)*72+k]=f2bs(ga.w);
            lG[(n0+4)*72+k]=f2bs(gb.x); lG[(n0+5)*72+k]=f2bs(gb.y); lG[(n0+6)*72+k]=f2bs(gb.z); lG[(n0+7)*72+k]=f2bs(gb.w);
            lU[(n0+0)*72+k]=f2bs(ua.x); lU[(n0+1)*72+k]=f2bs(ua.y); lU[(n0+2)*72+k]=f2bs(ua.z); lU[(n0+3)*72+k]=f2bs(ua.w);
            lU[(n0+4)*72+k]=f2bs(ub.x); lU[(n0+5)*72+k]=f2bs(ub.y); lU[(n0+6)*72+k]=f2bs(ub.z); lU[(n0+7)*72+k]=f2bs(ub.w);
        }
        __syncthreads();
        #pragma unroll
        for (int kk = 0; kk < 64; kk += 32){
            s16x8 af[4], bg[2], bu[2];
            #pragma unroll
            for (int mi = 0; mi < 4; ++mi)
                af[mi] = *(const s16x8*)(&lA[(wr*64 + mi*16 + (l&15))*72 + kk + (l>>4)*8]);
            #pragma unroll
            for (int ni = 0; ni < 2; ++ni){
                int n = wc*32 + ni*16 + (l&15);
                bg[ni] = *(const s16x8*)(&lG[n*72 + kk + (l>>4)*8]);
                bu[ni] = *(const s16x8*)(&lU[n*72 + kk + (l>>4)*8]);
            }
            #pragma unroll
            for (int mi = 0; mi < 4; ++mi)
                #pragma unroll
                for (int ni = 0; ni < 2; ++ni){
                    ag[mi][ni] = __builtin_amdgcn_mfma_f32_16x16x32_bf16(af[mi], bg[ni], ag[mi][ni], 0,0,0);
                    au[mi][ni] = __builtin_amdgcn_mfma_f32_16x16x32_bf16(af[mi], bu[ni], au[mi][ni], 0,0,0);
                }
        }
        __syncthreads();
    }
    const int obase = offs[e];
    #pragma unroll
    for (int mi = 0; mi < 4; ++mi)
        #pragma unroll
        for (int ni = 0; ni < 2; ++ni)
            #pragma unroll
            for (int rr = 0; rr < 4; ++rr){
                int slot = bm0 + wr*64 + mi*16 + (l>>4)*4 + rr;
                if (slot < ne){
                    int col = bn0 + wc*32 + ni*16 + (l&15);
                    float g = ag[mi][ni][rr], uu = au[mi][ni][rr];
                    float val = (g/(1.f+__expf(-g)))*uu;
                    inter[(size_t)(obase+slot)*INTER_C + col] = f2b(val);
                }
            }
}

__global__ __launch_bounds__(256) void moe_mlp2_f(const bf16* __restrict__ inter,
                                                  const float* __restrict__ downW,
                                                  float* __restrict__ hres,
                                                  const float* __restrict__ wl,
                                                  const int* __restrict__ lists,
                                                  const int* __restrict__ cnt,
                                                  const int* __restrict__ offs){
    const int e = blockIdx.z;
    const int ne = cnt[e];
    const int bm0 = blockIdx.x*128;
    if (bm0 >= ne) return;
    const int bn0 = blockIdx.y*128;
    __shared__ __align__(16) short lA[128*72];
    __shared__ __align__(16) short lB[128*72];
    const int tid = threadIdx.x;
    const int l = tid & 63, w = tid >> 6, wr = w >> 1, wc = w & 1;
    const int obase = offs[e];
    const size_t ebase = (size_t)e*INTER_C*HID_C;
    f32x4 acc[4][4] = {};
    for (int kt = 0; kt < INTER_C/64; ++kt){
        #pragma unroll
        for (int i = 0; i < 4; ++i){
            int u = tid + i*256;
            int r = u >> 3, cu = u & 7;
            int slot = bm0 + r;
            s16x8 v = {};
            if (slot < ne)
                v = *(const s16x8*)((const short*)inter + (size_t)(obase + slot)*INTER_C + kt*64 + cu*8);
            *(s16x8*)(&lA[r*72 + cu*8]) = v;
        }
        #pragma unroll
        for (int i = 0; i < 4; ++i){
            int u = tid + i*256;
            int k = u >> 4, n0 = (u & 15)*8;
            const float* bp = downW + ebase + (size_t)(kt*64 + k)*HID_C + bn0 + n0;
            float4 a = *(const float4*)bp, b = *(const float4*)(bp+4);
            lB[(n0+0)*72+k]=f2bs(a.x); lB[(n0+1)*72+k]=f2bs(a.y); lB[(n0+2)*72+k]=f2bs(a.z); lB[(n0+3)*72+k]=f2bs(a.w);
            lB[(n0+4)*72+k]=f2bs(b.x); lB[(n0+5)*72+k]=f2bs(b.y); lB[(n0+6)*72+k]=f2bs(b.z); lB[(n0+7)*72+k]=f2bs(b.w);
        }
        __syncthreads();
        #pragma unroll
        for (int kk = 0; kk < 64; kk += 32){
            s16x8 af[4], bfr[4];
            #pragma unroll
            for (int mi = 0; mi < 4; ++mi)
                af[mi] = *(const s16x8*)(&lA[(wr*64 + mi*16 + (l&15))*72 + kk + (l>>4)*8]);
            #pragma unroll
            for (int ni = 0; ni < 4; ++ni){
                int n = wc*64 + ni*16 + (l&15);
                bfr[ni] = *(const s16x8*)(&lB[n*72 + kk + (l>>4)*8]);
            }
            #pragma unroll
            for (int mi = 0; mi < 4; ++mi)
                #pragma unroll
                for (int ni = 0; ni < 4; ++ni)
                    acc[mi][ni] = __builtin_amdgcn_mfma_f32_16x16x32_bf16(af[mi], bfr[ni], acc[mi][ni], 0,0,0);
        }
        __syncthreads();
    }
    #pragma unroll
    for (int mi = 0; mi < 4; ++mi)
        #pragma unroll
        for (int ni = 0; ni < 4; ++ni)
            #pragma unroll
            for (int rr = 0; rr < 4; ++rr){
                int slot = bm0 + wr*64 + mi*16 + (l>>4)*4 + rr;
                if (slot < ne){
                    int col = bn0 + wc*64 + ni*16 + (l&15);
                    int tok = lists[e*CAP + slot];
                    float wgt = wl[e*CAP + slot];
                    atomicAdd(&hres[(size_t)tok*HID_C + col], acc[mi][ni][rr]*wgt);
                }
            }
}

// ======================= HOST =======================
extern "C" void kernel_launch(void* const* d_in, const int* in_sizes, int n_in,
                              void* d_out, int out_size, void* d_ws, size_t ws_size,
                              hipStream_t stream){
    const float* hidden  = (const float*)d_in[0];
    const float* fcos    = (const float*)d_in[1];
    const float* fsin    = (const float*)d_in[2];
    const float* wq      = (const float*)d_in[3];
    const float* wk      = (const float*)d_in[4];
    const float* wv      = (const float*)d_in[5];
    const float* wo      = (const float*)d_in[6];
    const float* routerw = (const float*)d_in[7];
    const float* gatew   = (const float*)d_in[8];
    const float* upw     = (const float*)d_in[9];
    const float* downw   = (const float*)d_in[10];
    const float* n1w     = (const float*)d_in[11];
    const float* n2w     = (const float*)d_in[12];

    char* p = (char*)d_ws;
    size_t off = 0;
    auto alloc = [&](size_t b)->void*{ void* r = p + off; off = (off + b + 255) & ~(size_t)255; return r; };

    // ---- big-path layout ----
    int*   cnt    = (int*)alloc(64);
    float* psum   = (float*)alloc(64);
    int*   offs   = (int*)alloc(64);
    int*   lists  = (int*)alloc((size_t)E_C*CAP*4);
    float* wl     = (float*)alloc((size_t)E_C*CAP*4);
    short* wqkv2  = (short*)alloc((size_t)NQKV*K2C*2);        // combined hi/lo
    short* wo2    = (short*)alloc((size_t)HID_C*K2C*2);
    short* gate_t = (short*)alloc((size_t)E_C*INTER_C*HID_C*2);
    short* up_t   = (short*)alloc((size_t)E_C*INTER_C*HID_C*2);
    short* down_t = (short*)alloc((size_t)E_C*HID_C*INTER_C*2);
    short* h1c    = (short*)alloc((size_t)NTOK*K2C*2);        // norm1 combined; reused as attn-out combined
    float* qkvf   = (float*)alloc((size_t)NTOK*NQKV*4);       // later h2f + h2b
    float* hres   = (float*)alloc((size_t)NTOK*HID_C*4);
    bf16*  inter  = (bf16*)alloc((size_t)2*NTOK*INTER_C*2);
    size_t need_big = off;

    if (ws_size >= need_big){
        short* oc  = h1c;
        float* h2f = qkvf;
        bf16*  h2b = (bf16*)(qkvf + (size_t)NTOK*HID_C);

        (void)hipMemsetAsync(cnt, 0, 64, stream);
        (void)hipMemsetAsync(psum, 0, 64, stream);

        // prepass transposes
        tsplit2_k<<<dim3(32,32), 256, 0, stream>>>(wq, wqkv2, 1024, 0);
        tsplit2_k<<<dim3(8,32),  256, 0, stream>>>(wk, wqkv2, 256, 1024);
        tsplit2_k<<<dim3(8,32),  256, 0, stream>>>(wv, wqkv2, 256, 1280);
        tsplit2_k<<<dim3(32,32), 256, 0, stream>>>(wo, wo2, 1024, 0);
        tbf16_k<<<dim3(88,32,8), 256, 0, stream>>>(gatew, gate_t, 1024, 2816);
        tbf16_k<<<dim3(88,32,8), 256, 0, stream>>>(upw,   up_t,   1024, 2816);
        tbf16_k<<<dim3(32,88,8), 256, 0, stream>>>(downw, down_t, 2816, 1024);

        rmsn1c_k<<<NTOK, 256, 0, stream>>>(hidden, n1w, h1c);
        sgemm3_k<false><<<dim3(32,12), 256, 0, stream>>>(h1c, wqkv2, qkvf, nullptr, NQKV);
        rope2_k<<<10240, 256, 0, stream>>>(qkvf, fcos, fsin);
        attn2c_k<<<dim3(NTOK,16), 64, 0, stream>>>(qkvf, oc);
        sgemm3_k<true><<<dim3(32,8), 256, 0, stream>>>(oc, wo2, hres, hidden, 1024);
        rmsn2_k<<<NTOK, 256, 0, stream>>>(hres, n2w, h2f, h2b);
        router_k<<<NTOK, 64, 0, stream>>>(h2f, routerw, lists, wl, cnt, psum);
        finalize_k<<<1, 64, 0, stream>>>(cnt, psum, offs, (float*)d_out);
        moe1g_k<<<dim3(32,44,8), 256, 0, stream>>>((const short*)h2b, gate_t, up_t, inter, lists, cnt, offs);
        moe2g_k<<<dim3(32,8,8), 256, 0, stream>>>(inter, down_t, hres, wl, lists, cnt, offs);
        final_k<<<NTOK, 256, 0, stream>>>(hres, (float*)d_out);
        return;
    }

    // ---- fallback (round-5) layout ----
    off = 0;
    cnt    = (int*)alloc(64);
    psum   = (float*)alloc(64);
    offs   = (int*)alloc(64);
    lists  = (int*)alloc((size_t)E_C*CAP*4);
    wl     = (float*)alloc((size_t)E_C*CAP*4);
    float* h1  = (float*)alloc((size_t)NTOK*HID_C*4);
    float* qb  = (float*)alloc((size_t)NTOK*HID_C*4);
    float* kb  = (float*)alloc((size_t)NTOK*256*4);
    float* vb  = (float*)alloc((size_t)NTOK*256*4);
    float* hresF = (float*)alloc((size_t)NTOK*HID_C*4);
    bf16*  h2bF  = (bf16*)alloc((size_t)NTOK*HID_C*2);
    bf16*  interF= (bf16*)alloc((size_t)2*NTOK*INTER_C*2);
    float* attnb = h1;
    float* h2fF  = qb;

    (void)hipMemsetAsync(cnt, 0, 64, stream);
    (void)hipMemsetAsync(psum, 0, 64, stream);

    rmsnorm_f<false><<<NTOK, 256, 0, stream>>>(hidden, n1w, h1, nullptr);
    sgemm_f<false><<<dim3(32, 8), 256, 0, stream>>>(h1, wq, qb, nullptr, 1024, 1024);
    sgemm_f<false><<<dim3(32, 2), 256, 0, stream>>>(h1, wk, kb, nullptr, 256, 1024);
    sgemm_f<false><<<dim3(32, 2), 256, 0, stream>>>(h1, wv, vb, nullptr, 256, 1024);
    rope_f<<<10240, 256, 0, stream>>>(qb, kb, fcos, fsin);
    attn_f<<<dim3(NTOK, 16), 64, 0, stream>>>(qb, kb, vb, attnb);
    sgemm_f<true><<<dim3(32, 8), 256, 0, stream>>>(attnb, wo, hresF, hidden, 1024, 1024);
    rmsnorm_f<true><<<NTOK, 256, 0, stream>>>(hresF, n2w, h2fF, h2bF);
    router_k<<<NTOK, 64, 0, stream>>>(h2fF, routerw, lists, wl, cnt, psum);
    finalize_k<<<1, 64, 0, stream>>>(cnt, psum, offs, (float*)d_out);
    moe_mlp1_f<<<dim3(32, 44, 8), 256, 0, stream>>>(h2bF, gatew, upw, interF, lists, cnt, offs);
    moe_mlp2_f<<<dim3(32, 8, 8), 256, 0, stream>>>(interF, downw, hresF, wl, lists, cnt, offs);
    final_k<<<NTOK, 256, 0, stream>>>(hresF, (float*)d_out);
}

// Round 9
// 1744.976 us; speedup vs baseline: 1.8504x; 1.0579x over previous
//
#include <hip/hip_runtime.h>
#include <hip/hip_bf16.h>
#include <math.h>

typedef short s16x8 __attribute__((ext_vector_type(8)));
typedef float f32x4 __attribute__((ext_vector_type(4)));
typedef __hip_bfloat16 bf16;

#define NTOK 4096
#define S_LEN 2048
#define HID_C 1024
#define E_C 8
#define INTER_C 2816
#define WIN_C 64
#define CAP 4096
#define NQKV 1536
#define K2C 2048
#define OUT0_N ((size_t)NTOK*HID_C)

#define AS1 __attribute__((address_space(1)))
#define AS3 __attribute__((address_space(3)))

static __device__ __forceinline__ void gload16(const void* g, void* l){
    __builtin_amdgcn_global_load_lds((AS1 void*)(g), (AS3 void*)(l), 16, 0, 0);
}

static __device__ __forceinline__ float b2f(bf16 v){ return __bfloat162float(v); }
static __device__ __forceinline__ bf16  f2b(float v){ return __float2bfloat16(v); }
static __device__ __forceinline__ short f2bs(float v){ bf16 h = __float2bfloat16(v); return *reinterpret_cast<short*>(&h); }
struct SplitBF { short hi; short lo; };
static __device__ __forceinline__ SplitBF splitf(float x){
    SplitBF r;
    bf16 bh = __float2bfloat16(x);
    r.hi = *reinterpret_cast<short*>(&bh);
    float rem = x - __bfloat162float(bh);
    bf16 bl = __float2bfloat16(rem);
    r.lo = *reinterpret_cast<short*>(&bl);
    return r;
}

// Swizzle convention: within each 64-short (128B) group of a row, logical
// 8-short chunk c is stored at physical chunk c ^ (row & 7).  gload16 stages
// rows linearly, so readers XOR the chunk index with (lds_row & 7).

// ============ PREPASS: f32 [1024][N] -> combined hi/lo [row_off+n][2048], swizzled ============
__global__ __launch_bounds__(256) void tsplit2s_k(const float* __restrict__ src,
                                                  short* __restrict__ dst,
                                                  int N, int row_off){
    __shared__ float tile[32][33];
    const int n0 = blockIdx.x*32, k0 = blockIdx.y*32;
    const int tx = threadIdx.x & 31, ty = threadIdx.x >> 5;
    #pragma unroll
    for (int i = 0; i < 4; ++i)
        tile[ty + i*8][tx] = src[(size_t)(k0 + ty + i*8)*N + n0 + tx];
    __syncthreads();
    const int g = k0 >> 5;                 // 64-short group index
    const int chH = tx >> 3, chL = 4 | (tx >> 3), off = tx & 7;
    #pragma unroll
    for (int i = 0; i < 4; ++i){
        int nn = ty + i*8;                 // key = nn&7 = ty
        SplitBF s = splitf(tile[tx][nn]);
        size_t rowb = (size_t)(row_off + n0 + nn)*K2C + g*64;
        dst[rowb + ((chH ^ ty)<<3) + off] = s.hi;
        dst[rowb + ((chL ^ ty)<<3) + off] = s.lo;
    }
}

// f32 [e][K][N] -> bf16 [e][N][K], swizzled
__global__ __launch_bounds__(256) void tbf16s_k(const float* __restrict__ src0,
                                                short* __restrict__ dst0, int K, int N){
    const int e = blockIdx.z;
    const float* src = src0 + (size_t)e*K*N;
    short* dst = dst0 + (size_t)e*N*K;
    __shared__ float tile[32][33];
    const int n0 = blockIdx.x*32, k0 = blockIdx.y*32;
    const int tx = threadIdx.x & 31, ty = threadIdx.x >> 5;
    #pragma unroll
    for (int i = 0; i < 4; ++i)
        tile[ty + i*8][tx] = src[(size_t)(k0 + ty + i*8)*N + n0 + tx];
    __syncthreads();
    const int grp  = k0 >> 6;
    const int half = (k0 & 32) >> 3;       // chunk base 0 or 4
    const int ch   = half + (tx >> 3), off = tx & 7;
    #pragma unroll
    for (int i = 0; i < 4; ++i){
        int nn = ty + i*8;                 // key = ty
        dst[(size_t)(n0 + nn)*K + grp*64 + ((ch ^ ty)<<3) + off] = f2bs(tile[tx][nn]);
    }
}

// ================= RMSNorm: f32 in -> combined hi/lo out (swizzled) =================
__global__ __launch_bounds__(256) void rmsn1c_k(const float* __restrict__ xin,
                                                const float* __restrict__ w,
                                                short* __restrict__ oc){
    const int t = blockIdx.x, tid = threadIdx.x;
    float4 v = *(const float4*)(xin + (size_t)t*HID_C + tid*4);
    float x[4] = {v.x, v.y, v.z, v.w};
    float s = x[0]*x[0]+x[1]*x[1]+x[2]*x[2]+x[3]*x[3];
    #pragma unroll
    for (int off=32; off; off>>=1) s += __shfl_xor(s, off);
    __shared__ float red[4];
    if ((tid&63)==0) red[tid>>6] = s;
    __syncthreads();
    float tot = red[0]+red[1]+red[2]+red[3];
    float sc = rsqrtf(tot*(1.0f/HID_C) + 1e-8f);
    float4 wv = *(const float4*)(w + tid*4);
    float o[4] = { x[0]*sc*wv.x, x[1]*sc*wv.y, x[2]*sc*wv.z, x[3]*sc*wv.w };
    __align__(8) short th[4], tl[4];
    #pragma unroll
    for (int i=0;i<4;++i){ SplitBF sp = splitf(o[i]); th[i]=sp.hi; tl[i]=sp.lo; }
    const int g = tid>>3, q = tid&7;
    const int ch = q>>1, sub = (q&1)*4, key = t&7;
    short* rowp = oc + (size_t)t*K2C + g*64;
    *(uint2*)(rowp + ((ch ^ key)<<3) + sub)      = *(uint2*)th;
    *(uint2*)(rowp + (((4|ch) ^ key)<<3) + sub)  = *(uint2*)tl;
}

// norm2: f32 in -> f32 out + bf16 out (linear; feeds gathered-A paths)
__global__ __launch_bounds__(256) void rmsn2_k(const float* __restrict__ xin,
                                               const float* __restrict__ w,
                                               float* __restrict__ outf, bf16* __restrict__ outb){
    const int t = blockIdx.x, tid = threadIdx.x;
    float4 v = *(const float4*)(xin + (size_t)t*HID_C + tid*4);
    float x[4] = {v.x, v.y, v.z, v.w};
    float s = x[0]*x[0]+x[1]*x[1]+x[2]*x[2]+x[3]*x[3];
    #pragma unroll
    for (int off=32; off; off>>=1) s += __shfl_xor(s, off);
    __shared__ float red[4];
    if ((tid&63)==0) red[tid>>6] = s;
    __syncthreads();
    float tot = red[0]+red[1]+red[2]+red[3];
    float sc = rsqrtf(tot*(1.0f/HID_C) + 1e-8f);
    float4 wv = *(const float4*)(w + tid*4);
    float o[4] = { x[0]*sc*wv.x, x[1]*sc*wv.y, x[2]*sc*wv.z, x[3]*sc*wv.w };
    *(float4*)(outf + (size_t)t*HID_C + tid*4) = make_float4(o[0],o[1],o[2],o[3]);
    __align__(8) bf16 tmp[4] = { f2b(o[0]), f2b(o[1]), f2b(o[2]), f2b(o[3]) };
    *(uint2*)(outb + (size_t)t*HID_C + tid*4) = *(uint2*)tmp;
}

// ============ split GEMM: dbuf gload16 + counted vmcnt + swizzled reads ============
template<bool RESID>
__global__ __launch_bounds__(256) void sgemm4_k(const short* __restrict__ A2,
                                                const short* __restrict__ B2,
                                                float* __restrict__ C, const float* __restrict__ resid,
                                                int N){
    __shared__ __align__(16) short lA[2][128*64];
    __shared__ __align__(16) short lB[2][128*64];
    const int tid = threadIdx.x;
    const int bm0 = blockIdx.x*128, bn0 = blockIdx.y*128;
    const int l = tid & 63, w = tid >> 6, wr = w >> 1, wc = w & 1;
    const int lr = l >> 3, lc8 = (l & 7)*8;
    f32x4 acc[4][4] = {};
    auto STAGE = [&](int buf, int kt){
        #pragma unroll
        for (int j = 0; j < 4; ++j){
            int row = w*32 + j*8 + lr;
            gload16(A2 + (size_t)(bm0 + row)*K2C + kt*64 + lc8, &lA[buf][(w*32 + j*8)*64]);
            gload16(B2 + (size_t)(bn0 + row)*K2C + kt*64 + lc8, &lB[buf][(w*32 + j*8)*64]);
        }
    };
    STAGE(0, 0);
    for (int kt = 0; kt < 32; ++kt){
        const int cur = kt & 1;
        if (kt + 1 < 32){
            STAGE(cur ^ 1, kt + 1);
            asm volatile("s_waitcnt vmcnt(8)" ::: "memory");
        } else {
            asm volatile("s_waitcnt vmcnt(0)" ::: "memory");
        }
        __builtin_amdgcn_s_barrier();
        __builtin_amdgcn_sched_barrier(0);
        s16x8 ah[4], al[4], bh[4], bl[4];
        #pragma unroll
        for (int mi = 0; mi < 4; ++mi){
            int r = wr*64 + mi*16 + (l&15);
            int key = r & 7;
            ah[mi] = *(const s16x8*)(&lA[cur][r*64 + (((l>>4) ^ key)<<3)]);
            al[mi] = *(const s16x8*)(&lA[cur][r*64 + (((4|(l>>4)) ^ key)<<3)]);
        }
        #pragma unroll
        for (int ni = 0; ni < 4; ++ni){
            int n = wc*64 + ni*16 + (l&15);
            int key = n & 7;
            bh[ni] = *(const s16x8*)(&lB[cur][n*64 + (((l>>4) ^ key)<<3)]);
            bl[ni] = *(const s16x8*)(&lB[cur][n*64 + (((4|(l>>4)) ^ key)<<3)]);
        }
        #pragma unroll
        for (int mi = 0; mi < 4; ++mi)
            #pragma unroll
            for (int ni = 0; ni < 4; ++ni){
                acc[mi][ni] = __builtin_amdgcn_mfma_f32_16x16x32_bf16(ah[mi], bh[ni], acc[mi][ni], 0,0,0);
                acc[mi][ni] = __builtin_amdgcn_mfma_f32_16x16x32_bf16(ah[mi], bl[ni], acc[mi][ni], 0,0,0);
                acc[mi][ni] = __builtin_amdgcn_mfma_f32_16x16x32_bf16(al[mi], bh[ni], acc[mi][ni], 0,0,0);
            }
        __builtin_amdgcn_s_barrier();
    }
    #pragma unroll
    for (int mi = 0; mi < 4; ++mi)
        #pragma unroll
        for (int ni = 0; ni < 4; ++ni)
            #pragma unroll
            for (int rr = 0; rr < 4; ++rr){
                int row = bm0 + wr*64 + mi*16 + (l>>4)*4 + rr;
                int col = bn0 + wc*64 + ni*16 + (l&15);
                float vv = acc[mi][ni][rr];
                if (RESID) vv += resid[(size_t)row*N + col];
                C[(size_t)row*N + col] = vv;
            }
}

// ================ RoPE on packed qkv f32 [tok][1536] ================
__global__ __launch_bounds__(256) void rope2_k(float* __restrict__ qkv,
                                               const float* __restrict__ cosb, const float* __restrict__ sinb){
    int idx = blockIdx.x*256 + threadIdx.x;
    int t = idx / 640;
    int r = idx - t*640;
    int hs = r >> 5, tp = r & 31;
    int s = t & (S_LEN-1);
    float c  = cosb[s*32+tp];
    float sn = sinb[s*32+tp];
    float* base;
    if (hs < 16) base = qkv + (size_t)t*NQKV + hs*64 + 2*tp;
    else         base = qkv + (size_t)t*NQKV + 1024 + (hs-16)*64 + 2*tp;
    float2 v = *(float2*)base;
    *(float2*)base = make_float2(v.x*c - v.y*sn, v.x*sn + v.y*c);
}

// ======== attention -> combined hi/lo output (swizzled for sgemm4 A) ========
__global__ __launch_bounds__(64) void attn2c_k(const float* __restrict__ qkv,
                                               short* __restrict__ oc){
    const int l = threadIdx.x;
    const int bs = blockIdx.x;
    const int h = blockIdx.y, hk = h >> 2;
    const int sq = bs & (S_LEN-1);
    __shared__ float qs[64];
    __shared__ float ps[65];
    qs[l] = qkv[(size_t)bs*NQKV + h*64 + l];
    __syncthreads();
    const int j0 = (sq - WIN_C) > 0 ? (sq - WIN_C) : 0;
    const int nk = sq - j0 + 1;
    const int tokbase = bs - sq;
    float sc[2] = {-1e9f, -1e9f};
    #pragma unroll
    for (int it = 0; it < 2; ++it){
        int jj = l + it*64;
        if (jj < nk){
            const float* kp = qkv + (size_t)(tokbase + j0 + jj)*NQKV + 1024 + hk*64;
            float d = 0.f;
            #pragma unroll
            for (int c = 0; c < 16; ++c){
                float4 kv = *(const float4*)(kp + c*4);
                d += qs[c*4+0]*kv.x + qs[c*4+1]*kv.y + qs[c*4+2]*kv.z + qs[c*4+3]*kv.w;
            }
            sc[it] = d*0.125f;
        }
    }
    float m = fmaxf(sc[0], sc[1]);
    #pragma unroll
    for (int off=32; off; off>>=1) m = fmaxf(m, __shfl_xor(m, off));
    float e0 = (l      < nk) ? __expf(sc[0]-m) : 0.f;
    float e1 = (l + 64 < nk) ? __expf(sc[1]-m) : 0.f;
    float s = e0 + e1;
    #pragma unroll
    for (int off=32; off; off>>=1) s += __shfl_xor(s, off);
    float inv = 1.f/s;
    if (l      < nk) ps[l]    = e0*inv;
    if (l + 64 < nk) ps[l+64] = e1*inv;
    __syncthreads();
    float acc = 0.f;
    for (int jj = 0; jj < nk; ++jj)
        acc += ps[jj]*qkv[(size_t)(tokbase + j0 + jj)*NQKV + 1280 + hk*64 + l];
    SplitBF sp = splitf(acc);
    const int k = h*64 + l;
    const int g = k>>5, ch = (k&31)>>3, off = k&7, key = bs&7;
    short* rowp = oc + (size_t)bs*K2C + g*64;
    rowp[((ch ^ key)<<3) + off]      = sp.hi;
    rowp[(((4|ch) ^ key)<<3) + off]  = sp.lo;
}

// ================= router (f32) =================
__global__ __launch_bounds__(64) void router_k(const float* __restrict__ h2f, const float* __restrict__ rw,
                                               int* __restrict__ lists, float* __restrict__ wl,
                                               int* __restrict__ cnt, float* __restrict__ psum){
    const int t = blockIdx.x, l = threadIdx.x;
    float lg[8] = {0,0,0,0,0,0,0,0};
    for (int c = 0; c < 16; ++c){
        int kidx = l + c*64;
        float x = h2f[(size_t)t*HID_C + kidx];
        float4 w0 = *(const float4*)(rw + (size_t)kidx*8);
        float4 w1 = *(const float4*)(rw + (size_t)kidx*8 + 4);
        lg[0] += x*w0.x; lg[1] += x*w0.y; lg[2] += x*w0.z; lg[3] += x*w0.w;
        lg[4] += x*w1.x; lg[5] += x*w1.y; lg[6] += x*w1.z; lg[7] += x*w1.w;
    }
    #pragma unroll
    for (int e = 0; e < 8; ++e)
        #pragma unroll
        for (int off=32; off; off>>=1) lg[e] += __shfl_xor(lg[e], off);
    if (l == 0){
        float m = lg[0];
        #pragma unroll
        for (int e = 1; e < 8; ++e) m = fmaxf(m, lg[e]);
        float p[8]; float s = 0.f;
        #pragma unroll
        for (int e = 0; e < 8; ++e){ p[e] = __expf(lg[e]-m); s += p[e]; }
        float invs = 1.f/s;
        #pragma unroll
        for (int e = 0; e < 8; ++e){ p[e] *= invs; atomicAdd(&psum[e], p[e]); }
        float best = -1e30f, sec = -1e30f; int bi = 0, si = 0;
        #pragma unroll
        for (int e = 0; e < 8; ++e){
            float pv = p[e];
            if (pv > best){ sec = best; si = bi; best = pv; bi = e; }
            else if (pv > sec){ sec = pv; si = e; }
        }
        float wsum = best + sec + 1e-9f;
        int s0 = atomicAdd(&cnt[bi], 1);
        lists[bi*CAP + s0] = t; wl[bi*CAP + s0] = best/wsum;
        int s1 = atomicAdd(&cnt[si], 1);
        lists[si*CAP + s1] = t; wl[si*CAP + s1] = sec/wsum;
    }
}

__global__ void finalize_k(const int* __restrict__ cnt, const float* __restrict__ psum,
                           int* __restrict__ offs, float* __restrict__ out){
    if (threadIdx.x == 0 && blockIdx.x == 0){
        int o = 0; float loss = 0.f;
        for (int e = 0; e < 8; ++e){
            offs[e] = o; o += cnt[e];
            loss += (psum[e]*(1.0f/NTOK)) * ((float)cnt[e]*(1.0f/NTOK));
        }
        offs[8] = o;
        out[OUT0_N] = loss * (float)E_C * 0.01f;
    }
}

// ============ MoE gate/up: dbuf gload16, swizzled weights, linear gathered A ============
__global__ __launch_bounds__(256) void moe1g2_k(const short* __restrict__ h2b,
                                                const short* __restrict__ gate_t,
                                                const short* __restrict__ up_t,
                                                bf16* __restrict__ inter,
                                                const int* __restrict__ lists,
                                                const int* __restrict__ cnt,
                                                const int* __restrict__ offs){
    const int e = blockIdx.z;
    const int ne = cnt[e];
    const int bm0 = blockIdx.x*128;
    if (bm0 >= ne) return;
    const int bn0 = blockIdx.y*64;
    __shared__ __align__(16) short lA[2][128*64];
    __shared__ __align__(16) short lG[2][64*64];
    __shared__ __align__(16) short lU[2][64*64];
    const int tid = threadIdx.x;
    const int l = tid & 63, w = tid >> 6, wr = w >> 1, wc = w & 1;
    const int lr = l >> 3, lc8 = (l & 7)*8;
    const short* Gb = gate_t + (size_t)e*INTER_C*HID_C;
    const short* Ub = up_t   + (size_t)e*INTER_C*HID_C;
    int tokA[4];
    #pragma unroll
    for (int j = 0; j < 4; ++j){
        int slot = bm0 + w*32 + j*8 + lr;
        if (slot >= ne) slot = ne - 1;
        tokA[j] = lists[e*CAP + slot];
    }
    auto STAGE = [&](int buf, int kt){
        #pragma unroll
        for (int j = 0; j < 4; ++j)
            gload16(h2b + (size_t)tokA[j]*HID_C + kt*64 + lc8, &lA[buf][(w*32 + j*8)*64]);
        #pragma unroll
        for (int j = 0; j < 2; ++j){
            int n = w*16 + j*8 + lr;
            gload16(Gb + (size_t)(bn0 + n)*HID_C + kt*64 + lc8, &lG[buf][(w*16 + j*8)*64]);
            gload16(Ub + (size_t)(bn0 + n)*HID_C + kt*64 + lc8, &lU[buf][(w*16 + j*8)*64]);
        }
    };
    f32x4 ag[4][2] = {}; f32x4 au[4][2] = {};
    STAGE(0, 0);
    for (int kt = 0; kt < 16; ++kt){
        const int cur = kt & 1;
        if (kt + 1 < 16){
            STAGE(cur ^ 1, kt + 1);
            asm volatile("s_waitcnt vmcnt(8)" ::: "memory");
        } else {
            asm volatile("s_waitcnt vmcnt(0)" ::: "memory");
        }
        __builtin_amdgcn_s_barrier();
        __builtin_amdgcn_sched_barrier(0);
        #pragma unroll
        for (int kk = 0; kk < 64; kk += 32){
            s16x8 af[4], bg[2], bu[2];
            #pragma unroll
            for (int mi = 0; mi < 4; ++mi)
                af[mi] = *(const s16x8*)(&lA[cur][(wr*64 + mi*16 + (l&15))*64 + kk + (l>>4)*8]);
            #pragma unroll
            for (int ni = 0; ni < 2; ++ni){
                int n = wc*32 + ni*16 + (l&15);
                int key = n & 7;
                int ch = (kk>>3) + (l>>4);
                bg[ni] = *(const s16x8*)(&lG[cur][n*64 + ((ch ^ key)<<3)]);
                bu[ni] = *(const s16x8*)(&lU[cur][n*64 + ((ch ^ key)<<3)]);
            }
            #pragma unroll
            for (int mi = 0; mi < 4; ++mi)
                #pragma unroll
                for (int ni = 0; ni < 2; ++ni){
                    ag[mi][ni] = __builtin_amdgcn_mfma_f32_16x16x32_bf16(af[mi], bg[ni], ag[mi][ni], 0,0,0);
                    au[mi][ni] = __builtin_amdgcn_mfma_f32_16x16x32_bf16(af[mi], bu[ni], au[mi][ni], 0,0,0);
                }
        }
        __builtin_amdgcn_s_barrier();
    }
    const int obase = offs[e];
    #pragma unroll
    for (int mi = 0; mi < 4; ++mi)
        #pragma unroll
        for (int ni = 0; ni < 2; ++ni)
            #pragma unroll
            for (int rr = 0; rr < 4; ++rr){
                int slot = bm0 + wr*64 + mi*16 + (l>>4)*4 + rr;
                if (slot < ne){
                    int col = bn0 + wc*32 + ni*16 + (l&15);
                    float g = ag[mi][ni][rr], uu = au[mi][ni][rr];
                    float val = (g/(1.f+__expf(-g)))*uu;
                    inter[(size_t)(obase+slot)*INTER_C + col] = f2b(val);
                }
            }
}

// ============ MoE down: dbuf gload16, swizzled weights, linear gathered A ============
__global__ __launch_bounds__(256) void moe2g2_k(const bf16* __restrict__ inter,
                                                const short* __restrict__ down_t,
                                                float* __restrict__ hres,
                                                const float* __restrict__ wl,
                                                const int* __restrict__ lists,
                                                const int* __restrict__ cnt,
                                                const int* __restrict__ offs){
    const int e = blockIdx.z;
    const int ne = cnt[e];
    const int bm0 = blockIdx.x*128;
    if (bm0 >= ne) return;
    const int bn0 = blockIdx.y*128;
    __shared__ __align__(16) short lA[2][128*64];
    __shared__ __align__(16) short lB[2][128*64];
    const int tid = threadIdx.x;
    const int l = tid & 63, w = tid >> 6, wr = w >> 1, wc = w & 1;
    const int lr = l >> 3, lc8 = (l & 7)*8;
    const int obase = offs[e];
    const short* Db = down_t + (size_t)e*HID_C*INTER_C;
    const short* As = (const short*)inter;
    int rowA[4];
    #pragma unroll
    for (int j = 0; j < 4; ++j){
        int slot = bm0 + w*32 + j*8 + lr;
        if (slot >= ne) slot = ne - 1;
        rowA[j] = obase + slot;
    }
    auto STAGE = [&](int buf, int kt){
        #pragma unroll
        for (int j = 0; j < 4; ++j){
            gload16(As + (size_t)rowA[j]*INTER_C + kt*64 + lc8, &lA[buf][(w*32 + j*8)*64]);
            int n = w*32 + j*8 + lr;
            gload16(Db + (size_t)(bn0 + n)*INTER_C + kt*64 + lc8, &lB[buf][(w*32 + j*8)*64]);
        }
    };
    f32x4 acc[4][4] = {};
    STAGE(0, 0);
    for (int kt = 0; kt < 44; ++kt){
        const int cur = kt & 1;
        if (kt + 1 < 44){
            STAGE(cur ^ 1, kt + 1);
            asm volatile("s_waitcnt vmcnt(8)" ::: "memory");
        } else {
            asm volatile("s_waitcnt vmcnt(0)" ::: "memory");
        }
        __builtin_amdgcn_s_barrier();
        __builtin_amdgcn_sched_barrier(0);
        #pragma unroll
        for (int kk = 0; kk < 64; kk += 32){
            s16x8 af[4], bfr[4];
            #pragma unroll
            for (int mi = 0; mi < 4; ++mi)
                af[mi] = *(const s16x8*)(&lA[cur][(wr*64 + mi*16 + (l&15))*64 + kk + (l>>4)*8]);
            #pragma unroll
            for (int ni = 0; ni < 4; ++ni){
                int n = wc*64 + ni*16 + (l&15);
                int key = n & 7;
                int ch = (kk>>3) + (l>>4);
                bfr[ni] = *(const s16x8*)(&lB[cur][n*64 + ((ch ^ key)<<3)]);
            }
            #pragma unroll
            for (int mi = 0; mi < 4; ++mi)
                #pragma unroll
                for (int ni = 0; ni < 4; ++ni)
                    acc[mi][ni] = __builtin_amdgcn_mfma_f32_16x16x32_bf16(af[mi], bfr[ni], acc[mi][ni], 0,0,0);
        }
        __builtin_amdgcn_s_barrier();
    }
    #pragma unroll
    for (int mi = 0; mi < 4; ++mi)
        #pragma unroll
        for (int ni = 0; ni < 4; ++ni)
            #pragma unroll
            for (int rr = 0; rr < 4; ++rr){
                int slot = bm0 + wr*64 + mi*16 + (l>>4)*4 + rr;
                if (slot < ne){
                    int col = bn0 + wc*64 + ni*16 + (l&15);
                    int tok = lists[e*CAP + slot];
                    float wgt = wl[e*CAP + slot];
                    atomicAdd(&hres[(size_t)tok*HID_C + col], acc[mi][ni][rr]*wgt);
                }
            }
}

__global__ __launch_bounds__(256) void final_k(const float* __restrict__ hres,
                                               float* __restrict__ out){
    const int t = blockIdx.x, c = threadIdx.x*4;
    float4 hv = *(const float4*)(hres + (size_t)t*HID_C + c);
    *(float4*)(out + (size_t)t*HID_C + c) = hv;
}

// ======================= FALLBACK PATH (round-5, ws-lean) =======================
template<bool ALSO_BF16>
__global__ __launch_bounds__(256) void rmsnorm_f(const float* __restrict__ xin, const float* __restrict__ w,
                                                 float* __restrict__ outf, bf16* __restrict__ outb){
    const int t = blockIdx.x, tid = threadIdx.x;
    float4 v = *(const float4*)(xin + (size_t)t*HID_C + tid*4);
    float x[4] = {v.x, v.y, v.z, v.w};
    float s = x[0]*x[0]+x[1]*x[1]+x[2]*x[2]+x[3]*x[3];
    #pragma unroll
    for (int off=32; off; off>>=1) s += __shfl_xor(s, off);
    __shared__ float red[4];
    if ((tid&63)==0) red[tid>>6] = s;
    __syncthreads();
    float tot = red[0]+red[1]+red[2]+red[3];
    float sc = rsqrtf(tot*(1.0f/HID_C) + 1e-8f);
    float4 wv = *(const float4*)(w + tid*4);
    float o[4] = { x[0]*sc*wv.x, x[1]*sc*wv.y, x[2]*sc*wv.z, x[3]*sc*wv.w };
    *(float4*)(outf + (size_t)t*HID_C + tid*4) = make_float4(o[0],o[1],o[2],o[3]);
    if (ALSO_BF16){
        __align__(8) bf16 tmp[4] = { f2b(o[0]), f2b(o[1]), f2b(o[2]), f2b(o[3]) };
        *(uint2*)(outb + (size_t)t*HID_C + tid*4) = *(uint2*)tmp;
    }
}

template<bool RESID>
__global__ __launch_bounds__(256) void sgemm_f(const float* __restrict__ A, const float* __restrict__ B,
                                               float* __restrict__ C, const float* __restrict__ resid,
                                               int N, int K){
    __shared__ __align__(16) short lAh[128*40];
    __shared__ __align__(16) short lAl[128*40];
    __shared__ __align__(16) short lBh[128*40];
    __shared__ __align__(16) short lBl[128*40];
    const int tid = threadIdx.x;
    const int bm0 = blockIdx.x*128, bn0 = blockIdx.y*128;
    const int l = tid & 63, w = tid >> 6, wr = w >> 1, wc = w & 1;
    f32x4 acc[4][4] = {};
    for (int kt = 0; kt < K/32; ++kt){
        #pragma unroll
        for (int i = 0; i < 4; ++i){
            int u = tid + i*256;
            int r = u >> 3, c4 = (u & 7)*4;
            float4 v = *(const float4*)(A + (size_t)(bm0+r)*K + kt*32 + c4);
            SplitBF s0 = splitf(v.x), s1 = splitf(v.y), s2 = splitf(v.z), s3 = splitf(v.w);
            __align__(8) short hv[4] = { s0.hi, s1.hi, s2.hi, s3.hi };
            __align__(8) short lv[4] = { s0.lo, s1.lo, s2.lo, s3.lo };
            *(uint2*)(&lAh[r*40 + c4]) = *(uint2*)hv;
            *(uint2*)(&lAl[r*40 + c4]) = *(uint2*)lv;
        }
        #pragma unroll
        for (int i = 0; i < 4; ++i){
            int u = tid + i*256;
            int k = u >> 5, n0 = (u & 31)*4;
            float4 v = *(const float4*)(B + (size_t)(kt*32 + k)*N + bn0 + n0);
            SplitBF s0 = splitf(v.x), s1 = splitf(v.y), s2 = splitf(v.z), s3 = splitf(v.w);
            lBh[(n0+0)*40+k]=s0.hi; lBh[(n0+1)*40+k]=s1.hi; lBh[(n0+2)*40+k]=s2.hi; lBh[(n0+3)*40+k]=s3.hi;
            lBl[(n0+0)*40+k]=s0.lo; lBl[(n0+1)*40+k]=s1.lo; lBl[(n0+2)*40+k]=s2.lo; lBl[(n0+3)*40+k]=s3.lo;
        }
        __syncthreads();
        s16x8 ah[4], al[4], bh[4], bl[4];
        #pragma unroll
        for (int mi = 0; mi < 4; ++mi){
            int r = wr*64 + mi*16 + (l&15);
            ah[mi] = *(const s16x8*)(&lAh[r*40 + (l>>4)*8]);
            al[mi] = *(const s16x8*)(&lAl[r*40 + (l>>4)*8]);
        }
        #pragma unroll
        for (int ni = 0; ni < 4; ++ni){
            int n = wc*64 + ni*16 + (l&15);
            bh[ni] = *(const s16x8*)(&lBh[n*40 + (l>>4)*8]);
            bl[ni] = *(const s16x8*)(&lBl[n*40 + (l>>4)*8]);
        }
        #pragma unroll
        for (int mi = 0; mi < 4; ++mi)
            #pragma unroll
            for (int ni = 0; ni < 4; ++ni){
                acc[mi][ni] = __builtin_amdgcn_mfma_f32_16x16x32_bf16(ah[mi], bh[ni], acc[mi][ni], 0,0,0);
                acc[mi][ni] = __builtin_amdgcn_mfma_f32_16x16x32_bf16(ah[mi], bl[ni], acc[mi][ni], 0,0,0);
                acc[mi][ni] = __builtin_amdgcn_mfma_f32_16x16x32_bf16(al[mi], bh[ni], acc[mi][ni], 0,0,0);
            }
        __syncthreads();
    }
    #pragma unroll
    for (int mi = 0; mi < 4; ++mi)
        #pragma unroll
        for (int ni = 0; ni < 4; ++ni)
            #pragma unroll
            for (int rr = 0; rr < 4; ++rr){
                int row = bm0 + wr*64 + mi*16 + (l>>4)*4 + rr;
                int col = bn0 + wc*64 + ni*16 + (l&15);
                float vv = acc[mi][ni][rr];
                if (RESID) vv += resid[(size_t)row*N + col];
                C[(size_t)row*N + col] = vv;
            }
}

__global__ __launch_bounds__(256) void rope_f(float* __restrict__ qb, float* __restrict__ kb,
                                              const float* __restrict__ cosb, const float* __restrict__ sinb){
    int idx = blockIdx.x*256 + threadIdx.x;
    int t = idx / 640;
    int r = idx - t*640;
    int hs = r >> 5, tp = r & 31;
    int s = t & (S_LEN-1);
    float c  = cosb[s*32+tp];
    float sn = sinb[s*32+tp];
    float* base;
    if (hs < 16) base = qb + (size_t)t*1024 + hs*64 + 2*tp;
    else         base = kb + (size_t)t*256 + (hs-16)*64 + 2*tp;
    float2 v = *(float2*)base;
    *(float2*)base = make_float2(v.x*c - v.y*sn, v.x*sn + v.y*c);
}

__global__ __launch_bounds__(64) void attn_f(const float* __restrict__ qb, const float* __restrict__ kb,
                                             const float* __restrict__ vb, float* __restrict__ ob){
    const int l = threadIdx.x;
    const int bs = blockIdx.x;
    const int h = blockIdx.y, hk = h >> 2;
    const int sq = bs & (S_LEN-1);
    __shared__ float qs[64];
    __shared__ float ps[65];
    qs[l] = qb[(size_t)bs*1024 + h*64 + l];
    __syncthreads();
    const int j0 = (sq - WIN_C) > 0 ? (sq - WIN_C) : 0;
    const int nk = sq - j0 + 1;
    const int tokbase = bs - sq;
    float sc[2] = {-1e9f, -1e9f};
    #pragma unroll
    for (int it = 0; it < 2; ++it){
        int jj = l + it*64;
        if (jj < nk){
            const float* kp = kb + (size_t)(tokbase + j0 + jj)*256 + hk*64;
            float d = 0.f;
            #pragma unroll
            for (int c = 0; c < 16; ++c){
                float4 kv = *(const float4*)(kp + c*4);
                d += qs[c*4+0]*kv.x + qs[c*4+1]*kv.y + qs[c*4+2]*kv.z + qs[c*4+3]*kv.w;
            }
            sc[it] = d*0.125f;
        }
    }
    float m = fmaxf(sc[0], sc[1]);
    #pragma unroll
    for (int off=32; off; off>>=1) m = fmaxf(m, __shfl_xor(m, off));
    float e0 = (l      < nk) ? __expf(sc[0]-m) : 0.f;
    float e1 = (l + 64 < nk) ? __expf(sc[1]-m) : 0.f;
    float s = e0 + e1;
    #pragma unroll
    for (int off=32; off; off>>=1) s += __shfl_xor(s, off);
    float inv = 1.f/s;
    if (l      < nk) ps[l]    = e0*inv;
    if (l + 64 < nk) ps[l+64] = e1*inv;
    __syncthreads();
    float acc = 0.f;
    for (int jj = 0; jj < nk; ++jj)
        acc += ps[jj]*vb[(size_t)(tokbase + j0 + jj)*256 + hk*64 + l];
    ob[(size_t)bs*1024 + h*64 + l] = acc;
}

__global__ __launch_bounds__(256) void moe_mlp1_f(const bf16* __restrict__ h2b,
                                                  const float* __restrict__ gateW,
                                                  const float* __restrict__ upW,
                                                  bf16* __restrict__ inter,
                                                  const int* __restrict__ lists,
                                                  const int* __restrict__ cnt,
                                                  const int* __restrict__ offs){
    const int e = blockIdx.z;
    const int ne = cnt[e];
    const int bm0 = blockIdx.x*128;
    if (bm0 >= ne) return;
    const int bn0 = blockIdx.y*64;
    __shared__ __align__(16) short lA[128*72];
    __shared__ __align__(16) short lG[64*72];
    __shared__ __align__(16) short lU[64*72];
    const int tid = threadIdx.x;
    const int l = tid & 63, w = tid >> 6, wr = w >> 1, wc = w & 1;
    const size_t ebase = (size_t)e*HID_C*INTER_C;
    f32x4 ag[4][2] = {}; f32x4 au[4][2] = {};
    for (int kt = 0; kt < HID_C/64; ++kt){
        #pragma unroll
        for (int i = 0; i < 4; ++i){
            int u = tid + i*256;
            int r = u >> 3, cu = u & 7;
            int slot = bm0 + r;
            s16x8 v = {};
            if (slot < ne){
                int tok = lists[e*CAP + slot];
                v = *(const s16x8*)((const short*)h2b + (size_t)tok*HID_C + kt*64 + cu*8);
            }
            *(s16x8*)(&lA[r*72 + cu*8]) = v;
        }
        #pragma unroll
        for (int i = 0; i < 2; ++i){
            int u = tid + i*256;
            int k = u >> 3, n0 = (u & 7)*8;
            size_t gidx = ebase + (size_t)(kt*64 + k)*INTER_C + bn0 + n0;
            const float* gp = gateW + gidx;
            const float* up = upW + gidx;
            float4 ga = *(const float4*)gp, gb = *(const float4*)(gp+4);
            float4 ua = *(const float4*)up, ub = *(const float4*)(up+4);
            lG[(n0+0)*72+k]=f2bs(ga.x); lG[(n0+1)*72+k]=f2bs(ga.y); lG[(n0+2)*72+k]=f2bs(ga.z); lG[(n0+3)*72+k]=f2bs(ga.w);
            lG[(n0+4)*72+k]=f2bs(gb.x); lG[(n0+5)*72+k]=f2bs(gb.y); lG[(n0+6)*72+k]=f2bs(gb.z); lG[(n0+7)*72+k]=f2bs(gb.w);
            lU[(n0+0)*72+k]=f2bs(ua.x); lU[(n0+1)*72+k]=f2bs(ua.y); lU[(n0+2)*72+k]=f2bs(ua.z); lU[(n0+3)*72+k]=f2bs(ua.w);
            lU[(n0+4)*72+k]=f2bs(ub.x); lU[(n0+5)*72+k]=f2bs(ub.y); lU[(n0+6)*72+k]=f2bs(ub.z); lU[(n0+7)*72+k]=f2bs(ub.w);
        }
        __syncthreads();
        #pragma unroll
        for (int kk = 0; kk < 64; kk += 32){
            s16x8 af[4], bg[2], bu[2];
            #pragma unroll
            for (int mi = 0; mi < 4; ++mi)
                af[mi] = *(const s16x8*)(&lA[(wr*64 + mi*16 + (l&15))*72 + kk + (l>>4)*8]);
            #pragma unroll
            for (int ni = 0; ni < 2; ++ni){
                int n = wc*32 + ni*16 + (l&15);
                bg[ni] = *(const s16x8*)(&lG[n*72 + kk + (l>>4)*8]);
                bu[ni] = *(const s16x8*)(&lU[n*72 + kk + (l>>4)*8]);
            }
            #pragma unroll
            for (int mi = 0; mi < 4; ++mi)
                #pragma unroll
                for (int ni = 0; ni < 2; ++ni){
                    ag[mi][ni] = __builtin_amdgcn_mfma_f32_16x16x32_bf16(af[mi], bg[ni], ag[mi][ni], 0,0,0);
                    au[mi][ni] = __builtin_amdgcn_mfma_f32_16x16x32_bf16(af[mi], bu[ni], au[mi][ni], 0,0,0);
                }
        }
        __syncthreads();
    }
    const int obase = offs[e];
    #pragma unroll
    for (int mi = 0; mi < 4; ++mi)
        #pragma unroll
        for (int ni = 0; ni < 2; ++ni)
            #pragma unroll
            for (int rr = 0; rr < 4; ++rr){
                int slot = bm0 + wr*64 + mi*16 + (l>>4)*4 + rr;
                if (slot < ne){
                    int col = bn0 + wc*32 + ni*16 + (l&15);
                    float g = ag[mi][ni][rr], uu = au[mi][ni][rr];
                    float val = (g/(1.f+__expf(-g)))*uu;
                    inter[(size_t)(obase+slot)*INTER_C + col] = f2b(val);
                }
            }
}

__global__ __launch_bounds__(256) void moe_mlp2_f(const bf16* __restrict__ inter,
                                                  const float* __restrict__ downW,
                                                  float* __restrict__ hres,
                                                  const float* __restrict__ wl,
                                                  const int* __restrict__ lists,
                                                  const int* __restrict__ cnt,
                                                  const int* __restrict__ offs){
    const int e = blockIdx.z;
    const int ne = cnt[e];
    const int bm0 = blockIdx.x*128;
    if (bm0 >= ne) return;
    const int bn0 = blockIdx.y*128;
    __shared__ __align__(16) short lA[128*72];
    __shared__ __align__(16) short lB[128*72];
    const int tid = threadIdx.x;
    const int l = tid & 63, w = tid >> 6, wr = w >> 1, wc = w & 1;
    const int obase = offs[e];
    const size_t ebase = (size_t)e*INTER_C*HID_C;
    f32x4 acc[4][4] = {};
    for (int kt = 0; kt < INTER_C/64; ++kt){
        #pragma unroll
        for (int i = 0; i < 4; ++i){
            int u = tid + i*256;
            int r = u >> 3, cu = u & 7;
            int slot = bm0 + r;
            s16x8 v = {};
            if (slot < ne)
                v = *(const s16x8*)((const short*)inter + (size_t)(obase + slot)*INTER_C + kt*64 + cu*8);
            *(s16x8*)(&lA[r*72 + cu*8]) = v;
        }
        #pragma unroll
        for (int i = 0; i < 4; ++i){
            int u = tid + i*256;
            int k = u >> 4, n0 = (u & 15)*8;
            const float* bp = downW + ebase + (size_t)(kt*64 + k)*HID_C + bn0 + n0;
            float4 a = *(const float4*)bp, b = *(const float4*)(bp+4);
            lB[(n0+0)*72+k]=f2bs(a.x); lB[(n0+1)*72+k]=f2bs(a.y); lB[(n0+2)*72+k]=f2bs(a.z); lB[(n0+3)*72+k]=f2bs(a.w);
            lB[(n0+4)*72+k]=f2bs(b.x); lB[(n0+5)*72+k]=f2bs(b.y); lB[(n0+6)*72+k]=f2bs(b.z); lB[(n0+7)*72+k]=f2bs(b.w);
        }
        __syncthreads();
        #pragma unroll
        for (int kk = 0; kk < 64; kk += 32){
            s16x8 af[4], bfr[4];
            #pragma unroll
            for (int mi = 0; mi < 4; ++mi)
                af[mi] = *(const s16x8*)(&lA[(wr*64 + mi*16 + (l&15))*72 + kk + (l>>4)*8]);
            #pragma unroll
            for (int ni = 0; ni < 4; ++ni){
                int n = wc*64 + ni*16 + (l&15);
                bfr[ni] = *(const s16x8*)(&lB[n*72 + kk + (l>>4)*8]);
            }
            #pragma unroll
            for (int mi = 0; mi < 4; ++mi)
                #pragma unroll
                for (int ni = 0; ni < 4; ++ni)
                    acc[mi][ni] = __builtin_amdgcn_mfma_f32_16x16x32_bf16(af[mi], bfr[ni], acc[mi][ni], 0,0,0);
        }
        __syncthreads();
    }
    #pragma unroll
    for (int mi = 0; mi < 4; ++mi)
        #pragma unroll
        for (int ni = 0; ni < 4; ++ni)
            #pragma unroll
            for (int rr = 0; rr < 4; ++rr){
                int slot = bm0 + wr*64 + mi*16 + (l>>4)*4 + rr;
                if (slot < ne){
                    int col = bn0 + wc*64 + ni*16 + (l&15);
                    int tok = lists[e*CAP + slot];
                    float wgt = wl[e*CAP + slot];
                    atomicAdd(&hres[(size_t)tok*HID_C + col], acc[mi][ni][rr]*wgt);
                }
            }
}

// ======================= HOST =======================
extern "C" void kernel_launch(void* const* d_in, const int* in_sizes, int n_in,
                              void* d_out, int out_size, void* d_ws, size_t ws_size,
                              hipStream_t stream){
    const float* hidden  = (const float*)d_in[0];
    const float* fcos    = (const float*)d_in[1];
    const float* fsin    = (const float*)d_in[2];
    const float* wq      = (const float*)d_in[3];
    const float* wk      = (const float*)d_in[4];
    const float* wv      = (const float*)d_in[5];
    const float* wo      = (const float*)d_in[6];
    const float* routerw = (const float*)d_in[7];
    const float* gatew   = (const float*)d_in[8];
    const float* upw     = (const float*)d_in[9];
    const float* downw   = (const float*)d_in[10];
    const float* n1w     = (const float*)d_in[11];
    const float* n2w     = (const float*)d_in[12];

    char* p = (char*)d_ws;
    size_t off = 0;
    auto alloc = [&](size_t b)->void*{ void* r = p + off; off = (off + b + 255) & ~(size_t)255; return r; };

    // ---- big-path layout ----
    int*   cnt    = (int*)alloc(64);
    float* psum   = (float*)alloc(64);
    int*   offs   = (int*)alloc(64);
    int*   lists  = (int*)alloc((size_t)E_C*CAP*4);
    float* wl     = (float*)alloc((size_t)E_C*CAP*4);
    short* wqkv2  = (short*)alloc((size_t)NQKV*K2C*2);        // combined hi/lo, swizzled
    short* wo2    = (short*)alloc((size_t)HID_C*K2C*2);
    short* gate_t = (short*)alloc((size_t)E_C*INTER_C*HID_C*2);
    short* up_t   = (short*)alloc((size_t)E_C*INTER_C*HID_C*2);
    short* down_t = (short*)alloc((size_t)E_C*HID_C*INTER_C*2);
    short* h1c    = (short*)alloc((size_t)NTOK*K2C*2);        // norm1 combined swizzled; reused as attn-out
    float* qkvf   = (float*)alloc((size_t)NTOK*NQKV*4);       // later h2f + h2b
    float* hres   = (float*)alloc((size_t)NTOK*HID_C*4);
    bf16*  inter  = (bf16*)alloc((size_t)2*NTOK*INTER_C*2);
    size_t need_big = off;

    if (ws_size >= need_big){
        short* oc  = h1c;
        float* h2f = qkvf;
        bf16*  h2b = (bf16*)(qkvf + (size_t)NTOK*HID_C);

        (void)hipMemsetAsync(cnt, 0, 64, stream);
        (void)hipMemsetAsync(psum, 0, 64, stream);

        // prepass transposes (swizzled)
        tsplit2s_k<<<dim3(32,32), 256, 0, stream>>>(wq, wqkv2, 1024, 0);
        tsplit2s_k<<<dim3(8,32),  256, 0, stream>>>(wk, wqkv2, 256, 1024);
        tsplit2s_k<<<dim3(8,32),  256, 0, stream>>>(wv, wqkv2, 256, 1280);
        tsplit2s_k<<<dim3(32,32), 256, 0, stream>>>(wo, wo2, 1024, 0);
        tbf16s_k<<<dim3(88,32,8), 256, 0, stream>>>(gatew, gate_t, 1024, 2816);
        tbf16s_k<<<dim3(88,32,8), 256, 0, stream>>>(upw,   up_t,   1024, 2816);
        tbf16s_k<<<dim3(32,88,8), 256, 0, stream>>>(downw, down_t, 2816, 1024);

        rmsn1c_k<<<NTOK, 256, 0, stream>>>(hidden, n1w, h1c);
        sgemm4_k<false><<<dim3(32,12), 256, 0, stream>>>(h1c, wqkv2, qkvf, nullptr, NQKV);
        rope2_k<<<10240, 256, 0, stream>>>(qkvf, fcos, fsin);
        attn2c_k<<<dim3(NTOK,16), 64, 0, stream>>>(qkvf, oc);
        sgemm4_k<true><<<dim3(32,8), 256, 0, stream>>>(oc, wo2, hres, hidden, 1024);
        rmsn2_k<<<NTOK, 256, 0, stream>>>(hres, n2w, h2f, h2b);
        router_k<<<NTOK, 64, 0, stream>>>(h2f, routerw, lists, wl, cnt, psum);
        finalize_k<<<1, 64, 0, stream>>>(cnt, psum, offs, (float*)d_out);
        moe1g2_k<<<dim3(32,44,8), 256, 0, stream>>>((const short*)h2b, gate_t, up_t, inter, lists, cnt, offs);
        moe2g2_k<<<dim3(32,8,8), 256, 0, stream>>>(inter, down_t, hres, wl, lists, cnt, offs);
        final_k<<<NTOK, 256, 0, stream>>>(hres, (float*)d_out);
        return;
    }

    // ---- fallback (round-5) layout ----
    off = 0;
    cnt    = (int*)alloc(64);
    psum   = (float*)alloc(64);
    offs   = (int*)alloc(64);
    lists  = (int*)alloc((size_t)E_C*CAP*4);
    wl     = (float*)alloc((size_t)E_C*CAP*4);
    float* h1  = (float*)alloc((size_t)NTOK*HID_C*4);
    float* qb  = (float*)alloc((size_t)NTOK*HID_C*4);
    float* kb  = (float*)alloc((size_t)NTOK*256*4);
    float* vb  = (float*)alloc((size_t)NTOK*256*4);
    float* hresF = (float*)alloc((size_t)NTOK*HID_C*4);
    bf16*  h2bF  = (bf16*)alloc((size_t)NTOK*HID_C*2);
    bf16*  interF= (bf16*)alloc((size_t)2*NTOK*INTER_C*2);
    float* attnb = h1;
    float* h2fF  = qb;

    (void)hipMemsetAsync(cnt, 0, 64, stream);
    (void)hipMemsetAsync(psum, 0, 64, stream);

    rmsnorm_f<false><<<NTOK, 256, 0, stream>>>(hidden, n1w, h1, nullptr);
    sgemm_f<false><<<dim3(32, 8), 256, 0, stream>>>(h1, wq, qb, nullptr, 1024, 1024);
    sgemm_f<false><<<dim3(32, 2), 256, 0, stream>>>(h1, wk, kb, nullptr, 256, 1024);
    sgemm_f<false><<<dim3(32, 2), 256, 0, stream>>>(h1, wv, vb, nullptr, 256, 1024);
    rope_f<<<10240, 256, 0, stream>>>(qb, kb, fcos, fsin);
    attn_f<<<dim3(NTOK, 16), 64, 0, stream>>>(qb, kb, vb, attnb);
    sgemm_f<true><<<dim3(32, 8), 256, 0, stream>>>(attnb, wo, hresF, hidden, 1024, 1024);
    rmsnorm_f<true><<<NTOK, 256, 0, stream>>>(hresF, n2w, h2fF, h2bF);
    router_k<<<NTOK, 64, 0, stream>>>(h2fF, routerw, lists, wl, cnt, psum);
    finalize_k<<<1, 64, 0, stream>>>(cnt, psum, offs, (float*)d_out);
    moe_mlp1_f<<<dim3(32, 44, 8), 256, 0, stream>>>(h2bF, gatew, upw, interF, lists, cnt, offs);
    moe_mlp2_f<<<dim3(32, 8, 8), 256, 0, stream>>>(interF, downw, hresF, wl, lists, cnt, offs);
    final_k<<<NTOK, 256, 0, stream>>>(hresF, (float*)d_out);
}

// Round 10
// 1205.796 us; speedup vs baseline: 2.6778x; 1.4472x over previous
//
#include <hip/hip_runtime.h>
#include <hip/hip_bf16.h>
#include <math.h>

typedef short s16x8 __attribute__((ext_vector_type(8)));
typedef float f32x4 __attribute__((ext_vector_type(4)));
typedef __hip_bfloat16 bf16;

#define NTOK 4096
#define S_LEN 2048
#define HID_C 1024
#define E_C 8
#define INTER_C 2816
#define WIN_C 64
#define CAP 4096
#define NQKV 1536
#define K2C 2048
#define OUT0_N ((size_t)NTOK*HID_C)

#define AS1 __attribute__((address_space(1)))
#define AS3 __attribute__((address_space(3)))

static __device__ __forceinline__ void gload16(const void* g, void* l){
    __builtin_amdgcn_global_load_lds((AS1 void*)(g), (AS3 void*)(l), 16, 0, 0);
}

static __device__ __forceinline__ float b2f(bf16 v){ return __bfloat162float(v); }
static __device__ __forceinline__ bf16  f2b(float v){ return __float2bfloat16(v); }
static __device__ __forceinline__ short f2bs(float v){ bf16 h = __float2bfloat16(v); return *reinterpret_cast<short*>(&h); }
struct SplitBF { short hi; short lo; };
static __device__ __forceinline__ SplitBF splitf(float x){
    SplitBF r;
    bf16 bh = __float2bfloat16(x);
    r.hi = *reinterpret_cast<short*>(&bh);
    float rem = x - __bfloat162float(bh);
    bf16 bl = __float2bfloat16(rem);
    r.lo = *reinterpret_cast<short*>(&bl);
    return r;
}

// Swizzle convention: within each 64-short (128B) group of a row, logical
// 8-short chunk c is stored at physical chunk c ^ (row & 7).  gload16 stages
// rows linearly, so readers XOR the chunk index with (lds_row & 7).

// ============ PREPASS: f32 [1024][N] -> combined hi/lo [row_off+n][2048], swizzled ============
__global__ __launch_bounds__(256) void tsplit2s_k(const float* __restrict__ src,
                                                  short* __restrict__ dst,
                                                  int N, int row_off){
    __shared__ float tile[32][33];
    const int n0 = blockIdx.x*32, k0 = blockIdx.y*32;
    const int tx = threadIdx.x & 31, ty = threadIdx.x >> 5;
    #pragma unroll
    for (int i = 0; i < 4; ++i)
        tile[ty + i*8][tx] = src[(size_t)(k0 + ty + i*8)*N + n0 + tx];
    __syncthreads();
    const int g = k0 >> 5;                 // 64-short group index
    const int chH = tx >> 3, chL = 4 | (tx >> 3), off = tx & 7;
    #pragma unroll
    for (int i = 0; i < 4; ++i){
        int nn = ty + i*8;                 // key = nn&7 = ty
        SplitBF s = splitf(tile[tx][nn]);
        size_t rowb = (size_t)(row_off + n0 + nn)*K2C + g*64;
        dst[rowb + ((chH ^ ty)<<3) + off] = s.hi;
        dst[rowb + ((chL ^ ty)<<3) + off] = s.lo;
    }
}

// f32 [e][K][N] -> bf16 [e][N][K], swizzled
__global__ __launch_bounds__(256) void tbf16s_k(const float* __restrict__ src0,
                                                short* __restrict__ dst0, int K, int N){
    const int e = blockIdx.z;
    const float* src = src0 + (size_t)e*K*N;
    short* dst = dst0 + (size_t)e*N*K;
    __shared__ float tile[32][33];
    const int n0 = blockIdx.x*32, k0 = blockIdx.y*32;
    const int tx = threadIdx.x & 31, ty = threadIdx.x >> 5;
    #pragma unroll
    for (int i = 0; i < 4; ++i)
        tile[ty + i*8][tx] = src[(size_t)(k0 + ty + i*8)*N + n0 + tx];
    __syncthreads();
    const int grp  = k0 >> 6;
    const int half = (k0 & 32) >> 3;       // chunk base 0 or 4
    const int ch   = half + (tx >> 3), off = tx & 7;
    #pragma unroll
    for (int i = 0; i < 4; ++i){
        int nn = ty + i*8;                 // key = ty
        dst[(size_t)(n0 + nn)*K + grp*64 + ((ch ^ ty)<<3) + off] = f2bs(tile[tx][nn]);
    }
}

// ================= RMSNorm: f32 in -> combined hi/lo out (swizzled) =================
__global__ __launch_bounds__(256) void rmsn1c_k(const float* __restrict__ xin,
                                                const float* __restrict__ w,
                                                short* __restrict__ oc){
    const int t = blockIdx.x, tid = threadIdx.x;
    float4 v = *(const float4*)(xin + (size_t)t*HID_C + tid*4);
    float x[4] = {v.x, v.y, v.z, v.w};
    float s = x[0]*x[0]+x[1]*x[1]+x[2]*x[2]+x[3]*x[3];
    #pragma unroll
    for (int off=32; off; off>>=1) s += __shfl_xor(s, off);
    __shared__ float red[4];
    if ((tid&63)==0) red[tid>>6] = s;
    __syncthreads();
    float tot = red[0]+red[1]+red[2]+red[3];
    float sc = rsqrtf(tot*(1.0f/HID_C) + 1e-8f);
    float4 wv = *(const float4*)(w + tid*4);
    float o[4] = { x[0]*sc*wv.x, x[1]*sc*wv.y, x[2]*sc*wv.z, x[3]*sc*wv.w };
    __align__(8) short th[4], tl[4];
    #pragma unroll
    for (int i=0;i<4;++i){ SplitBF sp = splitf(o[i]); th[i]=sp.hi; tl[i]=sp.lo; }
    const int g = tid>>3, q = tid&7;
    const int ch = q>>1, sub = (q&1)*4, key = t&7;
    short* rowp = oc + (size_t)t*K2C + g*64;
    *(uint2*)(rowp + ((ch ^ key)<<3) + sub)      = *(uint2*)th;
    *(uint2*)(rowp + (((4|ch) ^ key)<<3) + sub)  = *(uint2*)tl;
}

// norm2: f32 in -> f32 out + bf16 out (linear; feeds gathered-A paths)
__global__ __launch_bounds__(256) void rmsn2_k(const float* __restrict__ xin,
                                               const float* __restrict__ w,
                                               float* __restrict__ outf, bf16* __restrict__ outb){
    const int t = blockIdx.x, tid = threadIdx.x;
    float4 v = *(const float4*)(xin + (size_t)t*HID_C + tid*4);
    float x[4] = {v.x, v.y, v.z, v.w};
    float s = x[0]*x[0]+x[1]*x[1]+x[2]*x[2]+x[3]*x[3];
    #pragma unroll
    for (int off=32; off; off>>=1) s += __shfl_xor(s, off);
    __shared__ float red[4];
    if ((tid&63)==0) red[tid>>6] = s;
    __syncthreads();
    float tot = red[0]+red[1]+red[2]+red[3];
    float sc = rsqrtf(tot*(1.0f/HID_C) + 1e-8f);
    float4 wv = *(const float4*)(w + tid*4);
    float o[4] = { x[0]*sc*wv.x, x[1]*sc*wv.y, x[2]*sc*wv.z, x[3]*sc*wv.w };
    *(float4*)(outf + (size_t)t*HID_C + tid*4) = make_float4(o[0],o[1],o[2],o[3]);
    __align__(8) bf16 tmp[4] = { f2b(o[0]), f2b(o[1]), f2b(o[2]), f2b(o[3]) };
    *(uint2*)(outb + (size_t)t*HID_C + tid*4) = *(uint2*)tmp;
}

// ============ split GEMM: dbuf gload16 + counted vmcnt + swizzled reads ============
template<bool RESID>
__global__ __launch_bounds__(256) void sgemm4_k(const short* __restrict__ A2,
                                                const short* __restrict__ B2,
                                                float* __restrict__ C, const float* __restrict__ resid,
                                                int N){
    __shared__ __align__(16) short lA[2][128*64];
    __shared__ __align__(16) short lB[2][128*64];
    const int tid = threadIdx.x;
    const int bm0 = blockIdx.x*128, bn0 = blockIdx.y*128;
    const int l = tid & 63, w = tid >> 6, wr = w >> 1, wc = w & 1;
    const int lr = l >> 3, lc8 = (l & 7)*8;
    f32x4 acc[4][4] = {};
    auto STAGE = [&](int buf, int kt){
        #pragma unroll
        for (int j = 0; j < 4; ++j){
            int row = w*32 + j*8 + lr;
            gload16(A2 + (size_t)(bm0 + row)*K2C + kt*64 + lc8, &lA[buf][(w*32 + j*8)*64]);
            gload16(B2 + (size_t)(bn0 + row)*K2C + kt*64 + lc8, &lB[buf][(w*32 + j*8)*64]);
        }
    };
    STAGE(0, 0);
    for (int kt = 0; kt < 32; ++kt){
        const int cur = kt & 1;
        if (kt + 1 < 32){
            STAGE(cur ^ 1, kt + 1);
            asm volatile("s_waitcnt vmcnt(8)" ::: "memory");
        } else {
            asm volatile("s_waitcnt vmcnt(0)" ::: "memory");
        }
        __builtin_amdgcn_s_barrier();
        __builtin_amdgcn_sched_barrier(0);
        s16x8 ah[4], al[4], bh[4], bl[4];
        #pragma unroll
        for (int mi = 0; mi < 4; ++mi){
            int r = wr*64 + mi*16 + (l&15);
            int key = r & 7;
            ah[mi] = *(const s16x8*)(&lA[cur][r*64 + (((l>>4) ^ key)<<3)]);
            al[mi] = *(const s16x8*)(&lA[cur][r*64 + (((4|(l>>4)) ^ key)<<3)]);
        }
        #pragma unroll
        for (int ni = 0; ni < 4; ++ni){
            int n = wc*64 + ni*16 + (l&15);
            int key = n & 7;
            bh[ni] = *(const s16x8*)(&lB[cur][n*64 + (((l>>4) ^ key)<<3)]);
            bl[ni] = *(const s16x8*)(&lB[cur][n*64 + (((4|(l>>4)) ^ key)<<3)]);
        }
        #pragma unroll
        for (int mi = 0; mi < 4; ++mi)
            #pragma unroll
            for (int ni = 0; ni < 4; ++ni){
                acc[mi][ni] = __builtin_amdgcn_mfma_f32_16x16x32_bf16(ah[mi], bh[ni], acc[mi][ni], 0,0,0);
                acc[mi][ni] = __builtin_amdgcn_mfma_f32_16x16x32_bf16(ah[mi], bl[ni], acc[mi][ni], 0,0,0);
                acc[mi][ni] = __builtin_amdgcn_mfma_f32_16x16x32_bf16(al[mi], bh[ni], acc[mi][ni], 0,0,0);
            }
        __builtin_amdgcn_s_barrier();
    }
    #pragma unroll
    for (int mi = 0; mi < 4; ++mi)
        #pragma unroll
        for (int ni = 0; ni < 4; ++ni)
            #pragma unroll
            for (int rr = 0; rr < 4; ++rr){
                int row = bm0 + wr*64 + mi*16 + (l>>4)*4 + rr;
                int col = bn0 + wc*64 + ni*16 + (l&15);
                float vv = acc[mi][ni][rr];
                if (RESID) vv += resid[(size_t)row*N + col];
                C[(size_t)row*N + col] = vv;
            }
}

// ================ RoPE on packed qkv f32 [tok][1536] ================
__global__ __launch_bounds__(256) void rope2_k(float* __restrict__ qkv,
                                               const float* __restrict__ cosb, const float* __restrict__ sinb){
    int idx = blockIdx.x*256 + threadIdx.x;
    int t = idx / 640;
    int r = idx - t*640;
    int hs = r >> 5, tp = r & 31;
    int s = t & (S_LEN-1);
    float c  = cosb[s*32+tp];
    float sn = sinb[s*32+tp];
    float* base;
    if (hs < 16) base = qkv + (size_t)t*NQKV + hs*64 + 2*tp;
    else         base = qkv + (size_t)t*NQKV + 1024 + (hs-16)*64 + 2*tp;
    float2 v = *(float2*)base;
    *(float2*)base = make_float2(v.x*c - v.y*sn, v.x*sn + v.y*c);
}

// ======== attention -> combined hi/lo output (swizzled for sgemm4 A) ========
__global__ __launch_bounds__(64) void attn2c_k(const float* __restrict__ qkv,
                                               short* __restrict__ oc){
    const int l = threadIdx.x;
    const int bs = blockIdx.x;
    const int h = blockIdx.y, hk = h >> 2;
    const int sq = bs & (S_LEN-1);
    __shared__ float qs[64];
    __shared__ float ps[65];
    qs[l] = qkv[(size_t)bs*NQKV + h*64 + l];
    __syncthreads();
    const int j0 = (sq - WIN_C) > 0 ? (sq - WIN_C) : 0;
    const int nk = sq - j0 + 1;
    const int tokbase = bs - sq;
    float sc[2] = {-1e9f, -1e9f};
    #pragma unroll
    for (int it = 0; it < 2; ++it){
        int jj = l + it*64;
        if (jj < nk){
            const float* kp = qkv + (size_t)(tokbase + j0 + jj)*NQKV + 1024 + hk*64;
            float d = 0.f;
            #pragma unroll
            for (int c = 0; c < 16; ++c){
                float4 kv = *(const float4*)(kp + c*4);
                d += qs[c*4+0]*kv.x + qs[c*4+1]*kv.y + qs[c*4+2]*kv.z + qs[c*4+3]*kv.w;
            }
            sc[it] = d*0.125f;
        }
    }
    float m = fmaxf(sc[0], sc[1]);
    #pragma unroll
    for (int off=32; off; off>>=1) m = fmaxf(m, __shfl_xor(m, off));
    float e0 = (l      < nk) ? __expf(sc[0]-m) : 0.f;
    float e1 = (l + 64 < nk) ? __expf(sc[1]-m) : 0.f;
    float s = e0 + e1;
    #pragma unroll
    for (int off=32; off; off>>=1) s += __shfl_xor(s, off);
    float inv = 1.f/s;
    if (l      < nk) ps[l]    = e0*inv;
    if (l + 64 < nk) ps[l+64] = e1*inv;
    __syncthreads();
    float acc = 0.f;
    for (int jj = 0; jj < nk; ++jj)
        acc += ps[jj]*qkv[(size_t)(tokbase + j0 + jj)*NQKV + 1280 + hk*64 + l];
    SplitBF sp = splitf(acc);
    const int k = h*64 + l;
    const int g = k>>5, ch = (k&31)>>3, off = k&7, key = bs&7;
    short* rowp = oc + (size_t)bs*K2C + g*64;
    rowp[((ch ^ key)<<3) + off]      = sp.hi;
    rowp[(((4|ch) ^ key)<<3) + off]  = sp.lo;
}

// ================= router (f32) =================
__global__ __launch_bounds__(64) void router_k(const float* __restrict__ h2f, const float* __restrict__ rw,
                                               int* __restrict__ lists, float* __restrict__ wl,
                                               int* __restrict__ cnt, float* __restrict__ psum){
    const int t = blockIdx.x, l = threadIdx.x;
    float lg[8] = {0,0,0,0,0,0,0,0};
    for (int c = 0; c < 16; ++c){
        int kidx = l + c*64;
        float x = h2f[(size_t)t*HID_C + kidx];
        float4 w0 = *(const float4*)(rw + (size_t)kidx*8);
        float4 w1 = *(const float4*)(rw + (size_t)kidx*8 + 4);
        lg[0] += x*w0.x; lg[1] += x*w0.y; lg[2] += x*w0.z; lg[3] += x*w0.w;
        lg[4] += x*w1.x; lg[5] += x*w1.y; lg[6] += x*w1.z; lg[7] += x*w1.w;
    }
    #pragma unroll
    for (int e = 0; e < 8; ++e)
        #pragma unroll
        for (int off=32; off; off>>=1) lg[e] += __shfl_xor(lg[e], off);
    if (l == 0){
        float m = lg[0];
        #pragma unroll
        for (int e = 1; e < 8; ++e) m = fmaxf(m, lg[e]);
        float p[8]; float s = 0.f;
        #pragma unroll
        for (int e = 0; e < 8; ++e){ p[e] = __expf(lg[e]-m); s += p[e]; }
        float invs = 1.f/s;
        #pragma unroll
        for (int e = 0; e < 8; ++e){ p[e] *= invs; atomicAdd(&psum[e], p[e]); }
        float best = -1e30f, sec = -1e30f; int bi = 0, si = 0;
        #pragma unroll
        for (int e = 0; e < 8; ++e){
            float pv = p[e];
            if (pv > best){ sec = best; si = bi; best = pv; bi = e; }
            else if (pv > sec){ sec = pv; si = e; }
        }
        float wsum = best + sec + 1e-9f;
        int s0 = atomicAdd(&cnt[bi], 1);
        lists[bi*CAP + s0] = t; wl[bi*CAP + s0] = best/wsum;
        int s1 = atomicAdd(&cnt[si], 1);
        lists[si*CAP + s1] = t; wl[si*CAP + s1] = sec/wsum;
    }
}

__global__ void finalize_k(const int* __restrict__ cnt, const float* __restrict__ psum,
                           int* __restrict__ offs, float* __restrict__ out){
    if (threadIdx.x == 0 && blockIdx.x == 0){
        int o = 0; float loss = 0.f;
        for (int e = 0; e < 8; ++e){
            offs[e] = o; o += cnt[e];
            loss += (psum[e]*(1.0f/NTOK)) * ((float)cnt[e]*(1.0f/NTOK));
        }
        offs[8] = o;
        out[OUT0_N] = loss * (float)E_C * 0.01f;
    }
}

// ============ MoE gate/up: XCD panel-grouped 1-D grid, dbuf gload16, setprio ============
// b: r=b&7 (XCD), j=b>>3; group G=r+8*(j>>5) in [0,352); e=G/44, bn=G%44; m=j&31.
// All 32 M-blocks of a (e,bn) panel share b%8 -> same XCD -> panel L2-resident.
__global__ __launch_bounds__(256) void moe1g3_k(const short* __restrict__ h2b,
                                                const short* __restrict__ gate_t,
                                                const short* __restrict__ up_t,
                                                bf16* __restrict__ inter,
                                                const int* __restrict__ lists,
                                                const int* __restrict__ cnt,
                                                const int* __restrict__ offs){
    const int b = blockIdx.x;
    const int r = b & 7, j = b >> 3;
    const int G = r + ((j >> 5) << 3);
    const int e = G / 44, bnG = G % 44;
    const int bm0 = (j & 31) * 128;
    const int ne = cnt[e];
    if (bm0 >= ne) return;
    const int bn0 = bnG * 64;
    __shared__ __align__(16) short lA[2][128*64];
    __shared__ __align__(16) short lG[2][64*64];
    __shared__ __align__(16) short lU[2][64*64];
    const int tid = threadIdx.x;
    const int l = tid & 63, w = tid >> 6, wr = w >> 1, wc = w & 1;
    const int lr = l >> 3, lc8 = (l & 7)*8;
    const short* Gb = gate_t + (size_t)e*INTER_C*HID_C;
    const short* Ub = up_t   + (size_t)e*INTER_C*HID_C;
    int tokA[4];
    #pragma unroll
    for (int jj = 0; jj < 4; ++jj){
        int slot = bm0 + w*32 + jj*8 + lr;
        if (slot >= ne) slot = ne - 1;
        tokA[jj] = lists[e*CAP + slot];
    }
    auto STAGE = [&](int buf, int kt){
        #pragma unroll
        for (int jj = 0; jj < 4; ++jj)
            gload16(h2b + (size_t)tokA[jj]*HID_C + kt*64 + lc8, &lA[buf][(w*32 + jj*8)*64]);
        #pragma unroll
        for (int jj = 0; jj < 2; ++jj){
            int n = w*16 + jj*8 + lr;
            gload16(Gb + (size_t)(bn0 + n)*HID_C + kt*64 + lc8, &lG[buf][(w*16 + jj*8)*64]);
            gload16(Ub + (size_t)(bn0 + n)*HID_C + kt*64 + lc8, &lU[buf][(w*16 + jj*8)*64]);
        }
    };
    f32x4 ag[4][2] = {}; f32x4 au[4][2] = {};
    STAGE(0, 0);
    for (int kt = 0; kt < 16; ++kt){
        const int cur = kt & 1;
        if (kt + 1 < 16){
            STAGE(cur ^ 1, kt + 1);
            asm volatile("s_waitcnt vmcnt(8)" ::: "memory");
        } else {
            asm volatile("s_waitcnt vmcnt(0)" ::: "memory");
        }
        __builtin_amdgcn_s_barrier();
        __builtin_amdgcn_sched_barrier(0);
        __builtin_amdgcn_s_setprio(1);
        #pragma unroll
        for (int kk = 0; kk < 64; kk += 32){
            s16x8 af[4], bg[2], bu[2];
            #pragma unroll
            for (int mi = 0; mi < 4; ++mi)
                af[mi] = *(const s16x8*)(&lA[cur][(wr*64 + mi*16 + (l&15))*64 + kk + (l>>4)*8]);
            #pragma unroll
            for (int ni = 0; ni < 2; ++ni){
                int n = wc*32 + ni*16 + (l&15);
                int key = n & 7;
                int ch = (kk>>3) + (l>>4);
                bg[ni] = *(const s16x8*)(&lG[cur][n*64 + ((ch ^ key)<<3)]);
                bu[ni] = *(const s16x8*)(&lU[cur][n*64 + ((ch ^ key)<<3)]);
            }
            #pragma unroll
            for (int mi = 0; mi < 4; ++mi)
                #pragma unroll
                for (int ni = 0; ni < 2; ++ni){
                    ag[mi][ni] = __builtin_amdgcn_mfma_f32_16x16x32_bf16(af[mi], bg[ni], ag[mi][ni], 0,0,0);
                    au[mi][ni] = __builtin_amdgcn_mfma_f32_16x16x32_bf16(af[mi], bu[ni], au[mi][ni], 0,0,0);
                }
        }
        __builtin_amdgcn_s_setprio(0);
        __builtin_amdgcn_s_barrier();
    }
    const int obase = offs[e];
    #pragma unroll
    for (int mi = 0; mi < 4; ++mi)
        #pragma unroll
        for (int ni = 0; ni < 2; ++ni)
            #pragma unroll
            for (int rr = 0; rr < 4; ++rr){
                int slot = bm0 + wr*64 + mi*16 + (l>>4)*4 + rr;
                if (slot < ne){
                    int col = bn0 + wc*32 + ni*16 + (l&15);
                    float g = ag[mi][ni][rr], uu = au[mi][ni][rr];
                    float val = (g/(1.f+__expf(-g)))*uu;
                    inter[(size_t)(obase+slot)*INTER_C + col] = f2b(val);
                }
            }
}

// ============ MoE down: XCD panel-grouped 1-D grid, dbuf gload16, setprio ============
// b: r=b&7, j=b>>3; G=r+8*(j>>5) in [0,64); e=G>>3, bn=G&7; m=j&31.
__global__ __launch_bounds__(256) void moe2g3_k(const bf16* __restrict__ inter,
                                                const short* __restrict__ down_t,
                                                float* __restrict__ hres,
                                                const float* __restrict__ wl,
                                                const int* __restrict__ lists,
                                                const int* __restrict__ cnt,
                                                const int* __restrict__ offs){
    const int b = blockIdx.x;
    const int r = b & 7, j = b >> 3;
    const int G = r + ((j >> 5) << 3);
    const int e = G >> 3, bnG = G & 7;
    const int bm0 = (j & 31) * 128;
    const int ne = cnt[e];
    if (bm0 >= ne) return;
    const int bn0 = bnG * 128;
    __shared__ __align__(16) short lA[2][128*64];
    __shared__ __align__(16) short lB[2][128*64];
    const int tid = threadIdx.x;
    const int l = tid & 63, w = tid >> 6, wr = w >> 1, wc = w & 1;
    const int lr = l >> 3, lc8 = (l & 7)*8;
    const int obase = offs[e];
    const short* Db = down_t + (size_t)e*HID_C*INTER_C;
    const short* As = (const short*)inter;
    int rowA[4];
    #pragma unroll
    for (int jj = 0; jj < 4; ++jj){
        int slot = bm0 + w*32 + jj*8 + lr;
        if (slot >= ne) slot = ne - 1;
        rowA[jj] = obase + slot;
    }
    auto STAGE = [&](int buf, int kt){
        #pragma unroll
        for (int jj = 0; jj < 4; ++jj){
            gload16(As + (size_t)rowA[jj]*INTER_C + kt*64 + lc8, &lA[buf][(w*32 + jj*8)*64]);
            int n = w*32 + jj*8 + lr;
            gload16(Db + (size_t)(bn0 + n)*INTER_C + kt*64 + lc8, &lB[buf][(w*32 + jj*8)*64]);
        }
    };
    f32x4 acc[4][4] = {};
    STAGE(0, 0);
    for (int kt = 0; kt < 44; ++kt){
        const int cur = kt & 1;
        if (kt + 1 < 44){
            STAGE(cur ^ 1, kt + 1);
            asm volatile("s_waitcnt vmcnt(8)" ::: "memory");
        } else {
            asm volatile("s_waitcnt vmcnt(0)" ::: "memory");
        }
        __builtin_amdgcn_s_barrier();
        __builtin_amdgcn_sched_barrier(0);
        __builtin_amdgcn_s_setprio(1);
        #pragma unroll
        for (int kk = 0; kk < 64; kk += 32){
            s16x8 af[4], bfr[4];
            #pragma unroll
            for (int mi = 0; mi < 4; ++mi)
                af[mi] = *(const s16x8*)(&lA[cur][(wr*64 + mi*16 + (l&15))*64 + kk + (l>>4)*8]);
            #pragma unroll
            for (int ni = 0; ni < 4; ++ni){
                int n = wc*64 + ni*16 + (l&15);
                int key = n & 7;
                int ch = (kk>>3) + (l>>4);
                bfr[ni] = *(const s16x8*)(&lB[cur][n*64 + ((ch ^ key)<<3)]);
            }
            #pragma unroll
            for (int mi = 0; mi < 4; ++mi)
                #pragma unroll
                for (int ni = 0; ni < 4; ++ni)
                    acc[mi][ni] = __builtin_amdgcn_mfma_f32_16x16x32_bf16(af[mi], bfr[ni], acc[mi][ni], 0,0,0);
        }
        __builtin_amdgcn_s_setprio(0);
        __builtin_amdgcn_s_barrier();
    }
    #pragma unroll
    for (int mi = 0; mi < 4; ++mi)
        #pragma unroll
        for (int ni = 0; ni < 4; ++ni)
            #pragma unroll
            for (int rr = 0; rr < 4; ++rr){
                int slot = bm0 + wr*64 + mi*16 + (l>>4)*4 + rr;
                if (slot < ne){
                    int col = bn0 + wc*64 + ni*16 + (l&15);
                    int tok = lists[e*CAP + slot];
                    float wgt = wl[e*CAP + slot];
                    atomicAdd(&hres[(size_t)tok*HID_C + col], acc[mi][ni][rr]*wgt);
                }
            }
}

__global__ __launch_bounds__(256) void final_k(const float* __restrict__ hres,
                                               float* __restrict__ out){
    const int t = blockIdx.x, c = threadIdx.x*4;
    float4 hv = *(const float4*)(hres + (size_t)t*HID_C + c);
    *(float4*)(out + (size_t)t*HID_C + c) = hv;
}

// ======================= FALLBACK PATH (round-5, ws-lean) =======================
template<bool ALSO_BF16>
__global__ __launch_bounds__(256) void rmsnorm_f(const float* __restrict__ xin, const float* __restrict__ w,
                                                 float* __restrict__ outf, bf16* __restrict__ outb){
    const int t = blockIdx.x, tid = threadIdx.x;
    float4 v = *(const float4*)(xin + (size_t)t*HID_C + tid*4);
    float x[4] = {v.x, v.y, v.z, v.w};
    float s = x[0]*x[0]+x[1]*x[1]+x[2]*x[2]+x[3]*x[3];
    #pragma unroll
    for (int off=32; off; off>>=1) s += __shfl_xor(s, off);
    __shared__ float red[4];
    if ((tid&63)==0) red[tid>>6] = s;
    __syncthreads();
    float tot = red[0]+red[1]+red[2]+red[3];
    float sc = rsqrtf(tot*(1.0f/HID_C) + 1e-8f);
    float4 wv = *(const float4*)(w + tid*4);
    float o[4] = { x[0]*sc*wv.x, x[1]*sc*wv.y, x[2]*sc*wv.z, x[3]*sc*wv.w };
    *(float4*)(outf + (size_t)t*HID_C + tid*4) = make_float4(o[0],o[1],o[2],o[3]);
    if (ALSO_BF16){
        __align__(8) bf16 tmp[4] = { f2b(o[0]), f2b(o[1]), f2b(o[2]), f2b(o[3]) };
        *(uint2*)(outb + (size_t)t*HID_C + tid*4) = *(uint2*)tmp;
    }
}

template<bool RESID>
__global__ __launch_bounds__(256) void sgemm_f(const float* __restrict__ A, const float* __restrict__ B,
                                               float* __restrict__ C, const float* __restrict__ resid,
                                               int N, int K){
    __shared__ __align__(16) short lAh[128*40];
    __shared__ __align__(16) short lAl[128*40];
    __shared__ __align__(16) short lBh[128*40];
    __shared__ __align__(16) short lBl[128*40];
    const int tid = threadIdx.x;
    const int bm0 = blockIdx.x*128, bn0 = blockIdx.y*128;
    const int l = tid & 63, w = tid >> 6, wr = w >> 1, wc = w & 1;
    f32x4 acc[4][4] = {};
    for (int kt = 0; kt < K/32; ++kt){
        #pragma unroll
        for (int i = 0; i < 4; ++i){
            int u = tid + i*256;
            int r = u >> 3, c4 = (u & 7)*4;
            float4 v = *(const float4*)(A + (size_t)(bm0+r)*K + kt*32 + c4);
            SplitBF s0 = splitf(v.x), s1 = splitf(v.y), s2 = splitf(v.z), s3 = splitf(v.w);
            __align__(8) short hv[4] = { s0.hi, s1.hi, s2.hi, s3.hi };
            __align__(8) short lv[4] = { s0.lo, s1.lo, s2.lo, s3.lo };
            *(uint2*)(&lAh[r*40 + c4]) = *(uint2*)hv;
            *(uint2*)(&lAl[r*40 + c4]) = *(uint2*)lv;
        }
        #pragma unroll
        for (int i = 0; i < 4; ++i){
            int u = tid + i*256;
            int k = u >> 5, n0 = (u & 31)*4;
            float4 v = *(const float4*)(B + (size_t)(kt*32 + k)*N + bn0 + n0);
            SplitBF s0 = splitf(v.x), s1 = splitf(v.y), s2 = splitf(v.z), s3 = splitf(v.w);
            lBh[(n0+0)*40+k]=s0.hi; lBh[(n0+1)*40+k]=s1.hi; lBh[(n0+2)*40+k]=s2.hi; lBh[(n0+3)*40+k]=s3.hi;
            lBl[(n0+0)*40+k]=s0.lo; lBl[(n0+1)*40+k]=s1.lo; lBl[(n0+2)*40+k]=s2.lo; lBl[(n0+3)*40+k]=s3.lo;
        }
        __syncthreads();
        s16x8 ah[4], al[4], bh[4], bl[4];
        #pragma unroll
        for (int mi = 0; mi < 4; ++mi){
            int r = wr*64 + mi*16 + (l&15);
            ah[mi] = *(const s16x8*)(&lAh[r*40 + (l>>4)*8]);
            al[mi] = *(const s16x8*)(&lAl[r*40 + (l>>4)*8]);
        }
        #pragma unroll
        for (int ni = 0; ni < 4; ++ni){
            int n = wc*64 + ni*16 + (l&15);
            bh[ni] = *(const s16x8*)(&lBh[n*40 + (l>>4)*8]);
            bl[ni] = *(const s16x8*)(&lBl[n*40 + (l>>4)*8]);
        }
        #pragma unroll
        for (int mi = 0; mi < 4; ++mi)
            #pragma unroll
            for (int ni = 0; ni < 4; ++ni){
                acc[mi][ni] = __builtin_amdgcn_mfma_f32_16x16x32_bf16(ah[mi], bh[ni], acc[mi][ni], 0,0,0);
                acc[mi][ni] = __builtin_amdgcn_mfma_f32_16x16x32_bf16(ah[mi], bl[ni], acc[mi][ni], 0,0,0);
                acc[mi][ni] = __builtin_amdgcn_mfma_f32_16x16x32_bf16(al[mi], bh[ni], acc[mi][ni], 0,0,0);
            }
        __syncthreads();
    }
    #pragma unroll
    for (int mi = 0; mi < 4; ++mi)
        #pragma unroll
        for (int ni = 0; ni < 4; ++ni)
            #pragma unroll
            for (int rr = 0; rr < 4; ++rr){
                int row = bm0 + wr*64 + mi*16 + (l>>4)*4 + rr;
                int col = bn0 + wc*64 + ni*16 + (l&15);
                float vv = acc[mi][ni][rr];
                if (RESID) vv += resid[(size_t)row*N + col];
                C[(size_t)row*N + col] = vv;
            }
}

__global__ __launch_bounds__(256) void rope_f(float* __restrict__ qb, float* __restrict__ kb,
                                              const float* __restrict__ cosb, const float* __restrict__ sinb){
    int idx = blockIdx.x*256 + threadIdx.x;
    int t = idx / 640;
    int r = idx - t*640;
    int hs = r >> 5, tp = r & 31;
    int s = t & (S_LEN-1);
    float c  = cosb[s*32+tp];
    float sn = sinb[s*32+tp];
    float* base;
    if (hs < 16) base = qb + (size_t)t*1024 + hs*64 + 2*tp;
    else         base = kb + (size_t)t*256 + (hs-16)*64 + 2*tp;
    float2 v = *(float2*)base;
    *(float2*)base = make_float2(v.x*c - v.y*sn, v.x*sn + v.y*c);
}

__global__ __launch_bounds__(64) void attn_f(const float* __restrict__ qb, const float* __restrict__ kb,
                                             const float* __restrict__ vb, float* __restrict__ ob){
    const int l = threadIdx.x;
    const int bs = blockIdx.x;
    const int h = blockIdx.y, hk = h >> 2;
    const int sq = bs & (S_LEN-1);
    __shared__ float qs[64];
    __shared__ float ps[65];
    qs[l] = qb[(size_t)bs*1024 + h*64 + l];
    __syncthreads();
    const int j0 = (sq - WIN_C) > 0 ? (sq - WIN_C) : 0;
    const int nk = sq - j0 + 1;
    const int tokbase = bs - sq;
    float sc[2] = {-1e9f, -1e9f};
    #pragma unroll
    for (int it = 0; it < 2; ++it){
        int jj = l + it*64;
        if (jj < nk){
            const float* kp = kb + (size_t)(tokbase + j0 + jj)*256 + hk*64;
            float d = 0.f;
            #pragma unroll
            for (int c = 0; c < 16; ++c){
                float4 kv = *(const float4*)(kp + c*4);
                d += qs[c*4+0]*kv.x + qs[c*4+1]*kv.y + qs[c*4+2]*kv.z + qs[c*4+3]*kv.w;
            }
            sc[it] = d*0.125f;
        }
    }
    float m = fmaxf(sc[0], sc[1]);
    #pragma unroll
    for (int off=32; off; off>>=1) m = fmaxf(m, __shfl_xor(m, off));
    float e0 = (l      < nk) ? __expf(sc[0]-m) : 0.f;
    float e1 = (l + 64 < nk) ? __expf(sc[1]-m) : 0.f;
    float s = e0 + e1;
    #pragma unroll
    for (int off=32; off; off>>=1) s += __shfl_xor(s, off);
    float inv = 1.f/s;
    if (l      < nk) ps[l]    = e0*inv;
    if (l + 64 < nk) ps[l+64] = e1*inv;
    __syncthreads();
    float acc = 0.f;
    for (int jj = 0; jj < nk; ++jj)
        acc += ps[jj]*vb[(size_t)(tokbase + j0 + jj)*256 + hk*64 + l];
    ob[(size_t)bs*1024 + h*64 + l] = acc;
}

__global__ __launch_bounds__(256) void moe_mlp1_f(const bf16* __restrict__ h2b,
                                                  const float* __restrict__ gateW,
                                                  const float* __restrict__ upW,
                                                  bf16* __restrict__ inter,
                                                  const int* __restrict__ lists,
                                                  const int* __restrict__ cnt,
                                                  const int* __restrict__ offs){
    const int e = blockIdx.z;
    const int ne = cnt[e];
    const int bm0 = blockIdx.x*128;
    if (bm0 >= ne) return;
    const int bn0 = blockIdx.y*64;
    __shared__ __align__(16) short lA[128*72];
    __shared__ __align__(16) short lG[64*72];
    __shared__ __align__(16) short lU[64*72];
    const int tid = threadIdx.x;
    const int l = tid & 63, w = tid >> 6, wr = w >> 1, wc = w & 1;
    const size_t ebase = (size_t)e*HID_C*INTER_C;
    f32x4 ag[4][2] = {}; f32x4 au[4][2] = {};
    for (int kt = 0; kt < HID_C/64; ++kt){
        #pragma unroll
        for (int i = 0; i < 4; ++i){
            int u = tid + i*256;
            int r = u >> 3, cu = u & 7;
            int slot = bm0 + r;
            s16x8 v = {};
            if (slot < ne){
                int tok = lists[e*CAP + slot];
                v = *(const s16x8*)((const short*)h2b + (size_t)tok*HID_C + kt*64 + cu*8);
            }
            *(s16x8*)(&lA[r*72 + cu*8]) = v;
        }
        #pragma unroll
        for (int i = 0; i < 2; ++i){
            int u = tid + i*256;
            int k = u >> 3, n0 = (u & 7)*8;
            size_t gidx = ebase + (size_t)(kt*64 + k)*INTER_C + bn0 + n0;
            const float* gp = gateW + gidx;
            const float* up = upW + gidx;
            float4 ga = *(const float4*)gp, gb = *(const float4*)(gp+4);
            float4 ua = *(const float4*)up, ub = *(const float4*)(up+4);
            lG[(n0+0)*72+k]=f2bs(ga.x); lG[(n0+1)*72+k]=f2bs(ga.y); lG[(n0+2)*72+k]=f2bs(ga.z); lG[(n0+3)*72+k]=f2bs(ga.w);
            lG[(n0+4)*72+k]=f2bs(gb.x); lG[(n0+5)*72+k]=f2bs(gb.y); lG[(n0+6)*72+k]=f2bs(gb.z); lG[(n0+7)*72+k]=f2bs(gb.w);
            lU[(n0+0)*72+k]=f2bs(ua.x); lU[(n0+1)*72+k]=f2bs(ua.y); lU[(n0+2)*72+k]=f2bs(ua.z); lU[(n0+3)*72+k]=f2bs(ua.w);
            lU[(n0+4)*72+k]=f2bs(ub.x); lU[(n0+5)*72+k]=f2bs(ub.y); lU[(n0+6)*72+k]=f2bs(ub.z); lU[(n0+7)*72+k]=f2bs(ub.w);
        }
        __syncthreads();
        #pragma unroll
        for (int kk = 0; kk < 64; kk += 32){
            s16x8 af[4], bg[2], bu[2];
            #pragma unroll
            for (int mi = 0; mi < 4; ++mi)
                af[mi] = *(const s16x8*)(&lA[(wr*64 + mi*16 + (l&15))*72 + kk + (l>>4)*8]);
            #pragma unroll
            for (int ni = 0; ni < 2; ++ni){
                int n = wc*32 + ni*16 + (l&15);
                bg[ni] = *(const s16x8*)(&lG[n*72 + kk + (l>>4)*8]);
                bu[ni] = *(const s16x8*)(&lU[n*72 + kk + (l>>4)*8]);
            }
            #pragma unroll
            for (int mi = 0; mi < 4; ++mi)
                #pragma unroll
                for (int ni = 0; ni < 2; ++ni){
                    ag[mi][ni] = __builtin_amdgcn_mfma_f32_16x16x32_bf16(af[mi], bg[ni], ag[mi][ni], 0,0,0);
                    au[mi][ni] = __builtin_amdgcn_mfma_f32_16x16x32_bf16(af[mi], bu[ni], au[mi][ni], 0,0,0);
                }
        }
        __syncthreads();
    }
    const int obase = offs[e];
    #pragma unroll
    for (int mi = 0; mi < 4; ++mi)
        #pragma unroll
        for (int ni = 0; ni < 2; ++ni)
            #pragma unroll
            for (int rr = 0; rr < 4; ++rr){
                int slot = bm0 + wr*64 + mi*16 + (l>>4)*4 + rr;
                if (slot < ne){
                    int col = bn0 + wc*32 + ni*16 + (l&15);
                    float g = ag[mi][ni][rr], uu = au[mi][ni][rr];
                    float val = (g/(1.f+__expf(-g)))*uu;
                    inter[(size_t)(obase+slot)*INTER_C + col] = f2b(val);
                }
            }
}

__global__ __launch_bounds__(256) void moe_mlp2_f(const bf16* __restrict__ inter,
                                                  const float* __restrict__ downW,
                                                  float* __restrict__ hres,
                                                  const float* __restrict__ wl,
                                                  const int* __restrict__ lists,
                                                  const int* __restrict__ cnt,
                                                  const int* __restrict__ offs){
    const int e = blockIdx.z;
    const int ne = cnt[e];
    const int bm0 = blockIdx.x*128;
    if (bm0 >= ne) return;
    const int bn0 = blockIdx.y*128;
    __shared__ __align__(16) short lA[128*72];
    __shared__ __align__(16) short lB[128*72];
    const int tid = threadIdx.x;
    const int l = tid & 63, w = tid >> 6, wr = w >> 1, wc = w & 1;
    const int obase = offs[e];
    const size_t ebase = (size_t)e*INTER_C*HID_C;
    f32x4 acc[4][4] = {};
    for (int kt = 0; kt < INTER_C/64; ++kt){
        #pragma unroll
        for (int i = 0; i < 4; ++i){
            int u = tid + i*256;
            int r = u >> 3, cu = u & 7;
            int slot = bm0 + r;
            s16x8 v = {};
            if (slot < ne)
                v = *(const s16x8*)((const short*)inter + (size_t)(obase + slot)*INTER_C + kt*64 + cu*8);
            *(s16x8*)(&lA[r*72 + cu*8]) = v;
        }
        #pragma unroll
        for (int i = 0; i < 4; ++i){
            int u = tid + i*256;
            int k = u >> 4, n0 = (u & 15)*8;
            const float* bp = downW + ebase + (size_t)(kt*64 + k)*HID_C + bn0 + n0;
            float4 a = *(const float4*)bp, b = *(const float4*)(bp+4);
            lB[(n0+0)*72+k]=f2bs(a.x); lB[(n0+1)*72+k]=f2bs(a.y); lB[(n0+2)*72+k]=f2bs(a.z); lB[(n0+3)*72+k]=f2bs(a.w);
            lB[(n0+4)*72+k]=f2bs(b.x); lB[(n0+5)*72+k]=f2bs(b.y); lB[(n0+6)*72+k]=f2bs(b.z); lB[(n0+7)*72+k]=f2bs(b.w);
        }
        __syncthreads();
        #pragma unroll
        for (int kk = 0; kk < 64; kk += 32){
            s16x8 af[4], bfr[4];
            #pragma unroll
            for (int mi = 0; mi < 4; ++mi)
                af[mi] = *(const s16x8*)(&lA[(wr*64 + mi*16 + (l&15))*72 + kk + (l>>4)*8]);
            #pragma unroll
            for (int ni = 0; ni < 4; ++ni){
                int n = wc*64 + ni*16 + (l&15);
                bfr[ni] = *(const s16x8*)(&lB[n*72 + kk + (l>>4)*8]);
            }
            #pragma unroll
            for (int mi = 0; mi < 4; ++mi)
                #pragma unroll
                for (int ni = 0; ni < 4; ++ni)
                    acc[mi][ni] = __builtin_amdgcn_mfma_f32_16x16x32_bf16(af[mi], bfr[ni], acc[mi][ni], 0,0,0);
        }
        __syncthreads();
    }
    #pragma unroll
    for (int mi = 0; mi < 4; ++mi)
        #pragma unroll
        for (int ni = 0; ni < 4; ++ni)
            #pragma unroll
            for (int rr = 0; rr < 4; ++rr){
                int slot = bm0 + wr*64 + mi*16 + (l>>4)*4 + rr;
                if (slot < ne){
                    int col = bn0 + wc*64 + ni*16 + (l&15);
                    int tok = lists[e*CAP + slot];
                    float wgt = wl[e*CAP + slot];
                    atomicAdd(&hres[(size_t)tok*HID_C + col], acc[mi][ni][rr]*wgt);
                }
            }
}

// ======================= HOST =======================
extern "C" void kernel_launch(void* const* d_in, const int* in_sizes, int n_in,
                              void* d_out, int out_size, void* d_ws, size_t ws_size,
                              hipStream_t stream){
    const float* hidden  = (const float*)d_in[0];
    const float* fcos    = (const float*)d_in[1];
    const float* fsin    = (const float*)d_in[2];
    const float* wq      = (const float*)d_in[3];
    const float* wk      = (const float*)d_in[4];
    const float* wv      = (const float*)d_in[5];
    const float* wo      = (const float*)d_in[6];
    const float* routerw = (const float*)d_in[7];
    const float* gatew   = (const float*)d_in[8];
    const float* upw     = (const float*)d_in[9];
    const float* downw   = (const float*)d_in[10];
    const float* n1w     = (const float*)d_in[11];
    const float* n2w     = (const float*)d_in[12];

    char* p = (char*)d_ws;
    size_t off = 0;
    auto alloc = [&](size_t b)->void*{ void* r = p + off; off = (off + b + 255) & ~(size_t)255; return r; };

    // ---- big-path layout ----
    int*   cnt    = (int*)alloc(64);
    float* psum   = (float*)alloc(64);
    int*   offs   = (int*)alloc(64);
    int*   lists  = (int*)alloc((size_t)E_C*CAP*4);
    float* wl     = (float*)alloc((size_t)E_C*CAP*4);
    short* wqkv2  = (short*)alloc((size_t)NQKV*K2C*2);        // combined hi/lo, swizzled
    short* wo2    = (short*)alloc((size_t)HID_C*K2C*2);
    short* gate_t = (short*)alloc((size_t)E_C*INTER_C*HID_C*2);
    short* up_t   = (short*)alloc((size_t)E_C*INTER_C*HID_C*2);
    short* down_t = (short*)alloc((size_t)E_C*HID_C*INTER_C*2);
    short* h1c    = (short*)alloc((size_t)NTOK*K2C*2);        // norm1 combined swizzled; reused as attn-out
    float* qkvf   = (float*)alloc((size_t)NTOK*NQKV*4);       // later h2f + h2b
    float* hres   = (float*)alloc((size_t)NTOK*HID_C*4);
    bf16*  inter  = (bf16*)alloc((size_t)2*NTOK*INTER_C*2);
    size_t need_big = off;

    if (ws_size >= need_big){
        short* oc  = h1c;
        float* h2f = qkvf;
        bf16*  h2b = (bf16*)(qkvf + (size_t)NTOK*HID_C);

        (void)hipMemsetAsync(cnt, 0, 64, stream);
        (void)hipMemsetAsync(psum, 0, 64, stream);

        // prepass transposes (swizzled)
        tsplit2s_k<<<dim3(32,32), 256, 0, stream>>>(wq, wqkv2, 1024, 0);
        tsplit2s_k<<<dim3(8,32),  256, 0, stream>>>(wk, wqkv2, 256, 1024);
        tsplit2s_k<<<dim3(8,32),  256, 0, stream>>>(wv, wqkv2, 256, 1280);
        tsplit2s_k<<<dim3(32,32), 256, 0, stream>>>(wo, wo2, 1024, 0);
        tbf16s_k<<<dim3(88,32,8), 256, 0, stream>>>(gatew, gate_t, 1024, 2816);
        tbf16s_k<<<dim3(88,32,8), 256, 0, stream>>>(upw,   up_t,   1024, 2816);
        tbf16s_k<<<dim3(32,88,8), 256, 0, stream>>>(downw, down_t, 2816, 1024);

        rmsn1c_k<<<NTOK, 256, 0, stream>>>(hidden, n1w, h1c);
        sgemm4_k<false><<<dim3(32,12), 256, 0, stream>>>(h1c, wqkv2, qkvf, nullptr, NQKV);
        rope2_k<<<10240, 256, 0, stream>>>(qkvf, fcos, fsin);
        attn2c_k<<<dim3(NTOK,16), 64, 0, stream>>>(qkvf, oc);
        sgemm4_k<true><<<dim3(32,8), 256, 0, stream>>>(oc, wo2, hres, hidden, 1024);
        rmsn2_k<<<NTOK, 256, 0, stream>>>(hres, n2w, h2f, h2b);
        router_k<<<NTOK, 64, 0, stream>>>(h2f, routerw, lists, wl, cnt, psum);
        finalize_k<<<1, 64, 0, stream>>>(cnt, psum, offs, (float*)d_out);
        moe1g3_k<<<11264, 256, 0, stream>>>((const short*)h2b, gate_t, up_t, inter, lists, cnt, offs);
        moe2g3_k<<<2048, 256, 0, stream>>>(inter, down_t, hres, wl, lists, cnt, offs);
        final_k<<<NTOK, 256, 0, stream>>>(hres, (float*)d_out);
        return;
    }

    // ---- fallback (round-5) layout ----
    off = 0;
    cnt    = (int*)alloc(64);
    psum   = (float*)alloc(64);
    offs   = (int*)alloc(64);
    lists  = (int*)alloc((size_t)E_C*CAP*4);
    wl     = (float*)alloc((size_t)E_C*CAP*4);
    float* h1  = (float*)alloc((size_t)NTOK*HID_C*4);
    float* qb  = (float*)alloc((size_t)NTOK*HID_C*4);
    float* kb  = (float*)alloc((size_t)NTOK*256*4);
    float* vb  = (float*)alloc((size_t)NTOK*256*4);
    float* hresF = (float*)alloc((size_t)NTOK*HID_C*4);
    bf16*  h2bF  = (bf16*)alloc((size_t)NTOK*HID_C*2);
    bf16*  interF= (bf16*)alloc((size_t)2*NTOK*INTER_C*2);
    float* attnb = h1;
    float* h2fF  = qb;

    (void)hipMemsetAsync(cnt, 0, 64, stream);
    (void)hipMemsetAsync(psum, 0, 64, stream);

    rmsnorm_f<false><<<NTOK, 256, 0, stream>>>(hidden, n1w, h1, nullptr);
    sgemm_f<false><<<dim3(32, 8), 256, 0, stream>>>(h1, wq, qb, nullptr, 1024, 1024);
    sgemm_f<false><<<dim3(32, 2), 256, 0, stream>>>(h1, wk, kb, nullptr, 256, 1024);
    sgemm_f<false><<<dim3(32, 2), 256, 0, stream>>>(h1, wv, vb, nullptr, 256, 1024);
    rope_f<<<10240, 256, 0, stream>>>(qb, kb, fcos, fsin);
    attn_f<<<dim3(NTOK, 16), 64, 0, stream>>>(qb, kb, vb, attnb);
    sgemm_f<true><<<dim3(32, 8), 256, 0, stream>>>(attnb, wo, hresF, hidden, 1024, 1024);
    rmsnorm_f<true><<<NTOK, 256, 0, stream>>>(hresF, n2w, h2fF, h2bF);
    router_k<<<NTOK, 64, 0, stream>>>(h2fF, routerw, lists, wl, cnt, psum);
    finalize_k<<<1, 64, 0, stream>>>(cnt, psum, offs, (float*)d_out);
    moe_mlp1_f<<<dim3(32, 44, 8), 256, 0, stream>>>(h2bF, gatew, upw, interF, lists, cnt, offs);
    moe_mlp2_f<<<dim3(32, 8, 8), 256, 0, stream>>>(interF, downw, hresF, wl, lists, cnt, offs);
    final_k<<<NTOK, 256, 0, stream>>>(hresF, (float*)d_out);
}

// Round 11
// 811.137 us; speedup vs baseline: 3.9807x; 1.4866x over previous
//
#include <hip/hip_runtime.h>
#include <hip/hip_bf16.h>
#include <math.h>

typedef short s16x8 __attribute__((ext_vector_type(8)));
typedef float f32x4 __attribute__((ext_vector_type(4)));
typedef __hip_bfloat16 bf16;

#define NTOK 4096
#define S_LEN 2048
#define HID_C 1024
#define E_C 8
#define INTER_C 2816
#define WIN_C 64
#define CAP 4096
#define NQKV 1536
#define K2C 2048
#define OUT0_N ((size_t)NTOK*HID_C)

#define AS1 __attribute__((address_space(1)))
#define AS3 __attribute__((address_space(3)))

static __device__ __forceinline__ void gload16(const void* g, void* l){
    __builtin_amdgcn_global_load_lds((AS1 void*)(g), (AS3 void*)(l), 16, 0, 0);
}

static __device__ __forceinline__ float b2f(bf16 v){ return __bfloat162float(v); }
static __device__ __forceinline__ bf16  f2b(float v){ return __float2bfloat16(v); }
static __device__ __forceinline__ short f2bs(float v){ bf16 h = __float2bfloat16(v); return *reinterpret_cast<short*>(&h); }
struct SplitBF { short hi; short lo; };
static __device__ __forceinline__ SplitBF splitf(float x){
    SplitBF r;
    bf16 bh = __float2bfloat16(x);
    r.hi = *reinterpret_cast<short*>(&bh);
    float rem = x - __bfloat162float(bh);
    bf16 bl = __float2bfloat16(rem);
    r.lo = *reinterpret_cast<short*>(&bl);
    return r;
}

// Swizzle convention: within each 64-short (128B) group of a row, logical
// 8-short chunk c is stored at physical chunk c ^ (row & 7).  gload16 stages
// rows linearly, so readers XOR the chunk index with (lds_row & 7).

// ============ PREPASS: f32 [1024][N] -> combined hi/lo [row_off+n][2048], swizzled ============
__global__ __launch_bounds__(256) void tsplit2s_k(const float* __restrict__ src,
                                                  short* __restrict__ dst,
                                                  int N, int row_off){
    __shared__ float tile[32][33];
    const int n0 = blockIdx.x*32, k0 = blockIdx.y*32;
    const int tx = threadIdx.x & 31, ty = threadIdx.x >> 5;
    #pragma unroll
    for (int i = 0; i < 4; ++i)
        tile[ty + i*8][tx] = src[(size_t)(k0 + ty + i*8)*N + n0 + tx];
    __syncthreads();
    const int g = k0 >> 5;                 // 64-short group index
    const int chH = tx >> 3, chL = 4 | (tx >> 3), off = tx & 7;
    #pragma unroll
    for (int i = 0; i < 4; ++i){
        int nn = ty + i*8;                 // key = nn&7 = ty
        SplitBF s = splitf(tile[tx][nn]);
        size_t rowb = (size_t)(row_off + n0 + nn)*K2C + g*64;
        dst[rowb + ((chH ^ ty)<<3) + off] = s.hi;
        dst[rowb + ((chL ^ ty)<<3) + off] = s.lo;
    }
}

// f32 [e][K][N] -> bf16 [e][N][K], swizzled
__global__ __launch_bounds__(256) void tbf16s_k(const float* __restrict__ src0,
                                                short* __restrict__ dst0, int K, int N){
    const int e = blockIdx.z;
    const float* src = src0 + (size_t)e*K*N;
    short* dst = dst0 + (size_t)e*N*K;
    __shared__ float tile[32][33];
    const int n0 = blockIdx.x*32, k0 = blockIdx.y*32;
    const int tx = threadIdx.x & 31, ty = threadIdx.x >> 5;
    #pragma unroll
    for (int i = 0; i < 4; ++i)
        tile[ty + i*8][tx] = src[(size_t)(k0 + ty + i*8)*N + n0 + tx];
    __syncthreads();
    const int grp  = k0 >> 6;
    const int half = (k0 & 32) >> 3;       // chunk base 0 or 4
    const int ch   = half + (tx >> 3), off = tx & 7;
    #pragma unroll
    for (int i = 0; i < 4; ++i){
        int nn = ty + i*8;                 // key = ty
        dst[(size_t)(n0 + nn)*K + grp*64 + ((ch ^ ty)<<3) + off] = f2bs(tile[tx][nn]);
    }
}

// ================= RMSNorm: f32 in -> combined hi/lo out (swizzled) =================
__global__ __launch_bounds__(256) void rmsn1c_k(const float* __restrict__ xin,
                                                const float* __restrict__ w,
                                                short* __restrict__ oc){
    const int t = blockIdx.x, tid = threadIdx.x;
    float4 v = *(const float4*)(xin + (size_t)t*HID_C + tid*4);
    float x[4] = {v.x, v.y, v.z, v.w};
    float s = x[0]*x[0]+x[1]*x[1]+x[2]*x[2]+x[3]*x[3];
    #pragma unroll
    for (int off=32; off; off>>=1) s += __shfl_xor(s, off);
    __shared__ float red[4];
    if ((tid&63)==0) red[tid>>6] = s;
    __syncthreads();
    float tot = red[0]+red[1]+red[2]+red[3];
    float sc = rsqrtf(tot*(1.0f/HID_C) + 1e-8f);
    float4 wv = *(const float4*)(w + tid*4);
    float o[4] = { x[0]*sc*wv.x, x[1]*sc*wv.y, x[2]*sc*wv.z, x[3]*sc*wv.w };
    __align__(8) short th[4], tl[4];
    #pragma unroll
    for (int i=0;i<4;++i){ SplitBF sp = splitf(o[i]); th[i]=sp.hi; tl[i]=sp.lo; }
    const int g = tid>>3, q = tid&7;
    const int ch = q>>1, sub = (q&1)*4, key = t&7;
    short* rowp = oc + (size_t)t*K2C + g*64;
    *(uint2*)(rowp + ((ch ^ key)<<3) + sub)      = *(uint2*)th;
    *(uint2*)(rowp + (((4|ch) ^ key)<<3) + sub)  = *(uint2*)tl;
}

// norm2: f32 in -> f32 out + bf16 out (linear; feeds gathered-A paths)
__global__ __launch_bounds__(256) void rmsn2_k(const float* __restrict__ xin,
                                               const float* __restrict__ w,
                                               float* __restrict__ outf, bf16* __restrict__ outb){
    const int t = blockIdx.x, tid = threadIdx.x;
    float4 v = *(const float4*)(xin + (size_t)t*HID_C + tid*4);
    float x[4] = {v.x, v.y, v.z, v.w};
    float s = x[0]*x[0]+x[1]*x[1]+x[2]*x[2]+x[3]*x[3];
    #pragma unroll
    for (int off=32; off; off>>=1) s += __shfl_xor(s, off);
    __shared__ float red[4];
    if ((tid&63)==0) red[tid>>6] = s;
    __syncthreads();
    float tot = red[0]+red[1]+red[2]+red[3];
    float sc = rsqrtf(tot*(1.0f/HID_C) + 1e-8f);
    float4 wv = *(const float4*)(w + tid*4);
    float o[4] = { x[0]*sc*wv.x, x[1]*sc*wv.y, x[2]*sc*wv.z, x[3]*sc*wv.w };
    *(float4*)(outf + (size_t)t*HID_C + tid*4) = make_float4(o[0],o[1],o[2],o[3]);
    __align__(8) bf16 tmp[4] = { f2b(o[0]), f2b(o[1]), f2b(o[2]), f2b(o[3]) };
    *(uint2*)(outb + (size_t)t*HID_C + tid*4) = *(uint2*)tmp;
}

// ============ split GEMM: dbuf gload16 + counted vmcnt + swizzled reads ============
template<bool RESID>
__global__ __launch_bounds__(256) void sgemm4_k(const short* __restrict__ A2,
                                                const short* __restrict__ B2,
                                                float* __restrict__ C, const float* __restrict__ resid,
                                                int N){
    __shared__ __align__(16) short lA[2][128*64];
    __shared__ __align__(16) short lB[2][128*64];
    const int tid = threadIdx.x;
    const int bm0 = blockIdx.x*128, bn0 = blockIdx.y*128;
    const int l = tid & 63, w = tid >> 6, wr = w >> 1, wc = w & 1;
    const int lr = l >> 3, lc8 = (l & 7)*8;
    f32x4 acc[4][4] = {};
    auto STAGE = [&](int buf, int kt){
        #pragma unroll
        for (int j = 0; j < 4; ++j){
            int row = w*32 + j*8 + lr;
            gload16(A2 + (size_t)(bm0 + row)*K2C + kt*64 + lc8, &lA[buf][(w*32 + j*8)*64]);
            gload16(B2 + (size_t)(bn0 + row)*K2C + kt*64 + lc8, &lB[buf][(w*32 + j*8)*64]);
        }
    };
    STAGE(0, 0);
    for (int kt = 0; kt < 32; ++kt){
        const int cur = kt & 1;
        if (kt + 1 < 32){
            STAGE(cur ^ 1, kt + 1);
            asm volatile("s_waitcnt vmcnt(8)" ::: "memory");
        } else {
            asm volatile("s_waitcnt vmcnt(0)" ::: "memory");
        }
        __builtin_amdgcn_s_barrier();
        __builtin_amdgcn_sched_barrier(0);
        s16x8 ah[4], al[4], bh[4], bl[4];
        #pragma unroll
        for (int mi = 0; mi < 4; ++mi){
            int r = wr*64 + mi*16 + (l&15);
            int key = r & 7;
            ah[mi] = *(const s16x8*)(&lA[cur][r*64 + (((l>>4) ^ key)<<3)]);
            al[mi] = *(const s16x8*)(&lA[cur][r*64 + (((4|(l>>4)) ^ key)<<3)]);
        }
        #pragma unroll
        for (int ni = 0; ni < 4; ++ni){
            int n = wc*64 + ni*16 + (l&15);
            int key = n & 7;
            bh[ni] = *(const s16x8*)(&lB[cur][n*64 + (((l>>4) ^ key)<<3)]);
            bl[ni] = *(const s16x8*)(&lB[cur][n*64 + (((4|(l>>4)) ^ key)<<3)]);
        }
        #pragma unroll
        for (int mi = 0; mi < 4; ++mi)
            #pragma unroll
            for (int ni = 0; ni < 4; ++ni){
                acc[mi][ni] = __builtin_amdgcn_mfma_f32_16x16x32_bf16(ah[mi], bh[ni], acc[mi][ni], 0,0,0);
                acc[mi][ni] = __builtin_amdgcn_mfma_f32_16x16x32_bf16(ah[mi], bl[ni], acc[mi][ni], 0,0,0);
                acc[mi][ni] = __builtin_amdgcn_mfma_f32_16x16x32_bf16(al[mi], bh[ni], acc[mi][ni], 0,0,0);
            }
        __builtin_amdgcn_s_barrier();
    }
    #pragma unroll
    for (int mi = 0; mi < 4; ++mi)
        #pragma unroll
        for (int ni = 0; ni < 4; ++ni)
            #pragma unroll
            for (int rr = 0; rr < 4; ++rr){
                int row = bm0 + wr*64 + mi*16 + (l>>4)*4 + rr;
                int col = bn0 + wc*64 + ni*16 + (l&15);
                float vv = acc[mi][ni][rr];
                if (RESID) vv += resid[(size_t)row*N + col];
                C[(size_t)row*N + col] = vv;
            }
}

// ================ RoPE on packed qkv f32 [tok][1536] ================
__global__ __launch_bounds__(256) void rope2_k(float* __restrict__ qkv,
                                               const float* __restrict__ cosb, const float* __restrict__ sinb){
    int idx = blockIdx.x*256 + threadIdx.x;
    int t = idx / 640;
    int r = idx - t*640;
    int hs = r >> 5, tp = r & 31;
    int s = t & (S_LEN-1);
    float c  = cosb[s*32+tp];
    float sn = sinb[s*32+tp];
    float* base;
    if (hs < 16) base = qkv + (size_t)t*NQKV + hs*64 + 2*tp;
    else         base = qkv + (size_t)t*NQKV + 1024 + (hs-16)*64 + 2*tp;
    float2 v = *(float2*)base;
    *(float2*)base = make_float2(v.x*c - v.y*sn, v.x*sn + v.y*c);
}

// ======== attention -> combined hi/lo output (swizzled for sgemm4 A) ========
__global__ __launch_bounds__(64) void attn2c_k(const float* __restrict__ qkv,
                                               short* __restrict__ oc){
    const int l = threadIdx.x;
    const int bs = blockIdx.x;
    const int h = blockIdx.y, hk = h >> 2;
    const int sq = bs & (S_LEN-1);
    __shared__ float qs[64];
    __shared__ float ps[65];
    qs[l] = qkv[(size_t)bs*NQKV + h*64 + l];
    __syncthreads();
    const int j0 = (sq - WIN_C) > 0 ? (sq - WIN_C) : 0;
    const int nk = sq - j0 + 1;
    const int tokbase = bs - sq;
    float sc[2] = {-1e9f, -1e9f};
    #pragma unroll
    for (int it = 0; it < 2; ++it){
        int jj = l + it*64;
        if (jj < nk){
            const float* kp = qkv + (size_t)(tokbase + j0 + jj)*NQKV + 1024 + hk*64;
            float d = 0.f;
            #pragma unroll
            for (int c = 0; c < 16; ++c){
                float4 kv = *(const float4*)(kp + c*4);
                d += qs[c*4+0]*kv.x + qs[c*4+1]*kv.y + qs[c*4+2]*kv.z + qs[c*4+3]*kv.w;
            }
            sc[it] = d*0.125f;
        }
    }
    float m = fmaxf(sc[0], sc[1]);
    #pragma unroll
    for (int off=32; off; off>>=1) m = fmaxf(m, __shfl_xor(m, off));
    float e0 = (l      < nk) ? __expf(sc[0]-m) : 0.f;
    float e1 = (l + 64 < nk) ? __expf(sc[1]-m) : 0.f;
    float s = e0 + e1;
    #pragma unroll
    for (int off=32; off; off>>=1) s += __shfl_xor(s, off);
    float inv = 1.f/s;
    if (l      < nk) ps[l]    = e0*inv;
    if (l + 64 < nk) ps[l+64] = e1*inv;
    __syncthreads();
    float acc = 0.f;
    for (int jj = 0; jj < nk; ++jj)
        acc += ps[jj]*qkv[(size_t)(tokbase + j0 + jj)*NQKV + 1280 + hk*64 + l];
    SplitBF sp = splitf(acc);
    const int k = h*64 + l;
    const int g = k>>5, ch = (k&31)>>3, off = k&7, key = bs&7;
    short* rowp = oc + (size_t)bs*K2C + g*64;
    rowp[((ch ^ key)<<3) + off]      = sp.hi;
    rowp[(((4|ch) ^ key)<<3) + off]  = sp.lo;
}

// ================= router v2: 16 tokens/block, LDS-aggregated atomics =================
__global__ __launch_bounds__(256) void router2_k(const float* __restrict__ h2f, const float* __restrict__ rw,
                                                 int* __restrict__ lists, float* __restrict__ wl,
                                                 int* __restrict__ cnt, float* __restrict__ psum){
    const int tid = threadIdx.x, l = tid & 63, w = tid >> 6;
    __shared__ int   sE0[16], sE1[16], sSlot0[16], sSlot1[16];
    __shared__ float sW0[16], sW1[16];
    __shared__ float sPsum[8];
    __shared__ int   sCnt[8], sBase[8];
    if (tid < 8){ sPsum[tid] = 0.f; sCnt[tid] = 0; }
    __syncthreads();
    #pragma unroll
    for (int i = 0; i < 4; ++i){
        const int li = w*4 + i;
        const int t = blockIdx.x*16 + li;
        float lg[8] = {0,0,0,0,0,0,0,0};
        for (int c = 0; c < 16; ++c){
            int kidx = l + c*64;
            float x = h2f[(size_t)t*HID_C + kidx];
            float4 w0 = *(const float4*)(rw + (size_t)kidx*8);
            float4 w1 = *(const float4*)(rw + (size_t)kidx*8 + 4);
            lg[0] += x*w0.x; lg[1] += x*w0.y; lg[2] += x*w0.z; lg[3] += x*w0.w;
            lg[4] += x*w1.x; lg[5] += x*w1.y; lg[6] += x*w1.z; lg[7] += x*w1.w;
        }
        #pragma unroll
        for (int e = 0; e < 8; ++e)
            #pragma unroll
            for (int off=32; off; off>>=1) lg[e] += __shfl_xor(lg[e], off);
        if (l == 0){
            float m = lg[0];
            #pragma unroll
            for (int e = 1; e < 8; ++e) m = fmaxf(m, lg[e]);
            float p[8]; float s = 0.f;
            #pragma unroll
            for (int e = 0; e < 8; ++e){ p[e] = __expf(lg[e]-m); s += p[e]; }
            float invs = 1.f/s;
            #pragma unroll
            for (int e = 0; e < 8; ++e){ p[e] *= invs; atomicAdd(&sPsum[e], p[e]); }
            float best = -1e30f, sec = -1e30f; int bi = 0, si = 0;
            #pragma unroll
            for (int e = 0; e < 8; ++e){
                float pv = p[e];
                if (pv > best){ sec = best; si = bi; best = pv; bi = e; }
                else if (pv > sec){ sec = pv; si = e; }
            }
            float wsum = best + sec + 1e-9f;
            sE0[li] = bi; sE1[li] = si;
            sW0[li] = best/wsum; sW1[li] = sec/wsum;
            sSlot0[li] = atomicAdd(&sCnt[bi], 1);
            sSlot1[li] = atomicAdd(&sCnt[si], 1);
        }
    }
    __syncthreads();
    if (tid < 8){
        sBase[tid] = atomicAdd(&cnt[tid], sCnt[tid]);
        atomicAdd(&psum[tid], sPsum[tid]);
    }
    __syncthreads();
    if (tid < 16){
        int t = blockIdx.x*16 + tid;
        int e0 = sE0[tid], e1 = sE1[tid];
        int s0 = sBase[e0] + sSlot0[tid];
        int s1 = sBase[e1] + sSlot1[tid];
        lists[e0*CAP + s0] = t; wl[e0*CAP + s0] = sW0[tid];
        lists[e1*CAP + s1] = t; wl[e1*CAP + s1] = sW1[tid];
    }
}

__global__ void finalize_k(const int* __restrict__ cnt, const float* __restrict__ psum,
                           int* __restrict__ offs, float* __restrict__ out){
    if (threadIdx.x == 0 && blockIdx.x == 0){
        int o = 0; float loss = 0.f;
        for (int e = 0; e < 8; ++e){
            offs[e] = o; o += cnt[e];
            loss += (psum[e]*(1.0f/NTOK)) * ((float)cnt[e]*(1.0f/NTOK));
        }
        offs[8] = o;
        out[OUT0_N] = loss * (float)E_C * 0.01f;
    }
}

// ============ MoE gate/up: XCD panel-grouped 1-D grid, dbuf gload16, setprio ============
__global__ __launch_bounds__(256) void moe1g3_k(const short* __restrict__ h2b,
                                                const short* __restrict__ gate_t,
                                                const short* __restrict__ up_t,
                                                bf16* __restrict__ inter,
                                                const int* __restrict__ lists,
                                                const int* __restrict__ cnt,
                                                const int* __restrict__ offs){
    const int b = blockIdx.x;
    const int r = b & 7, j = b >> 3;
    const int G = r + ((j >> 5) << 3);
    const int e = G / 44, bnG = G % 44;
    const int bm0 = (j & 31) * 128;
    const int ne = cnt[e];
    if (bm0 >= ne) return;
    const int bn0 = bnG * 64;
    __shared__ __align__(16) short lA[2][128*64];
    __shared__ __align__(16) short lG[2][64*64];
    __shared__ __align__(16) short lU[2][64*64];
    const int tid = threadIdx.x;
    const int l = tid & 63, w = tid >> 6, wr = w >> 1, wc = w & 1;
    const int lr = l >> 3, lc8 = (l & 7)*8;
    const short* Gb = gate_t + (size_t)e*INTER_C*HID_C;
    const short* Ub = up_t   + (size_t)e*INTER_C*HID_C;
    int tokA[4];
    #pragma unroll
    for (int jj = 0; jj < 4; ++jj){
        int slot = bm0 + w*32 + jj*8 + lr;
        if (slot >= ne) slot = ne - 1;
        tokA[jj] = lists[e*CAP + slot];
    }
    auto STAGE = [&](int buf, int kt){
        #pragma unroll
        for (int jj = 0; jj < 4; ++jj)
            gload16(h2b + (size_t)tokA[jj]*HID_C + kt*64 + lc8, &lA[buf][(w*32 + jj*8)*64]);
        #pragma unroll
        for (int jj = 0; jj < 2; ++jj){
            int n = w*16 + jj*8 + lr;
            gload16(Gb + (size_t)(bn0 + n)*HID_C + kt*64 + lc8, &lG[buf][(w*16 + jj*8)*64]);
            gload16(Ub + (size_t)(bn0 + n)*HID_C + kt*64 + lc8, &lU[buf][(w*16 + jj*8)*64]);
        }
    };
    f32x4 ag[4][2] = {}; f32x4 au[4][2] = {};
    STAGE(0, 0);
    for (int kt = 0; kt < 16; ++kt){
        const int cur = kt & 1;
        if (kt + 1 < 16){
            STAGE(cur ^ 1, kt + 1);
            asm volatile("s_waitcnt vmcnt(8)" ::: "memory");
        } else {
            asm volatile("s_waitcnt vmcnt(0)" ::: "memory");
        }
        __builtin_amdgcn_s_barrier();
        __builtin_amdgcn_sched_barrier(0);
        __builtin_amdgcn_s_setprio(1);
        #pragma unroll
        for (int kk = 0; kk < 64; kk += 32){
            s16x8 af[4], bg[2], bu[2];
            #pragma unroll
            for (int mi = 0; mi < 4; ++mi)
                af[mi] = *(const s16x8*)(&lA[cur][(wr*64 + mi*16 + (l&15))*64 + kk + (l>>4)*8]);
            #pragma unroll
            for (int ni = 0; ni < 2; ++ni){
                int n = wc*32 + ni*16 + (l&15);
                int key = n & 7;
                int ch = (kk>>3) + (l>>4);
                bg[ni] = *(const s16x8*)(&lG[cur][n*64 + ((ch ^ key)<<3)]);
                bu[ni] = *(const s16x8*)(&lU[cur][n*64 + ((ch ^ key)<<3)]);
            }
            #pragma unroll
            for (int mi = 0; mi < 4; ++mi)
                #pragma unroll
                for (int ni = 0; ni < 2; ++ni){
                    ag[mi][ni] = __builtin_amdgcn_mfma_f32_16x16x32_bf16(af[mi], bg[ni], ag[mi][ni], 0,0,0);
                    au[mi][ni] = __builtin_amdgcn_mfma_f32_16x16x32_bf16(af[mi], bu[ni], au[mi][ni], 0,0,0);
                }
        }
        __builtin_amdgcn_s_setprio(0);
        __builtin_amdgcn_s_barrier();
    }
    const int obase = offs[e];
    #pragma unroll
    for (int mi = 0; mi < 4; ++mi)
        #pragma unroll
        for (int ni = 0; ni < 2; ++ni)
            #pragma unroll
            for (int rr = 0; rr < 4; ++rr){
                int slot = bm0 + wr*64 + mi*16 + (l>>4)*4 + rr;
                if (slot < ne){
                    int col = bn0 + wc*32 + ni*16 + (l&15);
                    float g = ag[mi][ni][rr], uu = au[mi][ni][rr];
                    float val = (g/(1.f+__expf(-g)))*uu;
                    inter[(size_t)(obase+slot)*INTER_C + col] = f2b(val);
                }
            }
}

// ============ MoE down: XCD panel-grouped 1-D grid, dbuf gload16, setprio ============
__global__ __launch_bounds__(256) void moe2g3_k(const bf16* __restrict__ inter,
                                                const short* __restrict__ down_t,
                                                float* __restrict__ hres,
                                                const float* __restrict__ wl,
                                                const int* __restrict__ lists,
                                                const int* __restrict__ cnt,
                                                const int* __restrict__ offs){
    const int b = blockIdx.x;
    const int r = b & 7, j = b >> 3;
    const int G = r + ((j >> 5) << 3);
    const int e = G >> 3, bnG = G & 7;
    const int bm0 = (j & 31) * 128;
    const int ne = cnt[e];
    if (bm0 >= ne) return;
    const int bn0 = bnG * 128;
    __shared__ __align__(16) short lA[2][128*64];
    __shared__ __align__(16) short lB[2][128*64];
    const int tid = threadIdx.x;
    const int l = tid & 63, w = tid >> 6, wr = w >> 1, wc = w & 1;
    const int lr = l >> 3, lc8 = (l & 7)*8;
    const int obase = offs[e];
    const short* Db = down_t + (size_t)e*HID_C*INTER_C;
    const short* As = (const short*)inter;
    int rowA[4];
    #pragma unroll
    for (int jj = 0; jj < 4; ++jj){
        int slot = bm0 + w*32 + jj*8 + lr;
        if (slot >= ne) slot = ne - 1;
        rowA[jj] = obase + slot;
    }
    auto STAGE = [&](int buf, int kt){
        #pragma unroll
        for (int jj = 0; jj < 4; ++jj){
            gload16(As + (size_t)rowA[jj]*INTER_C + kt*64 + lc8, &lA[buf][(w*32 + jj*8)*64]);
            int n = w*32 + jj*8 + lr;
            gload16(Db + (size_t)(bn0 + n)*INTER_C + kt*64 + lc8, &lB[buf][(w*32 + jj*8)*64]);
        }
    };
    f32x4 acc[4][4] = {};
    STAGE(0, 0);
    for (int kt = 0; kt < 44; ++kt){
        const int cur = kt & 1;
        if (kt + 1 < 44){
            STAGE(cur ^ 1, kt + 1);
            asm volatile("s_waitcnt vmcnt(8)" ::: "memory");
        } else {
            asm volatile("s_waitcnt vmcnt(0)" ::: "memory");
        }
        __builtin_amdgcn_s_barrier();
        __builtin_amdgcn_sched_barrier(0);
        __builtin_amdgcn_s_setprio(1);
        #pragma unroll
        for (int kk = 0; kk < 64; kk += 32){
            s16x8 af[4], bfr[4];
            #pragma unroll
            for (int mi = 0; mi < 4; ++mi)
                af[mi] = *(const s16x8*)(&lA[cur][(wr*64 + mi*16 + (l&15))*64 + kk + (l>>4)*8]);
            #pragma unroll
            for (int ni = 0; ni < 4; ++ni){
                int n = wc*64 + ni*16 + (l&15);
                int key = n & 7;
                int ch = (kk>>3) + (l>>4);
                bfr[ni] = *(const s16x8*)(&lB[cur][n*64 + ((ch ^ key)<<3)]);
            }
            #pragma unroll
            for (int mi = 0; mi < 4; ++mi)
                #pragma unroll
                for (int ni = 0; ni < 4; ++ni)
                    acc[mi][ni] = __builtin_amdgcn_mfma_f32_16x16x32_bf16(af[mi], bfr[ni], acc[mi][ni], 0,0,0);
        }
        __builtin_amdgcn_s_setprio(0);
        __builtin_amdgcn_s_barrier();
    }
    #pragma unroll
    for (int mi = 0; mi < 4; ++mi)
        #pragma unroll
        for (int ni = 0; ni < 4; ++ni)
            #pragma unroll
            for (int rr = 0; rr < 4; ++rr){
                int slot = bm0 + wr*64 + mi*16 + (l>>4)*4 + rr;
                if (slot < ne){
                    int col = bn0 + wc*64 + ni*16 + (l&15);
                    int tok = lists[e*CAP + slot];
                    float wgt = wl[e*CAP + slot];
                    atomicAdd(&hres[(size_t)tok*HID_C + col], acc[mi][ni][rr]*wgt);
                }
            }
}

__global__ __launch_bounds__(256) void final_k(const float* __restrict__ hres,
                                               float* __restrict__ out){
    const int t = blockIdx.x, c = threadIdx.x*4;
    float4 hv = *(const float4*)(hres + (size_t)t*HID_C + c);
    *(float4*)(out + (size_t)t*HID_C + c) = hv;
}

// ======================= FALLBACK PATH (round-5, ws-lean) =======================
__global__ __launch_bounds__(64) void router_k(const float* __restrict__ h2f, const float* __restrict__ rw,
                                               int* __restrict__ lists, float* __restrict__ wl,
                                               int* __restrict__ cnt, float* __restrict__ psum){
    const int t = blockIdx.x, l = threadIdx.x;
    float lg[8] = {0,0,0,0,0,0,0,0};
    for (int c = 0; c < 16; ++c){
        int kidx = l + c*64;
        float x = h2f[(size_t)t*HID_C + kidx];
        float4 w0 = *(const float4*)(rw + (size_t)kidx*8);
        float4 w1 = *(const float4*)(rw + (size_t)kidx*8 + 4);
        lg[0] += x*w0.x; lg[1] += x*w0.y; lg[2] += x*w0.z; lg[3] += x*w0.w;
        lg[4] += x*w1.x; lg[5] += x*w1.y; lg[6] += x*w1.z; lg[7] += x*w1.w;
    }
    #pragma unroll
    for (int e = 0; e < 8; ++e)
        #pragma unroll
        for (int off=32; off; off>>=1) lg[e] += __shfl_xor(lg[e], off);
    if (l == 0){
        float m = lg[0];
        #pragma unroll
        for (int e = 1; e < 8; ++e) m = fmaxf(m, lg[e]);
        float p[8]; float s = 0.f;
        #pragma unroll
        for (int e = 0; e < 8; ++e){ p[e] = __expf(lg[e]-m); s += p[e]; }
        float invs = 1.f/s;
        #pragma unroll
        for (int e = 0; e < 8; ++e){ p[e] *= invs; atomicAdd(&psum[e], p[e]); }
        float best = -1e30f, sec = -1e30f; int bi = 0, si = 0;
        #pragma unroll
        for (int e = 0; e < 8; ++e){
            float pv = p[e];
            if (pv > best){ sec = best; si = bi; best = pv; bi = e; }
            else if (pv > sec){ sec = pv; si = e; }
        }
        float wsum = best + sec + 1e-9f;
        int s0 = atomicAdd(&cnt[bi], 1);
        lists[bi*CAP + s0] = t; wl[bi*CAP + s0] = best/wsum;
        int s1 = atomicAdd(&cnt[si], 1);
        lists[si*CAP + s1] = t; wl[si*CAP + s1] = sec/wsum;
    }
}

template<bool ALSO_BF16>
__global__ __launch_bounds__(256) void rmsnorm_f(const float* __restrict__ xin, const float* __restrict__ w,
                                                 float* __restrict__ outf, bf16* __restrict__ outb){
    const int t = blockIdx.x, tid = threadIdx.x;
    float4 v = *(const float4*)(xin + (size_t)t*HID_C + tid*4);
    float x[4] = {v.x, v.y, v.z, v.w};
    float s = x[0]*x[0]+x[1]*x[1]+x[2]*x[2]+x[3]*x[3];
    #pragma unroll
    for (int off=32; off; off>>=1) s += __shfl_xor(s, off);
    __shared__ float red[4];
    if ((tid&63)==0) red[tid>>6] = s;
    __syncthreads();
    float tot = red[0]+red[1]+red[2]+red[3];
    float sc = rsqrtf(tot*(1.0f/HID_C) + 1e-8f);
    float4 wv = *(const float4*)(w + tid*4);
    float o[4] = { x[0]*sc*wv.x, x[1]*sc*wv.y, x[2]*sc*wv.z, x[3]*sc*wv.w };
    *(float4*)(outf + (size_t)t*HID_C + tid*4) = make_float4(o[0],o[1],o[2],o[3]);
    if (ALSO_BF16){
        __align__(8) bf16 tmp[4] = { f2b(o[0]), f2b(o[1]), f2b(o[2]), f2b(o[3]) };
        *(uint2*)(outb + (size_t)t*HID_C + tid*4) = *(uint2*)tmp;
    }
}

template<bool RESID>
__global__ __launch_bounds__(256) void sgemm_f(const float* __restrict__ A, const float* __restrict__ B,
                                               float* __restrict__ C, const float* __restrict__ resid,
                                               int N, int K){
    __shared__ __align__(16) short lAh[128*40];
    __shared__ __align__(16) short lAl[128*40];
    __shared__ __align__(16) short lBh[128*40];
    __shared__ __align__(16) short lBl[128*40];
    const int tid = threadIdx.x;
    const int bm0 = blockIdx.x*128, bn0 = blockIdx.y*128;
    const int l = tid & 63, w = tid >> 6, wr = w >> 1, wc = w & 1;
    f32x4 acc[4][4] = {};
    for (int kt = 0; kt < K/32; ++kt){
        #pragma unroll
        for (int i = 0; i < 4; ++i){
            int u = tid + i*256;
            int r = u >> 3, c4 = (u & 7)*4;
            float4 v = *(const float4*)(A + (size_t)(bm0+r)*K + kt*32 + c4);
            SplitBF s0 = splitf(v.x), s1 = splitf(v.y), s2 = splitf(v.z), s3 = splitf(v.w);
            __align__(8) short hv[4] = { s0.hi, s1.hi, s2.hi, s3.hi };
            __align__(8) short lv[4] = { s0.lo, s1.lo, s2.lo, s3.lo };
            *(uint2*)(&lAh[r*40 + c4]) = *(uint2*)hv;
            *(uint2*)(&lAl[r*40 + c4]) = *(uint2*)lv;
        }
        #pragma unroll
        for (int i = 0; i < 4; ++i){
            int u = tid + i*256;
            int k = u >> 5, n0 = (u & 31)*4;
            float4 v = *(const float4*)(B + (size_t)(kt*32 + k)*N + bn0 + n0);
            SplitBF s0 = splitf(v.x), s1 = splitf(v.y), s2 = splitf(v.z), s3 = splitf(v.w);
            lBh[(n0+0)*40+k]=s0.hi; lBh[(n0+1)*40+k]=s1.hi; lBh[(n0+2)*40+k]=s2.hi; lBh[(n0+3)*40+k]=s3.hi;
            lBl[(n0+0)*40+k]=s0.lo; lBl[(n0+1)*40+k]=s1.lo; lBl[(n0+2)*40+k]=s2.lo; lBl[(n0+3)*40+k]=s3.lo;
        }
        __syncthreads();
        s16x8 ah[4], al[4], bh[4], bl[4];
        #pragma unroll
        for (int mi = 0; mi < 4; ++mi){
            int r = wr*64 + mi*16 + (l&15);
            ah[mi] = *(const s16x8*)(&lAh[r*40 + (l>>4)*8]);
            al[mi] = *(const s16x8*)(&lAl[r*40 + (l>>4)*8]);
        }
        #pragma unroll
        for (int ni = 0; ni < 4; ++ni){
            int n = wc*64 + ni*16 + (l&15);
            bh[ni] = *(const s16x8*)(&lBh[n*40 + (l>>4)*8]);
            bl[ni] = *(const s16x8*)(&lBl[n*40 + (l>>4)*8]);
        }
        #pragma unroll
        for (int mi = 0; mi < 4; ++mi)
            #pragma unroll
            for (int ni = 0; ni < 4; ++ni){
                acc[mi][ni] = __builtin_amdgcn_mfma_f32_16x16x32_bf16(ah[mi], bh[ni], acc[mi][ni], 0,0,0);
                acc[mi][ni] = __builtin_amdgcn_mfma_f32_16x16x32_bf16(ah[mi], bl[ni], acc[mi][ni], 0,0,0);
                acc[mi][ni] = __builtin_amdgcn_mfma_f32_16x16x32_bf16(al[mi], bh[ni], acc[mi][ni], 0,0,0);
            }
        __syncthreads();
    }
    #pragma unroll
    for (int mi = 0; mi < 4; ++mi)
        #pragma unroll
        for (int ni = 0; ni < 4; ++ni)
            #pragma unroll
            for (int rr = 0; rr < 4; ++rr){
                int row = bm0 + wr*64 + mi*16 + (l>>4)*4 + rr;
                int col = bn0 + wc*64 + ni*16 + (l&15);
                float vv = acc[mi][ni][rr];
                if (RESID) vv += resid[(size_t)row*N + col];
                C[(size_t)row*N + col] = vv;
            }
}

__global__ __launch_bounds__(256) void rope_f(float* __restrict__ qb, float* __restrict__ kb,
                                              const float* __restrict__ cosb, const float* __restrict__ sinb){
    int idx = blockIdx.x*256 + threadIdx.x;
    int t = idx / 640;
    int r = idx - t*640;
    int hs = r >> 5, tp = r & 31;
    int s = t & (S_LEN-1);
    float c  = cosb[s*32+tp];
    float sn = sinb[s*32+tp];
    float* base;
    if (hs < 16) base = qb + (size_t)t*1024 + hs*64 + 2*tp;
    else         base = kb + (size_t)t*256 + (hs-16)*64 + 2*tp;
    float2 v = *(float2*)base;
    *(float2*)base = make_float2(v.x*c - v.y*sn, v.x*sn + v.y*c);
}

__global__ __launch_bounds__(64) void attn_f(const float* __restrict__ qb, const float* __restrict__ kb,
                                             const float* __restrict__ vb, float* __restrict__ ob){
    const int l = threadIdx.x;
    const int bs = blockIdx.x;
    const int h = blockIdx.y, hk = h >> 2;
    const int sq = bs & (S_LEN-1);
    __shared__ float qs[64];
    __shared__ float ps[65];
    qs[l] = qb[(size_t)bs*1024 + h*64 + l];
    __syncthreads();
    const int j0 = (sq - WIN_C) > 0 ? (sq - WIN_C) : 0;
    const int nk = sq - j0 + 1;
    const int tokbase = bs - sq;
    float sc[2] = {-1e9f, -1e9f};
    #pragma unroll
    for (int it = 0; it < 2; ++it){
        int jj = l + it*64;
        if (jj < nk){
            const float* kp = kb + (size_t)(tokbase + j0 + jj)*256 + hk*64;
            float d = 0.f;
            #pragma unroll
            for (int c = 0; c < 16; ++c){
                float4 kv = *(const float4*)(kp + c*4);
                d += qs[c*4+0]*kv.x + qs[c*4+1]*kv.y + qs[c*4+2]*kv.z + qs[c*4+3]*kv.w;
            }
            sc[it] = d*0.125f;
        }
    }
    float m = fmaxf(sc[0], sc[1]);
    #pragma unroll
    for (int off=32; off; off>>=1) m = fmaxf(m, __shfl_xor(m, off));
    float e0 = (l      < nk) ? __expf(sc[0]-m) : 0.f;
    float e1 = (l + 64 < nk) ? __expf(sc[1]-m) : 0.f;
    float s = e0 + e1;
    #pragma unroll
    for (int off=32; off; off>>=1) s += __shfl_xor(s, off);
    float inv = 1.f/s;
    if (l      < nk) ps[l]    = e0*inv;
    if (l + 64 < nk) ps[l+64] = e1*inv;
    __syncthreads();
    float acc = 0.f;
    for (int jj = 0; jj < nk; ++jj)
        acc += ps[jj]*vb[(size_t)(tokbase + j0 + jj)*256 + hk*64 + l];
    ob[(size_t)bs*1024 + h*64 + l] = acc;
}

__global__ __launch_bounds__(256) void moe_mlp1_f(const bf16* __restrict__ h2b,
                                                  const float* __restrict__ gateW,
                                                  const float* __restrict__ upW,
                                                  bf16* __restrict__ inter,
                                                  const int* __restrict__ lists,
                                                  const int* __restrict__ cnt,
                                                  const int* __restrict__ offs){
    const int e = blockIdx.z;
    const int ne = cnt[e];
    const int bm0 = blockIdx.x*128;
    if (bm0 >= ne) return;
    const int bn0 = blockIdx.y*64;
    __shared__ __align__(16) short lA[128*72];
    __shared__ __align__(16) short lG[64*72];
    __shared__ __align__(16) short lU[64*72];
    const int tid = threadIdx.x;
    const int l = tid & 63, w = tid >> 6, wr = w >> 1, wc = w & 1;
    const size_t ebase = (size_t)e*HID_C*INTER_C;
    f32x4 ag[4][2] = {}; f32x4 au[4][2] = {};
    for (int kt = 0; kt < HID_C/64; ++kt){
        #pragma unroll
        for (int i = 0; i < 4; ++i){
            int u = tid + i*256;
            int r = u >> 3, cu = u & 7;
            int slot = bm0 + r;
            s16x8 v = {};
            if (slot < ne){
                int tok = lists[e*CAP + slot];
                v = *(const s16x8*)((const short*)h2b + (size_t)tok*HID_C + kt*64 + cu*8);
            }
            *(s16x8*)(&lA[r*72 + cu*8]) = v;
        }
        #pragma unroll
        for (int i = 0; i < 2; ++i){
            int u = tid + i*256;
            int k = u >> 3, n0 = (u & 7)*8;
            size_t gidx = ebase + (size_t)(kt*64 + k)*INTER_C + bn0 + n0;
            const float* gp = gateW + gidx;
            const float* up = upW + gidx;
            float4 ga = *(const float4*)gp, gb = *(const float4*)(gp+4);
            float4 ua = *(const float4*)up, ub = *(const float4*)(up+4);
            lG[(n0+0)*72+k]=f2bs(ga.x); lG[(n0+1)*72+k]=f2bs(ga.y); lG[(n0+2)*72+k]=f2bs(ga.z); lG[(n0+3)*72+k]=f2bs(ga.w);
            lG[(n0+4)*72+k]=f2bs(gb.x); lG[(n0+5)*72+k]=f2bs(gb.y); lG[(n0+6)*72+k]=f2bs(gb.z); lG[(n0+7)*72+k]=f2bs(gb.w);
            lU[(n0+0)*72+k]=f2bs(ua.x); lU[(n0+1)*72+k]=f2bs(ua.y); lU[(n0+2)*72+k]=f2bs(ua.z); lU[(n0+3)*72+k]=f2bs(ua.w);
            lU[(n0+4)*72+k]=f2bs(ub.x); lU[(n0+5)*72+k]=f2bs(ub.y); lU[(n0+6)*72+k]=f2bs(ub.z); lU[(n0+7)*72+k]=f2bs(ub.w);
        }
        __syncthreads();
        #pragma unroll
        for (int kk = 0; kk < 64; kk += 32){
            s16x8 af[4], bg[2], bu[2];
            #pragma unroll
            for (int mi = 0; mi < 4; ++mi)
                af[mi] = *(const s16x8*)(&lA[(wr*64 + mi*16 + (l&15))*72 + kk + (l>>4)*8]);
            #pragma unroll
            for (int ni = 0; ni < 2; ++ni){
                int n = wc*32 + ni*16 + (l&15);
                bg[ni] = *(const s16x8*)(&lG[n*72 + kk + (l>>4)*8]);
                bu[ni] = *(const s16x8*)(&lU[n*72 + kk + (l>>4)*8]);
            }
            #pragma unroll
            for (int mi = 0; mi < 4; ++mi)
                #pragma unroll
                for (int ni = 0; ni < 2; ++ni){
                    ag[mi][ni] = __builtin_amdgcn_mfma_f32_16x16x32_bf16(af[mi], bg[ni], ag[mi][ni], 0,0,0);
                    au[mi][ni] = __builtin_amdgcn_mfma_f32_16x16x32_bf16(af[mi], bu[ni], au[mi][ni], 0,0,0);
                }
        }
        __syncthreads();
    }
    const int obase = offs[e];
    #pragma unroll
    for (int mi = 0; mi < 4; ++mi)
        #pragma unroll
        for (int ni = 0; ni < 2; ++ni)
            #pragma unroll
            for (int rr = 0; rr < 4; ++rr){
                int slot = bm0 + wr*64 + mi*16 + (l>>4)*4 + rr;
                if (slot < ne){
                    int col = bn0 + wc*32 + ni*16 + (l&15);
                    float g = ag[mi][ni][rr], uu = au[mi][ni][rr];
                    float val = (g/(1.f+__expf(-g)))*uu;
                    inter[(size_t)(obase+slot)*INTER_C + col] = f2b(val);
                }
            }
}

__global__ __launch_bounds__(256) void moe_mlp2_f(const bf16* __restrict__ inter,
                                                  const float* __restrict__ downW,
                                                  float* __restrict__ hres,
                                                  const float* __restrict__ wl,
                                                  const int* __restrict__ lists,
                                                  const int* __restrict__ cnt,
                                                  const int* __restrict__ offs){
    const int e = blockIdx.z;
    const int ne = cnt[e];
    const int bm0 = blockIdx.x*128;
    if (bm0 >= ne) return;
    const int bn0 = blockIdx.y*128;
    __shared__ __align__(16) short lA[128*72];
    __shared__ __align__(16) short lB[128*72];
    const int tid = threadIdx.x;
    const int l = tid & 63, w = tid >> 6, wr = w >> 1, wc = w & 1;
    const int obase = offs[e];
    const size_t ebase = (size_t)e*INTER_C*HID_C;
    f32x4 acc[4][4] = {};
    for (int kt = 0; kt < INTER_C/64; ++kt){
        #pragma unroll
        for (int i = 0; i < 4; ++i){
            int u = tid + i*256;
            int r = u >> 3, cu = u & 7;
            int slot = bm0 + r;
            s16x8 v = {};
            if (slot < ne)
                v = *(const s16x8*)((const short*)inter + (size_t)(obase + slot)*INTER_C + kt*64 + cu*8);
            *(s16x8*)(&lA[r*72 + cu*8]) = v;
        }
        #pragma unroll
        for (int i = 0; i < 4; ++i){
            int u = tid + i*256;
            int k = u >> 4, n0 = (u & 15)*8;
            const float* bp = downW + ebase + (size_t)(kt*64 + k)*HID_C + bn0 + n0;
            float4 a = *(const float4*)bp, b = *(const float4*)(bp+4);
            lB[(n0+0)*72+k]=f2bs(a.x); lB[(n0+1)*72+k]=f2bs(a.y); lB[(n0+2)*72+k]=f2bs(a.z); lB[(n0+3)*72+k]=f2bs(a.w);
            lB[(n0+4)*72+k]=f2bs(b.x); lB[(n0+5)*72+k]=f2bs(b.y); lB[(n0+6)*72+k]=f2bs(b.z); lB[(n0+7)*72+k]=f2bs(b.w);
        }
        __syncthreads();
        #pragma unroll
        for (int kk = 0; kk < 64; kk += 32){
            s16x8 af[4], bfr[4];
            #pragma unroll
            for (int mi = 0; mi < 4; ++mi)
                af[mi] = *(const s16x8*)(&lA[(wr*64 + mi*16 + (l&15))*72 + kk + (l>>4)*8]);
            #pragma unroll
            for (int ni = 0; ni < 4; ++ni){
                int n = wc*64 + ni*16 + (l&15);
                bfr[ni] = *(const s16x8*)(&lB[n*72 + kk + (l>>4)*8]);
            }
            #pragma unroll
            for (int mi = 0; mi < 4; ++mi)
                #pragma unroll
                for (int ni = 0; ni < 4; ++ni)
                    acc[mi][ni] = __builtin_amdgcn_mfma_f32_16x16x32_bf16(af[mi], bfr[ni], acc[mi][ni], 0,0,0);
        }
        __syncthreads();
    }
    #pragma unroll
    for (int mi = 0; mi < 4; ++mi)
        #pragma unroll
        for (int ni = 0; ni < 4; ++ni)
            #pragma unroll
            for (int rr = 0; rr < 4; ++rr){
                int slot = bm0 + wr*64 + mi*16 + (l>>4)*4 + rr;
                if (slot < ne){
                    int col = bn0 + wc*64 + ni*16 + (l&15);
                    int tok = lists[e*CAP + slot];
                    float wgt = wl[e*CAP + slot];
                    atomicAdd(&hres[(size_t)tok*HID_C + col], acc[mi][ni][rr]*wgt);
                }
            }
}

// ======================= HOST =======================
extern "C" void kernel_launch(void* const* d_in, const int* in_sizes, int n_in,
                              void* d_out, int out_size, void* d_ws, size_t ws_size,
                              hipStream_t stream){
    const float* hidden  = (const float*)d_in[0];
    const float* fcos    = (const float*)d_in[1];
    const float* fsin    = (const float*)d_in[2];
    const float* wq      = (const float*)d_in[3];
    const float* wk      = (const float*)d_in[4];
    const float* wv      = (const float*)d_in[5];
    const float* wo      = (const float*)d_in[6];
    const float* routerw = (const float*)d_in[7];
    const float* gatew   = (const float*)d_in[8];
    const float* upw     = (const float*)d_in[9];
    const float* downw   = (const float*)d_in[10];
    const float* n1w     = (const float*)d_in[11];
    const float* n2w     = (const float*)d_in[12];

    char* p = (char*)d_ws;
    size_t off = 0;
    auto alloc = [&](size_t b)->void*{ void* r = p + off; off = (off + b + 255) & ~(size_t)255; return r; };

    // ---- big-path layout ----
    int*   cnt    = (int*)alloc(64);
    float* psum   = (float*)alloc(64);
    int*   offs   = (int*)alloc(64);
    int*   lists  = (int*)alloc((size_t)E_C*CAP*4);
    float* wl     = (float*)alloc((size_t)E_C*CAP*4);
    short* wqkv2  = (short*)alloc((size_t)NQKV*K2C*2);        // combined hi/lo, swizzled
    short* wo2    = (short*)alloc((size_t)HID_C*K2C*2);
    short* gate_t = (short*)alloc((size_t)E_C*INTER_C*HID_C*2);
    short* up_t   = (short*)alloc((size_t)E_C*INTER_C*HID_C*2);
    short* down_t = (short*)alloc((size_t)E_C*HID_C*INTER_C*2);
    short* h1c    = (short*)alloc((size_t)NTOK*K2C*2);        // norm1 combined swizzled; reused as attn-out
    float* qkvf   = (float*)alloc((size_t)NTOK*NQKV*4);       // later h2f + h2b
    float* hres   = (float*)alloc((size_t)NTOK*HID_C*4);
    bf16*  inter  = (bf16*)alloc((size_t)2*NTOK*INTER_C*2);
    size_t need_big = off;

    if (ws_size >= need_big){
        short* oc  = h1c;
        float* h2f = qkvf;
        bf16*  h2b = (bf16*)(qkvf + (size_t)NTOK*HID_C);

        (void)hipMemsetAsync(cnt, 0, 64, stream);
        (void)hipMemsetAsync(psum, 0, 64, stream);

        // prepass transposes (swizzled)
        tsplit2s_k<<<dim3(32,32), 256, 0, stream>>>(wq, wqkv2, 1024, 0);
        tsplit2s_k<<<dim3(8,32),  256, 0, stream>>>(wk, wqkv2, 256, 1024);
        tsplit2s_k<<<dim3(8,32),  256, 0, stream>>>(wv, wqkv2, 256, 1280);
        tsplit2s_k<<<dim3(32,32), 256, 0, stream>>>(wo, wo2, 1024, 0);
        tbf16s_k<<<dim3(88,32,8), 256, 0, stream>>>(gatew, gate_t, 1024, 2816);
        tbf16s_k<<<dim3(88,32,8), 256, 0, stream>>>(upw,   up_t,   1024, 2816);
        tbf16s_k<<<dim3(32,88,8), 256, 0, stream>>>(downw, down_t, 2816, 1024);

        rmsn1c_k<<<NTOK, 256, 0, stream>>>(hidden, n1w, h1c);
        sgemm4_k<false><<<dim3(32,12), 256, 0, stream>>>(h1c, wqkv2, qkvf, nullptr, NQKV);
        rope2_k<<<10240, 256, 0, stream>>>(qkvf, fcos, fsin);
        attn2c_k<<<dim3(NTOK,16), 64, 0, stream>>>(qkvf, oc);
        sgemm4_k<true><<<dim3(32,8), 256, 0, stream>>>(oc, wo2, hres, hidden, 1024);
        rmsn2_k<<<NTOK, 256, 0, stream>>>(hres, n2w, h2f, h2b);
        router2_k<<<256, 256, 0, stream>>>(h2f, routerw, lists, wl, cnt, psum);
        finalize_k<<<1, 64, 0, stream>>>(cnt, psum, offs, (float*)d_out);
        moe1g3_k<<<11264, 256, 0, stream>>>((const short*)h2b, gate_t, up_t, inter, lists, cnt, offs);
        moe2g3_k<<<2048, 256, 0, stream>>>(inter, down_t, hres, wl, lists, cnt, offs);
        final_k<<<NTOK, 256, 0, stream>>>(hres, (float*)d_out);
        return;
    }

    // ---- fallback (round-5) layout ----
    off = 0;
    cnt    = (int*)alloc(64);
    psum   = (float*)alloc(64);
    offs   = (int*)alloc(64);
    lists  = (int*)alloc((size_t)E_C*CAP*4);
    wl     = (float*)alloc((size_t)E_C*CAP*4);
    float* h1  = (float*)alloc((size_t)NTOK*HID_C*4);
    float* qb  = (float*)alloc((size_t)NTOK*HID_C*4);
    float* kb  = (float*)alloc((size_t)NTOK*256*4);
    float* vb  = (float*)alloc((size_t)NTOK*256*4);
    float* hresF = (float*)alloc((size_t)NTOK*HID_C*4);
    bf16*  h2bF  = (bf16*)alloc((size_t)NTOK*HID_C*2);
    bf16*  interF= (bf16*)alloc((size_t)2*NTOK*INTER_C*2);
    float* attnb = h1;
    float* h2fF  = qb;

    (void)hipMemsetAsync(cnt, 0, 64, stream);
    (void)hipMemsetAsync(psum, 0, 64, stream);

    rmsnorm_f<false><<<NTOK, 256, 0, stream>>>(hidden, n1w, h1, nullptr);
    sgemm_f<false><<<dim3(32, 8), 256, 0, stream>>>(h1, wq, qb, nullptr, 1024, 1024);
    sgemm_f<false><<<dim3(32, 2), 256, 0, stream>>>(h1, wk, kb, nullptr, 256, 1024);
    sgemm_f<false><<<dim3(32, 2), 256, 0, stream>>>(h1, wv, vb, nullptr, 256, 1024);
    rope_f<<<10240, 256, 0, stream>>>(qb, kb, fcos, fsin);
    attn_f<<<dim3(NTOK, 16), 64, 0, stream>>>(qb, kb, vb, attnb);
    sgemm_f<true><<<dim3(32, 8), 256, 0, stream>>>(attnb, wo, hresF, hidden, 1024, 1024);
    rmsnorm_f<true><<<NTOK, 256, 0, stream>>>(hresF, n2w, h2fF, h2bF);
    router_k<<<NTOK, 64, 0, stream>>>(h2fF, routerw, lists, wl, cnt, psum);
    finalize_k<<<1, 64, 0, stream>>>(cnt, psum, offs, (float*)d_out);
    moe_mlp1_f<<<dim3(32, 44, 8), 256, 0, stream>>>(h2bF, gatew, upw, interF, lists, cnt, offs);
    moe_mlp2_f<<<dim3(32, 8, 8), 256, 0, stream>>>(interF, downw, hresF, wl, lists, cnt, offs);
    final_k<<<NTOK, 256, 0, stream>>>(hresF, (float*)d_out);
}

// Round 12
// 696.722 us; speedup vs baseline: 4.6344x; 1.1642x over previous
//
#include <hip/hip_runtime.h>
#include <hip/hip_bf16.h>
#include <math.h>

typedef short s16x8 __attribute__((ext_vector_type(8)));
typedef float f32x4 __attribute__((ext_vector_type(4)));
typedef __hip_bfloat16 bf16;

#define NTOK 4096
#define S_LEN 2048
#define HID_C 1024
#define E_C 8
#define INTER_C 2816
#define WIN_C 64
#define CAP 4096
#define NQKV 1536
#define K2C 2048
#define ATILE 16
#define KR 80
#define OUT0_N ((size_t)NTOK*HID_C)

#define AS1 __attribute__((address_space(1)))
#define AS3 __attribute__((address_space(3)))

static __device__ __forceinline__ void gload16(const void* g, void* l){
    __builtin_amdgcn_global_load_lds((AS1 void*)(g), (AS3 void*)(l), 16, 0, 0);
}

static __device__ __forceinline__ float b2f(bf16 v){ return __bfloat162float(v); }
static __device__ __forceinline__ bf16  f2b(float v){ return __float2bfloat16(v); }
static __device__ __forceinline__ short f2bs(float v){ bf16 h = __float2bfloat16(v); return *reinterpret_cast<short*>(&h); }
struct SplitBF { short hi; short lo; };
static __device__ __forceinline__ SplitBF splitf(float x){
    SplitBF r;
    bf16 bh = __float2bfloat16(x);
    r.hi = *reinterpret_cast<short*>(&bh);
    float rem = x - __bfloat162float(bh);
    bf16 bl = __float2bfloat16(rem);
    r.lo = *reinterpret_cast<short*>(&bl);
    return r;
}

// Swizzle convention: within each 64-short (128B) group of a row, logical
// 8-short chunk c is stored at physical chunk c ^ (row & 7).

// ============ PREPASS: f32 [1024][N] -> combined hi/lo [row_off+n][2048], swizzled ============
__global__ __launch_bounds__(256) void tsplit2s_k(const float* __restrict__ src,
                                                  short* __restrict__ dst,
                                                  int N, int row_off){
    __shared__ float tile[32][33];
    const int n0 = blockIdx.x*32, k0 = blockIdx.y*32;
    const int tx = threadIdx.x & 31, ty = threadIdx.x >> 5;
    #pragma unroll
    for (int i = 0; i < 4; ++i)
        tile[ty + i*8][tx] = src[(size_t)(k0 + ty + i*8)*N + n0 + tx];
    __syncthreads();
    const int g = k0 >> 5;
    const int chH = tx >> 3, chL = 4 | (tx >> 3), off = tx & 7;
    #pragma unroll
    for (int i = 0; i < 4; ++i){
        int nn = ty + i*8;
        SplitBF s = splitf(tile[tx][nn]);
        size_t rowb = (size_t)(row_off + n0 + nn)*K2C + g*64;
        dst[rowb + ((chH ^ ty)<<3) + off] = s.hi;
        dst[rowb + ((chL ^ ty)<<3) + off] = s.lo;
    }
}

// f32 [e][K][N] -> bf16 [e][N][K], swizzled
__global__ __launch_bounds__(256) void tbf16s_k(const float* __restrict__ src0,
                                                short* __restrict__ dst0, int K, int N){
    const int e = blockIdx.z;
    const float* src = src0 + (size_t)e*K*N;
    short* dst = dst0 + (size_t)e*N*K;
    __shared__ float tile[32][33];
    const int n0 = blockIdx.x*32, k0 = blockIdx.y*32;
    const int tx = threadIdx.x & 31, ty = threadIdx.x >> 5;
    #pragma unroll
    for (int i = 0; i < 4; ++i)
        tile[ty + i*8][tx] = src[(size_t)(k0 + ty + i*8)*N + n0 + tx];
    __syncthreads();
    const int grp  = k0 >> 6;
    const int half = (k0 & 32) >> 3;
    const int ch   = half + (tx >> 3), off = tx & 7;
    #pragma unroll
    for (int i = 0; i < 4; ++i){
        int nn = ty + i*8;
        dst[(size_t)(n0 + nn)*K + grp*64 + ((ch ^ ty)<<3) + off] = f2bs(tile[tx][nn]);
    }
}

// ================= RMSNorm: f32 in -> combined hi/lo out (swizzled) =================
__global__ __launch_bounds__(256) void rmsn1c_k(const float* __restrict__ xin,
                                                const float* __restrict__ w,
                                                short* __restrict__ oc){
    const int t = blockIdx.x, tid = threadIdx.x;
    float4 v = *(const float4*)(xin + (size_t)t*HID_C + tid*4);
    float x[4] = {v.x, v.y, v.z, v.w};
    float s = x[0]*x[0]+x[1]*x[1]+x[2]*x[2]+x[3]*x[3];
    #pragma unroll
    for (int off=32; off; off>>=1) s += __shfl_xor(s, off);
    __shared__ float red[4];
    if ((tid&63)==0) red[tid>>6] = s;
    __syncthreads();
    float tot = red[0]+red[1]+red[2]+red[3];
    float sc = rsqrtf(tot*(1.0f/HID_C) + 1e-8f);
    float4 wv = *(const float4*)(w + tid*4);
    float o[4] = { x[0]*sc*wv.x, x[1]*sc*wv.y, x[2]*sc*wv.z, x[3]*sc*wv.w };
    __align__(8) short th[4], tl[4];
    #pragma unroll
    for (int i=0;i<4;++i){ SplitBF sp = splitf(o[i]); th[i]=sp.hi; tl[i]=sp.lo; }
    const int g = tid>>3, q = tid&7;
    const int ch = q>>1, sub = (q&1)*4, key = t&7;
    short* rowp = oc + (size_t)t*K2C + g*64;
    *(uint2*)(rowp + ((ch ^ key)<<3) + sub)      = *(uint2*)th;
    *(uint2*)(rowp + (((4|ch) ^ key)<<3) + sub)  = *(uint2*)tl;
}

// norm2: f32 in -> f32 out + bf16 out
__global__ __launch_bounds__(256) void rmsn2_k(const float* __restrict__ xin,
                                               const float* __restrict__ w,
                                               float* __restrict__ outf, bf16* __restrict__ outb){
    const int t = blockIdx.x, tid = threadIdx.x;
    float4 v = *(const float4*)(xin + (size_t)t*HID_C + tid*4);
    float x[4] = {v.x, v.y, v.z, v.w};
    float s = x[0]*x[0]+x[1]*x[1]+x[2]*x[2]+x[3]*x[3];
    #pragma unroll
    for (int off=32; off; off>>=1) s += __shfl_xor(s, off);
    __shared__ float red[4];
    if ((tid&63)==0) red[tid>>6] = s;
    __syncthreads();
    float tot = red[0]+red[1]+red[2]+red[3];
    float sc = rsqrtf(tot*(1.0f/HID_C) + 1e-8f);
    float4 wv = *(const float4*)(w + tid*4);
    float o[4] = { x[0]*sc*wv.x, x[1]*sc*wv.y, x[2]*sc*wv.z, x[3]*sc*wv.w };
    *(float4*)(outf + (size_t)t*HID_C + tid*4) = make_float4(o[0],o[1],o[2],o[3]);
    __align__(8) bf16 tmp[4] = { f2b(o[0]), f2b(o[1]), f2b(o[2]), f2b(o[3]) };
    *(uint2*)(outb + (size_t)t*HID_C + tid*4) = *(uint2*)tmp;
}

// ============ split GEMM: dbuf gload16 + counted vmcnt + swizzled reads ============
template<bool RESID>
__global__ __launch_bounds__(256) void sgemm4_k(const short* __restrict__ A2,
                                                const short* __restrict__ B2,
                                                float* __restrict__ C, const float* __restrict__ resid,
                                                int N){
    __shared__ __align__(16) short lA[2][128*64];
    __shared__ __align__(16) short lB[2][128*64];
    const int tid = threadIdx.x;
    const int bm0 = blockIdx.x*128, bn0 = blockIdx.y*128;
    const int l = tid & 63, w = tid >> 6, wr = w >> 1, wc = w & 1;
    const int lr = l >> 3, lc8 = (l & 7)*8;
    f32x4 acc[4][4] = {};
    auto STAGE = [&](int buf, int kt){
        #pragma unroll
        for (int j = 0; j < 4; ++j){
            int row = w*32 + j*8 + lr;
            gload16(A2 + (size_t)(bm0 + row)*K2C + kt*64 + lc8, &lA[buf][(w*32 + j*8)*64]);
            gload16(B2 + (size_t)(bn0 + row)*K2C + kt*64 + lc8, &lB[buf][(w*32 + j*8)*64]);
        }
    };
    STAGE(0, 0);
    for (int kt = 0; kt < 32; ++kt){
        const int cur = kt & 1;
        if (kt + 1 < 32){
            STAGE(cur ^ 1, kt + 1);
            asm volatile("s_waitcnt vmcnt(8)" ::: "memory");
        } else {
            asm volatile("s_waitcnt vmcnt(0)" ::: "memory");
        }
        __builtin_amdgcn_s_barrier();
        __builtin_amdgcn_sched_barrier(0);
        s16x8 ah[4], al[4], bh[4], bl[4];
        #pragma unroll
        for (int mi = 0; mi < 4; ++mi){
            int r = wr*64 + mi*16 + (l&15);
            int key = r & 7;
            ah[mi] = *(const s16x8*)(&lA[cur][r*64 + (((l>>4) ^ key)<<3)]);
            al[mi] = *(const s16x8*)(&lA[cur][r*64 + (((4|(l>>4)) ^ key)<<3)]);
        }
        #pragma unroll
        for (int ni = 0; ni < 4; ++ni){
            int n = wc*64 + ni*16 + (l&15);
            int key = n & 7;
            bh[ni] = *(const s16x8*)(&lB[cur][n*64 + (((l>>4) ^ key)<<3)]);
            bl[ni] = *(const s16x8*)(&lB[cur][n*64 + (((4|(l>>4)) ^ key)<<3)]);
        }
        #pragma unroll
        for (int mi = 0; mi < 4; ++mi)
            #pragma unroll
            for (int ni = 0; ni < 4; ++ni){
                acc[mi][ni] = __builtin_amdgcn_mfma_f32_16x16x32_bf16(ah[mi], bh[ni], acc[mi][ni], 0,0,0);
                acc[mi][ni] = __builtin_amdgcn_mfma_f32_16x16x32_bf16(ah[mi], bl[ni], acc[mi][ni], 0,0,0);
                acc[mi][ni] = __builtin_amdgcn_mfma_f32_16x16x32_bf16(al[mi], bh[ni], acc[mi][ni], 0,0,0);
            }
        __builtin_amdgcn_s_barrier();
    }
    #pragma unroll
    for (int mi = 0; mi < 4; ++mi)
        #pragma unroll
        for (int ni = 0; ni < 4; ++ni)
            #pragma unroll
            for (int rr = 0; rr < 4; ++rr){
                int row = bm0 + wr*64 + mi*16 + (l>>4)*4 + rr;
                int col = bn0 + wc*64 + ni*16 + (l&15);
                float vv = acc[mi][ni][rr];
                if (RESID) vv += resid[(size_t)row*N + col];
                C[(size_t)row*N + col] = vv;
            }
}

// ================ RoPE on packed qkv f32 [tok][1536] ================
__global__ __launch_bounds__(256) void rope2_k(float* __restrict__ qkv,
                                               const float* __restrict__ cosb, const float* __restrict__ sinb){
    int idx = blockIdx.x*256 + threadIdx.x;
    int t = idx / 640;
    int r = idx - t*640;
    int hs = r >> 5, tp = r & 31;
    int s = t & (S_LEN-1);
    float c  = cosb[s*32+tp];
    float sn = sinb[s*32+tp];
    float* base;
    if (hs < 16) base = qkv + (size_t)t*NQKV + hs*64 + 2*tp;
    else         base = qkv + (size_t)t*NQKV + 1024 + (hs-16)*64 + 2*tp;
    float2 v = *(float2*)base;
    *(float2*)base = make_float2(v.x*c - v.y*sn, v.x*sn + v.y*c);
}

// ======== tiled shared-KV attention: block=(16-token tile, kv group), 4 waves=4 heads ========
__global__ __launch_bounds__(256) void attn3_k(const float* __restrict__ qkv,
                                               short* __restrict__ oc){
    const int t0 = blockIdx.x * ATILE;          // global token base
    const int hk = blockIdx.y;                  // kv group
    const int sq0 = t0 & (S_LEN-1);
    const int tokbase = t0 - sq0;
    const int tid = threadIdx.x, l = tid & 63, w = tid >> 6;
    __shared__ float Kl[KR*65];
    __shared__ float Vl[KR*65];
    __shared__ float qsh[4][64];
    __shared__ float ps[4][64];
    // stage K/V window rows r: key pos kp = sq0-64+r, r in [0,80)
    for (int rr = tid >> 4; rr < KR; rr += 16){
        int c4 = (tid & 15)*4;
        int kp = sq0 - 64 + rr;
        float4 kv = make_float4(0,0,0,0), vv = kv;
        if (kp >= 0){
            const float* base = qkv + (size_t)(tokbase + kp)*NQKV + 1024 + hk*64 + c4;
            kv = *(const float4*)base;
            vv = *(const float4*)(base + 256);
        }
        Kl[rr*65 + c4+0]=kv.x; Kl[rr*65 + c4+1]=kv.y; Kl[rr*65 + c4+2]=kv.z; Kl[rr*65 + c4+3]=kv.w;
        Vl[rr*65 + c4+0]=vv.x; Vl[rr*65 + c4+1]=vv.y; Vl[rr*65 + c4+2]=vv.z; Vl[rr*65 + c4+3]=vv.w;
    }
    __syncthreads();
    const int h = hk*4 + w;
    for (int i = 0; i < ATILE; ++i){
        const int t = t0 + i, sq = sq0 + i;
        qsh[w][l] = qkv[(size_t)t*NQKV + h*64 + l];
        // (same-wave LDS write->read; compiler inserts lgkmcnt)
        // scores: lane l handles key row i+l (pos sq-64+l); diagonal row i+64 via reduce
        float d = 0.f;
        const float* krow = &Kl[(i + l)*65];
        #pragma unroll
        for (int c = 0; c < 64; ++c) d += qsh[w][c] * krow[c];
        const bool valid = (sq - 64 + l) >= 0;
        float sc = valid ? d*0.125f : -1e30f;
        float part = qsh[w][l] * Kl[(i + 64)*65 + l];
        #pragma unroll
        for (int off = 32; off; off >>= 1) part += __shfl_xor(part, off);
        float dg = part*0.125f;
        float m = sc;
        #pragma unroll
        for (int off = 32; off; off >>= 1) m = fmaxf(m, __shfl_xor(m, off));
        m = fmaxf(m, dg);
        float e = __expf(sc - m);
        float ssum = e;
        #pragma unroll
        for (int off = 32; off; off >>= 1) ssum += __shfl_xor(ssum, off);
        float edg = __expf(dg - m);
        ssum += edg;
        float inv = 1.f / ssum;
        ps[w][l] = e * inv;
        float pdg = edg * inv;
        // PV: lane l = output dim l
        float acc = 0.f;
        #pragma unroll 8
        for (int jj = 0; jj < 64; ++jj) acc += ps[w][jj] * Vl[(i + jj)*65 + l];
        acc += pdg * Vl[(i + 64)*65 + l];
        // write split hi/lo swizzled
        SplitBF sp = splitf(acc);
        const int k = h*64 + l;
        const int g = k>>5, ch = (k&31)>>3, off2 = k&7, key = t&7;
        short* rowp = oc + (size_t)t*K2C + g*64;
        rowp[((ch ^ key)<<3) + off2]     = sp.hi;
        rowp[(((4|ch) ^ key)<<3) + off2] = sp.lo;
    }
}

// ================= router v2: 16 tokens/block, LDS-aggregated atomics =================
__global__ __launch_bounds__(256) void router2_k(const float* __restrict__ h2f, const float* __restrict__ rw,
                                                 int* __restrict__ lists, float* __restrict__ wl,
                                                 int* __restrict__ cnt, float* __restrict__ psum){
    const int tid = threadIdx.x, l = tid & 63, w = tid >> 6;
    __shared__ int   sE0[16], sE1[16], sSlot0[16], sSlot1[16];
    __shared__ float sW0[16], sW1[16];
    __shared__ float sPsum[8];
    __shared__ int   sCnt[8], sBase[8];
    if (tid < 8){ sPsum[tid] = 0.f; sCnt[tid] = 0; }
    __syncthreads();
    #pragma unroll
    for (int i = 0; i < 4; ++i){
        const int li = w*4 + i;
        const int t = blockIdx.x*16 + li;
        float lg[8] = {0,0,0,0,0,0,0,0};
        for (int c = 0; c < 16; ++c){
            int kidx = l + c*64;
            float x = h2f[(size_t)t*HID_C + kidx];
            float4 w0 = *(const float4*)(rw + (size_t)kidx*8);
            float4 w1 = *(const float4*)(rw + (size_t)kidx*8 + 4);
            lg[0] += x*w0.x; lg[1] += x*w0.y; lg[2] += x*w0.z; lg[3] += x*w0.w;
            lg[4] += x*w1.x; lg[5] += x*w1.y; lg[6] += x*w1.z; lg[7] += x*w1.w;
        }
        #pragma unroll
        for (int e = 0; e < 8; ++e)
            #pragma unroll
            for (int off=32; off; off>>=1) lg[e] += __shfl_xor(lg[e], off);
        if (l == 0){
            float m = lg[0];
            #pragma unroll
            for (int e = 1; e < 8; ++e) m = fmaxf(m, lg[e]);
            float p[8]; float s = 0.f;
            #pragma unroll
            for (int e = 0; e < 8; ++e){ p[e] = __expf(lg[e]-m); s += p[e]; }
            float invs = 1.f/s;
            #pragma unroll
            for (int e = 0; e < 8; ++e){ p[e] *= invs; atomicAdd(&sPsum[e], p[e]); }
            float best = -1e30f, sec = -1e30f; int bi = 0, si = 0;
            #pragma unroll
            for (int e = 0; e < 8; ++e){
                float pv = p[e];
                if (pv > best){ sec = best; si = bi; best = pv; bi = e; }
                else if (pv > sec){ sec = pv; si = e; }
            }
            float wsum = best + sec + 1e-9f;
            sE0[li] = bi; sE1[li] = si;
            sW0[li] = best/wsum; sW1[li] = sec/wsum;
            sSlot0[li] = atomicAdd(&sCnt[bi], 1);
            sSlot1[li] = atomicAdd(&sCnt[si], 1);
        }
    }
    __syncthreads();
    if (tid < 8){
        sBase[tid] = atomicAdd(&cnt[tid], sCnt[tid]);
        atomicAdd(&psum[tid], sPsum[tid]);
    }
    __syncthreads();
    if (tid < 16){
        int t = blockIdx.x*16 + tid;
        int e0 = sE0[tid], e1 = sE1[tid];
        int s0 = sBase[e0] + sSlot0[tid];
        int s1 = sBase[e1] + sSlot1[tid];
        lists[e0*CAP + s0] = t; wl[e0*CAP + s0] = sW0[tid];
        lists[e1*CAP + s1] = t; wl[e1*CAP + s1] = sW1[tid];
    }
}

__global__ void finalize_k(const int* __restrict__ cnt, const float* __restrict__ psum,
                           int* __restrict__ offs, float* __restrict__ out){
    if (threadIdx.x == 0 && blockIdx.x == 0){
        int o = 0; float loss = 0.f;
        for (int e = 0; e < 8; ++e){
            offs[e] = o; o += cnt[e];
            loss += (psum[e]*(1.0f/NTOK)) * ((float)cnt[e]*(1.0f/NTOK));
        }
        offs[8] = o;
        out[OUT0_N] = loss * (float)E_C * 0.01f;
    }
}

// ============ MoE gate/up: XCD panel-grouped 1-D grid, dbuf gload16, setprio ============
__global__ __launch_bounds__(256) void moe1g3_k(const short* __restrict__ h2b,
                                                const short* __restrict__ gate_t,
                                                const short* __restrict__ up_t,
                                                bf16* __restrict__ inter,
                                                const int* __restrict__ lists,
                                                const int* __restrict__ cnt,
                                                const int* __restrict__ offs){
    const int b = blockIdx.x;
    const int r = b & 7, j = b >> 3;
    const int G = r + ((j >> 5) << 3);
    const int e = G / 44, bnG = G % 44;
    const int bm0 = (j & 31) * 128;
    const int ne = cnt[e];
    if (bm0 >= ne) return;
    const int bn0 = bnG * 64;
    __shared__ __align__(16) short lA[2][128*64];
    __shared__ __align__(16) short lG[2][64*64];
    __shared__ __align__(16) short lU[2][64*64];
    const int tid = threadIdx.x;
    const int l = tid & 63, w = tid >> 6, wr = w >> 1, wc = w & 1;
    const int lr = l >> 3, lc8 = (l & 7)*8;
    const short* Gb = gate_t + (size_t)e*INTER_C*HID_C;
    const short* Ub = up_t   + (size_t)e*INTER_C*HID_C;
    int tokA[4];
    #pragma unroll
    for (int jj = 0; jj < 4; ++jj){
        int slot = bm0 + w*32 + jj*8 + lr;
        if (slot >= ne) slot = ne - 1;
        tokA[jj] = lists[e*CAP + slot];
    }
    auto STAGE = [&](int buf, int kt){
        #pragma unroll
        for (int jj = 0; jj < 4; ++jj)
            gload16(h2b + (size_t)tokA[jj]*HID_C + kt*64 + lc8, &lA[buf][(w*32 + jj*8)*64]);
        #pragma unroll
        for (int jj = 0; jj < 2; ++jj){
            int n = w*16 + jj*8 + lr;
            gload16(Gb + (size_t)(bn0 + n)*HID_C + kt*64 + lc8, &lG[buf][(w*16 + jj*8)*64]);
            gload16(Ub + (size_t)(bn0 + n)*HID_C + kt*64 + lc8, &lU[buf][(w*16 + jj*8)*64]);
        }
    };
    f32x4 ag[4][2] = {}; f32x4 au[4][2] = {};
    STAGE(0, 0);
    for (int kt = 0; kt < 16; ++kt){
        const int cur = kt & 1;
        if (kt + 1 < 16){
            STAGE(cur ^ 1, kt + 1);
            asm volatile("s_waitcnt vmcnt(8)" ::: "memory");
        } else {
            asm volatile("s_waitcnt vmcnt(0)" ::: "memory");
        }
        __builtin_amdgcn_s_barrier();
        __builtin_amdgcn_sched_barrier(0);
        __builtin_amdgcn_s_setprio(1);
        #pragma unroll
        for (int kk = 0; kk < 64; kk += 32){
            s16x8 af[4], bg[2], bu[2];
            #pragma unroll
            for (int mi = 0; mi < 4; ++mi)
                af[mi] = *(const s16x8*)(&lA[cur][(wr*64 + mi*16 + (l&15))*64 + kk + (l>>4)*8]);
            #pragma unroll
            for (int ni = 0; ni < 2; ++ni){
                int n = wc*32 + ni*16 + (l&15);
                int key = n & 7;
                int ch = (kk>>3) + (l>>4);
                bg[ni] = *(const s16x8*)(&lG[cur][n*64 + ((ch ^ key)<<3)]);
                bu[ni] = *(const s16x8*)(&lU[cur][n*64 + ((ch ^ key)<<3)]);
            }
            #pragma unroll
            for (int mi = 0; mi < 4; ++mi)
                #pragma unroll
                for (int ni = 0; ni < 2; ++ni){
                    ag[mi][ni] = __builtin_amdgcn_mfma_f32_16x16x32_bf16(af[mi], bg[ni], ag[mi][ni], 0,0,0);
                    au[mi][ni] = __builtin_amdgcn_mfma_f32_16x16x32_bf16(af[mi], bu[ni], au[mi][ni], 0,0,0);
                }
        }
        __builtin_amdgcn_s_setprio(0);
        __builtin_amdgcn_s_barrier();
    }
    const int obase = offs[e];
    #pragma unroll
    for (int mi = 0; mi < 4; ++mi)
        #pragma unroll
        for (int ni = 0; ni < 2; ++ni)
            #pragma unroll
            for (int rr = 0; rr < 4; ++rr){
                int slot = bm0 + wr*64 + mi*16 + (l>>4)*4 + rr;
                if (slot < ne){
                    int col = bn0 + wc*32 + ni*16 + (l&15);
                    float g = ag[mi][ni][rr], uu = au[mi][ni][rr];
                    float val = (g/(1.f+__expf(-g)))*uu;
                    inter[(size_t)(obase+slot)*INTER_C + col] = f2b(val);
                }
            }
}

// ============ MoE down: XCD panel-grouped 1-D grid, dbuf gload16, setprio; atomics into out ============
__global__ __launch_bounds__(256) void moe2g3_k(const bf16* __restrict__ inter,
                                                const short* __restrict__ down_t,
                                                float* __restrict__ outp,
                                                const float* __restrict__ wl,
                                                const int* __restrict__ lists,
                                                const int* __restrict__ cnt,
                                                const int* __restrict__ offs){
    const int b = blockIdx.x;
    const int r = b & 7, j = b >> 3;
    const int G = r + ((j >> 5) << 3);
    const int e = G >> 3, bnG = G & 7;
    const int bm0 = (j & 31) * 128;
    const int ne = cnt[e];
    if (bm0 >= ne) return;
    const int bn0 = bnG * 128;
    __shared__ __align__(16) short lA[2][128*64];
    __shared__ __align__(16) short lB[2][128*64];
    const int tid = threadIdx.x;
    const int l = tid & 63, w = tid >> 6, wr = w >> 1, wc = w & 1;
    const int lr = l >> 3, lc8 = (l & 7)*8;
    const int obase = offs[e];
    const short* Db = down_t + (size_t)e*HID_C*INTER_C;
    const short* As = (const short*)inter;
    int rowA[4];
    #pragma unroll
    for (int jj = 0; jj < 4; ++jj){
        int slot = bm0 + w*32 + jj*8 + lr;
        if (slot >= ne) slot = ne - 1;
        rowA[jj] = obase + slot;
    }
    auto STAGE = [&](int buf, int kt){
        #pragma unroll
        for (int jj = 0; jj < 4; ++jj){
            gload16(As + (size_t)rowA[jj]*INTER_C + kt*64 + lc8, &lA[buf][(w*32 + jj*8)*64]);
            int n = w*32 + jj*8 + lr;
            gload16(Db + (size_t)(bn0 + n)*INTER_C + kt*64 + lc8, &lB[buf][(w*32 + jj*8)*64]);
        }
    };
    f32x4 acc[4][4] = {};
    STAGE(0, 0);
    for (int kt = 0; kt < 44; ++kt){
        const int cur = kt & 1;
        if (kt + 1 < 44){
            STAGE(cur ^ 1, kt + 1);
            asm volatile("s_waitcnt vmcnt(8)" ::: "memory");
        } else {
            asm volatile("s_waitcnt vmcnt(0)" ::: "memory");
        }
        __builtin_amdgcn_s_barrier();
        __builtin_amdgcn_sched_barrier(0);
        __builtin_amdgcn_s_setprio(1);
        #pragma unroll
        for (int kk = 0; kk < 64; kk += 32){
            s16x8 af[4], bfr[4];
            #pragma unroll
            for (int mi = 0; mi < 4; ++mi)
                af[mi] = *(const s16x8*)(&lA[cur][(wr*64 + mi*16 + (l&15))*64 + kk + (l>>4)*8]);
            #pragma unroll
            for (int ni = 0; ni < 4; ++ni){
                int n = wc*64 + ni*16 + (l&15);
                int key = n & 7;
                int ch = (kk>>3) + (l>>4);
                bfr[ni] = *(const s16x8*)(&lB[cur][n*64 + ((ch ^ key)<<3)]);
            }
            #pragma unroll
            for (int mi = 0; mi < 4; ++mi)
                #pragma unroll
                for (int ni = 0; ni < 4; ++ni)
                    acc[mi][ni] = __builtin_amdgcn_mfma_f32_16x16x32_bf16(af[mi], bfr[ni], acc[mi][ni], 0,0,0);
        }
        __builtin_amdgcn_s_setprio(0);
        __builtin_amdgcn_s_barrier();
    }
    #pragma unroll
    for (int mi = 0; mi < 4; ++mi)
        #pragma unroll
        for (int ni = 0; ni < 4; ++ni)
            #pragma unroll
            for (int rr = 0; rr < 4; ++rr){
                int slot = bm0 + wr*64 + mi*16 + (l>>4)*4 + rr;
                if (slot < ne){
                    int col = bn0 + wc*64 + ni*16 + (l&15);
                    int tok = lists[e*CAP + slot];
                    float wgt = wl[e*CAP + slot];
                    atomicAdd(&outp[(size_t)tok*HID_C + col], acc[mi][ni][rr]*wgt);
                }
            }
}

__global__ __launch_bounds__(256) void final_k(const float* __restrict__ hres,
                                               float* __restrict__ out){
    const int t = blockIdx.x, c = threadIdx.x*4;
    float4 hv = *(const float4*)(hres + (size_t)t*HID_C + c);
    *(float4*)(out + (size_t)t*HID_C + c) = hv;
}

// ======================= HOST =======================
extern "C" void kernel_launch(void* const* d_in, const int* in_sizes, int n_in,
                              void* d_out, int out_size, void* d_ws, size_t ws_size,
                              hipStream_t stream){
    const float* hidden  = (const float*)d_in[0];
    const float* fcos    = (const float*)d_in[1];
    const float* fsin    = (const float*)d_in[2];
    const float* wq      = (const float*)d_in[3];
    const float* wk      = (const float*)d_in[4];
    const float* wv      = (const float*)d_in[5];
    const float* wo      = (const float*)d_in[6];
    const float* routerw = (const float*)d_in[7];
    const float* gatew   = (const float*)d_in[8];
    const float* upw     = (const float*)d_in[9];
    const float* downw   = (const float*)d_in[10];
    const float* n1w     = (const float*)d_in[11];
    const float* n2w     = (const float*)d_in[12];

    char* p = (char*)d_ws;
    size_t off = 0;
    auto alloc = [&](size_t b)->void*{ void* r = p + off; off = (off + b + 255) & ~(size_t)255; return r; };

    int*   cnt    = (int*)alloc(64);
    float* psum   = (float*)alloc(64);
    int*   offs   = (int*)alloc(64);
    int*   lists  = (int*)alloc((size_t)E_C*CAP*4);
    float* wl     = (float*)alloc((size_t)E_C*CAP*4);
    short* wqkv2  = (short*)alloc((size_t)NQKV*K2C*2);
    short* wo2    = (short*)alloc((size_t)HID_C*K2C*2);
    short* gate_t = (short*)alloc((size_t)E_C*INTER_C*HID_C*2);
    short* up_t   = (short*)alloc((size_t)E_C*INTER_C*HID_C*2);
    short* down_t = (short*)alloc((size_t)E_C*HID_C*INTER_C*2);
    short* h1c    = (short*)alloc((size_t)NTOK*K2C*2);
    float* qkvf   = (float*)alloc((size_t)NTOK*NQKV*4);
    float* hres   = (float*)alloc((size_t)NTOK*HID_C*4);
    bf16*  inter  = (bf16*)alloc((size_t)2*NTOK*INTER_C*2);

    short* oc  = h1c;
    float* h2f = qkvf;
    bf16*  h2b = (bf16*)(qkvf + (size_t)NTOK*HID_C);
    float* outp = (float*)d_out;

    (void)hipMemsetAsync(cnt, 0, 64, stream);
    (void)hipMemsetAsync(psum, 0, 64, stream);

    // prepass transposes (swizzled)
    tsplit2s_k<<<dim3(32,32), 256, 0, stream>>>(wq, wqkv2, 1024, 0);
    tsplit2s_k<<<dim3(8,32),  256, 0, stream>>>(wk, wqkv2, 256, 1024);
    tsplit2s_k<<<dim3(8,32),  256, 0, stream>>>(wv, wqkv2, 256, 1280);
    tsplit2s_k<<<dim3(32,32), 256, 0, stream>>>(wo, wo2, 1024, 0);
    tbf16s_k<<<dim3(88,32,8), 256, 0, stream>>>(gatew, gate_t, 1024, 2816);
    tbf16s_k<<<dim3(88,32,8), 256, 0, stream>>>(upw,   up_t,   1024, 2816);
    tbf16s_k<<<dim3(32,88,8), 256, 0, stream>>>(downw, down_t, 2816, 1024);

    rmsn1c_k<<<NTOK, 256, 0, stream>>>(hidden, n1w, h1c);
    sgemm4_k<false><<<dim3(32,12), 256, 0, stream>>>(h1c, wqkv2, qkvf, nullptr, NQKV);
    rope2_k<<<10240, 256, 0, stream>>>(qkvf, fcos, fsin);
    attn3_k<<<dim3(NTOK/ATILE, 4), 256, 0, stream>>>(qkvf, oc);
    sgemm4_k<true><<<dim3(32,8), 256, 0, stream>>>(oc, wo2, hres, hidden, 1024);
    rmsn2_k<<<NTOK, 256, 0, stream>>>(hres, n2w, h2f, h2b);
    router2_k<<<256, 256, 0, stream>>>(h2f, routerw, lists, wl, cnt, psum);
    finalize_k<<<1, 64, 0, stream>>>(cnt, psum, offs, outp);
    final_k<<<NTOK, 256, 0, stream>>>(hres, outp);          // out = resid+attn (before MoE adds)
    moe1g3_k<<<11264, 256, 0, stream>>>((const short*)h2b, gate_t, up_t, inter, lists, cnt, offs);
    moe2g3_k<<<2048, 256, 0, stream>>>(inter, down_t, outp, wl, lists, cnt, offs);
}

// Round 13
// 684.639 us; speedup vs baseline: 4.7162x; 1.0176x over previous
//
#include <hip/hip_runtime.h>
#include <hip/hip_bf16.h>
#include <math.h>

typedef short s16x8 __attribute__((ext_vector_type(8)));
typedef float f32x4 __attribute__((ext_vector_type(4)));
typedef __hip_bfloat16 bf16;

#define NTOK 4096
#define S_LEN 2048
#define HID_C 1024
#define E_C 8
#define INTER_C 2816
#define WIN_C 64
#define CAP 4096
#define NQKV 1536
#define K2C 2048
#define ATILE 16
#define KR 80
#define OUT0_N ((size_t)NTOK*HID_C)

#define AS1 __attribute__((address_space(1)))
#define AS3 __attribute__((address_space(3)))

static __device__ __forceinline__ void gload16(const void* g, void* l){
    __builtin_amdgcn_global_load_lds((AS1 void*)(g), (AS3 void*)(l), 16, 0, 0);
}

static __device__ __forceinline__ float b2f(bf16 v){ return __bfloat162float(v); }
static __device__ __forceinline__ bf16  f2b(float v){ return __float2bfloat16(v); }
static __device__ __forceinline__ short f2bs(float v){ bf16 h = __float2bfloat16(v); return *reinterpret_cast<short*>(&h); }
struct SplitBF { short hi; short lo; };
static __device__ __forceinline__ SplitBF splitf(float x){
    SplitBF r;
    bf16 bh = __float2bfloat16(x);
    r.hi = *reinterpret_cast<short*>(&bh);
    float rem = x - __bfloat162float(bh);
    bf16 bl = __float2bfloat16(rem);
    r.lo = *reinterpret_cast<short*>(&bl);
    return r;
}

// Swizzle convention: within each 64-short (128B) group of a row, logical
// 8-short chunk c is stored at physical chunk c ^ (row & 7).

// ============ PREPASS: f32 [1024][N] -> combined hi/lo [row_off+n][2048], swizzled ============
__global__ __launch_bounds__(256) void tsplit2s_k(const float* __restrict__ src,
                                                  short* __restrict__ dst,
                                                  int N, int row_off){
    __shared__ float tile[32][33];
    const int n0 = blockIdx.x*32, k0 = blockIdx.y*32;
    const int tx = threadIdx.x & 31, ty = threadIdx.x >> 5;
    #pragma unroll
    for (int i = 0; i < 4; ++i)
        tile[ty + i*8][tx] = src[(size_t)(k0 + ty + i*8)*N + n0 + tx];
    __syncthreads();
    const int g = k0 >> 5;
    const int chH = tx >> 3, chL = 4 | (tx >> 3), off = tx & 7;
    #pragma unroll
    for (int i = 0; i < 4; ++i){
        int nn = ty + i*8;
        SplitBF s = splitf(tile[tx][nn]);
        size_t rowb = (size_t)(row_off + n0 + nn)*K2C + g*64;
        dst[rowb + ((chH ^ ty)<<3) + off] = s.hi;
        dst[rowb + ((chL ^ ty)<<3) + off] = s.lo;
    }
}

// f32 [e][K][N] -> bf16 [e][N][K], swizzled
__global__ __launch_bounds__(256) void tbf16s_k(const float* __restrict__ src0,
                                                short* __restrict__ dst0, int K, int N){
    const int e = blockIdx.z;
    const float* src = src0 + (size_t)e*K*N;
    short* dst = dst0 + (size_t)e*N*K;
    __shared__ float tile[32][33];
    const int n0 = blockIdx.x*32, k0 = blockIdx.y*32;
    const int tx = threadIdx.x & 31, ty = threadIdx.x >> 5;
    #pragma unroll
    for (int i = 0; i < 4; ++i)
        tile[ty + i*8][tx] = src[(size_t)(k0 + ty + i*8)*N + n0 + tx];
    __syncthreads();
    const int grp  = k0 >> 6;
    const int half = (k0 & 32) >> 3;
    const int ch   = half + (tx >> 3), off = tx & 7;
    #pragma unroll
    for (int i = 0; i < 4; ++i){
        int nn = ty + i*8;
        dst[(size_t)(n0 + nn)*K + grp*64 + ((ch ^ ty)<<3) + off] = f2bs(tile[tx][nn]);
    }
}

// ================= RMSNorm: f32 in -> combined hi/lo out (swizzled) =================
__global__ __launch_bounds__(256) void rmsn1c_k(const float* __restrict__ xin,
                                                const float* __restrict__ w,
                                                short* __restrict__ oc){
    const int t = blockIdx.x, tid = threadIdx.x;
    float4 v = *(const float4*)(xin + (size_t)t*HID_C + tid*4);
    float x[4] = {v.x, v.y, v.z, v.w};
    float s = x[0]*x[0]+x[1]*x[1]+x[2]*x[2]+x[3]*x[3];
    #pragma unroll
    for (int off=32; off; off>>=1) s += __shfl_xor(s, off);
    __shared__ float red[4];
    if ((tid&63)==0) red[tid>>6] = s;
    __syncthreads();
    float tot = red[0]+red[1]+red[2]+red[3];
    float sc = rsqrtf(tot*(1.0f/HID_C) + 1e-8f);
    float4 wv = *(const float4*)(w + tid*4);
    float o[4] = { x[0]*sc*wv.x, x[1]*sc*wv.y, x[2]*sc*wv.z, x[3]*sc*wv.w };
    __align__(8) short th[4], tl[4];
    #pragma unroll
    for (int i=0;i<4;++i){ SplitBF sp = splitf(o[i]); th[i]=sp.hi; tl[i]=sp.lo; }
    const int g = tid>>3, q = tid&7;
    const int ch = q>>1, sub = (q&1)*4, key = t&7;
    short* rowp = oc + (size_t)t*K2C + g*64;
    *(uint2*)(rowp + ((ch ^ key)<<3) + sub)      = *(uint2*)th;
    *(uint2*)(rowp + (((4|ch) ^ key)<<3) + sub)  = *(uint2*)tl;
}

// norm2: f32 in -> f32 out + bf16 out
__global__ __launch_bounds__(256) void rmsn2_k(const float* __restrict__ xin,
                                               const float* __restrict__ w,
                                               float* __restrict__ outf, bf16* __restrict__ outb){
    const int t = blockIdx.x, tid = threadIdx.x;
    float4 v = *(const float4*)(xin + (size_t)t*HID_C + tid*4);
    float x[4] = {v.x, v.y, v.z, v.w};
    float s = x[0]*x[0]+x[1]*x[1]+x[2]*x[2]+x[3]*x[3];
    #pragma unroll
    for (int off=32; off; off>>=1) s += __shfl_xor(s, off);
    __shared__ float red[4];
    if ((tid&63)==0) red[tid>>6] = s;
    __syncthreads();
    float tot = red[0]+red[1]+red[2]+red[3];
    float sc = rsqrtf(tot*(1.0f/HID_C) + 1e-8f);
    float4 wv = *(const float4*)(w + tid*4);
    float o[4] = { x[0]*sc*wv.x, x[1]*sc*wv.y, x[2]*sc*wv.z, x[3]*sc*wv.w };
    *(float4*)(outf + (size_t)t*HID_C + tid*4) = make_float4(o[0],o[1],o[2],o[3]);
    __align__(8) bf16 tmp[4] = { f2b(o[0]), f2b(o[1]), f2b(o[2]), f2b(o[3]) };
    *(uint2*)(outb + (size_t)t*HID_C + tid*4) = *(uint2*)tmp;
}

// ============ split GEMM: dbuf gload16 + counted vmcnt + swizzled reads ============
template<bool RESID>
__global__ __launch_bounds__(256) void sgemm4_k(const short* __restrict__ A2,
                                                const short* __restrict__ B2,
                                                float* __restrict__ C, const float* __restrict__ resid,
                                                int N){
    __shared__ __align__(16) short lA[2][128*64];
    __shared__ __align__(16) short lB[2][128*64];
    const int tid = threadIdx.x;
    const int bm0 = blockIdx.x*128, bn0 = blockIdx.y*128;
    const int l = tid & 63, w = tid >> 6, wr = w >> 1, wc = w & 1;
    const int lr = l >> 3, lc8 = (l & 7)*8;
    f32x4 acc[4][4] = {};
    auto STAGE = [&](int buf, int kt){
        #pragma unroll
        for (int j = 0; j < 4; ++j){
            int row = w*32 + j*8 + lr;
            gload16(A2 + (size_t)(bm0 + row)*K2C + kt*64 + lc8, &lA[buf][(w*32 + j*8)*64]);
            gload16(B2 + (size_t)(bn0 + row)*K2C + kt*64 + lc8, &lB[buf][(w*32 + j*8)*64]);
        }
    };
    STAGE(0, 0);
    for (int kt = 0; kt < 32; ++kt){
        const int cur = kt & 1;
        if (kt + 1 < 32){
            STAGE(cur ^ 1, kt + 1);
            asm volatile("s_waitcnt vmcnt(8)" ::: "memory");
        } else {
            asm volatile("s_waitcnt vmcnt(0)" ::: "memory");
        }
        __builtin_amdgcn_s_barrier();
        __builtin_amdgcn_sched_barrier(0);
        s16x8 ah[4], al[4], bh[4], bl[4];
        #pragma unroll
        for (int mi = 0; mi < 4; ++mi){
            int r = wr*64 + mi*16 + (l&15);
            int key = r & 7;
            ah[mi] = *(const s16x8*)(&lA[cur][r*64 + (((l>>4) ^ key)<<3)]);
            al[mi] = *(const s16x8*)(&lA[cur][r*64 + (((4|(l>>4)) ^ key)<<3)]);
        }
        #pragma unroll
        for (int ni = 0; ni < 4; ++ni){
            int n = wc*64 + ni*16 + (l&15);
            int key = n & 7;
            bh[ni] = *(const s16x8*)(&lB[cur][n*64 + (((l>>4) ^ key)<<3)]);
            bl[ni] = *(const s16x8*)(&lB[cur][n*64 + (((4|(l>>4)) ^ key)<<3)]);
        }
        #pragma unroll
        for (int mi = 0; mi < 4; ++mi)
            #pragma unroll
            for (int ni = 0; ni < 4; ++ni){
                acc[mi][ni] = __builtin_amdgcn_mfma_f32_16x16x32_bf16(ah[mi], bh[ni], acc[mi][ni], 0,0,0);
                acc[mi][ni] = __builtin_amdgcn_mfma_f32_16x16x32_bf16(ah[mi], bl[ni], acc[mi][ni], 0,0,0);
                acc[mi][ni] = __builtin_amdgcn_mfma_f32_16x16x32_bf16(al[mi], bh[ni], acc[mi][ni], 0,0,0);
            }
        __builtin_amdgcn_s_barrier();
    }
    #pragma unroll
    for (int mi = 0; mi < 4; ++mi)
        #pragma unroll
        for (int ni = 0; ni < 4; ++ni)
            #pragma unroll
            for (int rr = 0; rr < 4; ++rr){
                int row = bm0 + wr*64 + mi*16 + (l>>4)*4 + rr;
                int col = bn0 + wc*64 + ni*16 + (l&15);
                float vv = acc[mi][ni][rr];
                if (RESID) vv += resid[(size_t)row*N + col];
                C[(size_t)row*N + col] = vv;
            }
}

// ================ RoPE on packed qkv f32 [tok][1536] ================
__global__ __launch_bounds__(256) void rope2_k(float* __restrict__ qkv,
                                               const float* __restrict__ cosb, const float* __restrict__ sinb){
    int idx = blockIdx.x*256 + threadIdx.x;
    int t = idx / 640;
    int r = idx - t*640;
    int hs = r >> 5, tp = r & 31;
    int s = t & (S_LEN-1);
    float c  = cosb[s*32+tp];
    float sn = sinb[s*32+tp];
    float* base;
    if (hs < 16) base = qkv + (size_t)t*NQKV + hs*64 + 2*tp;
    else         base = qkv + (size_t)t*NQKV + 1024 + (hs-16)*64 + 2*tp;
    float2 v = *(float2*)base;
    *(float2*)base = make_float2(v.x*c - v.y*sn, v.x*sn + v.y*c);
}

// ======== tiled shared-KV attention: block=(16-token tile, kv group), 4 waves=4 heads ========
__global__ __launch_bounds__(256) void attn3_k(const float* __restrict__ qkv,
                                               short* __restrict__ oc){
    const int t0 = blockIdx.x * ATILE;
    const int hk = blockIdx.y;
    const int sq0 = t0 & (S_LEN-1);
    const int tokbase = t0 - sq0;
    const int tid = threadIdx.x, l = tid & 63, w = tid >> 6;
    __shared__ float Kl[KR*65];
    __shared__ float Vl[KR*65];
    __shared__ float qsh[4][64];
    __shared__ float ps[4][64];
    for (int rr = tid >> 4; rr < KR; rr += 16){
        int c4 = (tid & 15)*4;
        int kp = sq0 - 64 + rr;
        float4 kv = make_float4(0,0,0,0), vv = kv;
        if (kp >= 0){
            const float* base = qkv + (size_t)(tokbase + kp)*NQKV + 1024 + hk*64 + c4;
            kv = *(const float4*)base;
            vv = *(const float4*)(base + 256);
        }
        Kl[rr*65 + c4+0]=kv.x; Kl[rr*65 + c4+1]=kv.y; Kl[rr*65 + c4+2]=kv.z; Kl[rr*65 + c4+3]=kv.w;
        Vl[rr*65 + c4+0]=vv.x; Vl[rr*65 + c4+1]=vv.y; Vl[rr*65 + c4+2]=vv.z; Vl[rr*65 + c4+3]=vv.w;
    }
    __syncthreads();
    const int h = hk*4 + w;
    for (int i = 0; i < ATILE; ++i){
        const int t = t0 + i, sq = sq0 + i;
        qsh[w][l] = qkv[(size_t)t*NQKV + h*64 + l];
        float d = 0.f;
        const float* krow = &Kl[(i + l)*65];
        #pragma unroll
        for (int c = 0; c < 64; ++c) d += qsh[w][c] * krow[c];
        const bool valid = (sq - 64 + l) >= 0;
        float sc = valid ? d*0.125f : -1e30f;
        float part = qsh[w][l] * Kl[(i + 64)*65 + l];
        #pragma unroll
        for (int off = 32; off; off >>= 1) part += __shfl_xor(part, off);
        float dg = part*0.125f;
        float m = sc;
        #pragma unroll
        for (int off = 32; off; off >>= 1) m = fmaxf(m, __shfl_xor(m, off));
        m = fmaxf(m, dg);
        float e = __expf(sc - m);
        float ssum = e;
        #pragma unroll
        for (int off = 32; off; off >>= 1) ssum += __shfl_xor(ssum, off);
        float edg = __expf(dg - m);
        ssum += edg;
        float inv = 1.f / ssum;
        ps[w][l] = e * inv;
        float pdg = edg * inv;
        float acc = 0.f;
        #pragma unroll 8
        for (int jj = 0; jj < 64; ++jj) acc += ps[w][jj] * Vl[(i + jj)*65 + l];
        acc += pdg * Vl[(i + 64)*65 + l];
        SplitBF sp = splitf(acc);
        const int k = h*64 + l;
        const int g = k>>5, ch = (k&31)>>3, off2 = k&7, key = t&7;
        short* rowp = oc + (size_t)t*K2C + g*64;
        rowp[((ch ^ key)<<3) + off2]     = sp.hi;
        rowp[(((4|ch) ^ key)<<3) + off2] = sp.lo;
    }
}

// ================= router v2: 16 tokens/block, LDS-aggregated atomics =================
__global__ __launch_bounds__(256) void router2_k(const float* __restrict__ h2f, const float* __restrict__ rw,
                                                 int* __restrict__ lists, float* __restrict__ wl,
                                                 int* __restrict__ cnt, float* __restrict__ psum){
    const int tid = threadIdx.x, l = tid & 63, w = tid >> 6;
    __shared__ int   sE0[16], sE1[16], sSlot0[16], sSlot1[16];
    __shared__ float sW0[16], sW1[16];
    __shared__ float sPsum[8];
    __shared__ int   sCnt[8], sBase[8];
    if (tid < 8){ sPsum[tid] = 0.f; sCnt[tid] = 0; }
    __syncthreads();
    #pragma unroll
    for (int i = 0; i < 4; ++i){
        const int li = w*4 + i;
        const int t = blockIdx.x*16 + li;
        float lg[8] = {0,0,0,0,0,0,0,0};
        for (int c = 0; c < 16; ++c){
            int kidx = l + c*64;
            float x = h2f[(size_t)t*HID_C + kidx];
            float4 w0 = *(const float4*)(rw + (size_t)kidx*8);
            float4 w1 = *(const float4*)(rw + (size_t)kidx*8 + 4);
            lg[0] += x*w0.x; lg[1] += x*w0.y; lg[2] += x*w0.z; lg[3] += x*w0.w;
            lg[4] += x*w1.x; lg[5] += x*w1.y; lg[6] += x*w1.z; lg[7] += x*w1.w;
        }
        #pragma unroll
        for (int e = 0; e < 8; ++e)
            #pragma unroll
            for (int off=32; off; off>>=1) lg[e] += __shfl_xor(lg[e], off);
        if (l == 0){
            float m = lg[0];
            #pragma unroll
            for (int e = 1; e < 8; ++e) m = fmaxf(m, lg[e]);
            float p[8]; float s = 0.f;
            #pragma unroll
            for (int e = 0; e < 8; ++e){ p[e] = __expf(lg[e]-m); s += p[e]; }
            float invs = 1.f/s;
            #pragma unroll
            for (int e = 0; e < 8; ++e){ p[e] *= invs; atomicAdd(&sPsum[e], p[e]); }
            float best = -1e30f, sec = -1e30f; int bi = 0, si = 0;
            #pragma unroll
            for (int e = 0; e < 8; ++e){
                float pv = p[e];
                if (pv > best){ sec = best; si = bi; best = pv; bi = e; }
                else if (pv > sec){ sec = pv; si = e; }
            }
            float wsum = best + sec + 1e-9f;
            sE0[li] = bi; sE1[li] = si;
            sW0[li] = best/wsum; sW1[li] = sec/wsum;
            sSlot0[li] = atomicAdd(&sCnt[bi], 1);
            sSlot1[li] = atomicAdd(&sCnt[si], 1);
        }
    }
    __syncthreads();
    if (tid < 8){
        sBase[tid] = atomicAdd(&cnt[tid], sCnt[tid]);
        atomicAdd(&psum[tid], sPsum[tid]);
    }
    __syncthreads();
    if (tid < 16){
        int t = blockIdx.x*16 + tid;
        int e0 = sE0[tid], e1 = sE1[tid];
        int s0 = sBase[e0] + sSlot0[tid];
        int s1 = sBase[e1] + sSlot1[tid];
        lists[e0*CAP + s0] = t; wl[e0*CAP + s0] = sW0[tid];
        lists[e1*CAP + s1] = t; wl[e1*CAP + s1] = sW1[tid];
    }
}

__global__ void finalize_k(const int* __restrict__ cnt, const float* __restrict__ psum,
                           int* __restrict__ offs, float* __restrict__ out){
    if (threadIdx.x == 0 && blockIdx.x == 0){
        int o = 0; float loss = 0.f;
        for (int e = 0; e < 8; ++e){
            offs[e] = o; o += cnt[e];
            loss += (psum[e]*(1.0f/NTOK)) * ((float)cnt[e]*(1.0f/NTOK));
        }
        offs[8] = o;
        out[OUT0_N] = loss * (float)E_C * 0.01f;
    }
}

// ============ MoE gate/up: XCD panel-grouped, dbuf gload16, A-source swizzle, setprio ============
__global__ __launch_bounds__(256) void moe1g3_k(const short* __restrict__ h2b,
                                                const short* __restrict__ gate_t,
                                                const short* __restrict__ up_t,
                                                bf16* __restrict__ inter,
                                                const int* __restrict__ lists,
                                                const int* __restrict__ cnt,
                                                const int* __restrict__ offs){
    const int b = blockIdx.x;
    const int r = b & 7, j = b >> 3;
    const int G = r + ((j >> 5) << 3);
    const int e = G / 44, bnG = G % 44;
    const int bm0 = (j & 31) * 128;
    const int ne = cnt[e];
    if (bm0 >= ne) return;
    const int bn0 = bnG * 64;
    __shared__ __align__(16) short lA[2][128*64];
    __shared__ __align__(16) short lG[2][64*64];
    __shared__ __align__(16) short lU[2][64*64];
    const int tid = threadIdx.x;
    const int l = tid & 63, w = tid >> 6, wr = w >> 1, wc = w & 1;
    const int lr = l >> 3, lc8 = (l & 7)*8;
    const int lcs = (((l & 7) ^ lr) << 3);          // A-source swizzled chunk offset
    const short* Gb = gate_t + (size_t)e*INTER_C*HID_C;
    const short* Ub = up_t   + (size_t)e*INTER_C*HID_C;
    int tokA[4];
    #pragma unroll
    for (int jj = 0; jj < 4; ++jj){
        int slot = bm0 + w*32 + jj*8 + lr;
        if (slot >= ne) slot = ne - 1;
        tokA[jj] = lists[e*CAP + slot];
    }
    auto STAGE = [&](int buf, int kt){
        #pragma unroll
        for (int jj = 0; jj < 4; ++jj)
            gload16(h2b + (size_t)tokA[jj]*HID_C + kt*64 + lcs, &lA[buf][(w*32 + jj*8)*64]);
        #pragma unroll
        for (int jj = 0; jj < 2; ++jj){
            int n = w*16 + jj*8 + lr;
            gload16(Gb + (size_t)(bn0 + n)*HID_C + kt*64 + lc8, &lG[buf][(w*16 + jj*8)*64]);
            gload16(Ub + (size_t)(bn0 + n)*HID_C + kt*64 + lc8, &lU[buf][(w*16 + jj*8)*64]);
        }
    };
    f32x4 ag[4][2] = {}; f32x4 au[4][2] = {};
    STAGE(0, 0);
    for (int kt = 0; kt < 16; ++kt){
        const int cur = kt & 1;
        if (kt + 1 < 16){
            STAGE(cur ^ 1, kt + 1);
            asm volatile("s_waitcnt vmcnt(8)" ::: "memory");
        } else {
            asm volatile("s_waitcnt vmcnt(0)" ::: "memory");
        }
        __builtin_amdgcn_s_barrier();
        __builtin_amdgcn_sched_barrier(0);
        __builtin_amdgcn_s_setprio(1);
        #pragma unroll
        for (int kk = 0; kk < 64; kk += 32){
            s16x8 af[4], bg[2], bu[2];
            #pragma unroll
            for (int mi = 0; mi < 4; ++mi){
                int ra = wr*64 + mi*16 + (l&15);
                int keyA = ra & 7;
                int chA = (kk>>3) + (l>>4);
                af[mi] = *(const s16x8*)(&lA[cur][ra*64 + ((chA ^ keyA)<<3)]);
            }
            #pragma unroll
            for (int ni = 0; ni < 2; ++ni){
                int n = wc*32 + ni*16 + (l&15);
                int key = n & 7;
                int ch = (kk>>3) + (l>>4);
                bg[ni] = *(const s16x8*)(&lG[cur][n*64 + ((ch ^ key)<<3)]);
                bu[ni] = *(const s16x8*)(&lU[cur][n*64 + ((ch ^ key)<<3)]);
            }
            #pragma unroll
            for (int mi = 0; mi < 4; ++mi)
                #pragma unroll
                for (int ni = 0; ni < 2; ++ni){
                    ag[mi][ni] = __builtin_amdgcn_mfma_f32_16x16x32_bf16(af[mi], bg[ni], ag[mi][ni], 0,0,0);
                    au[mi][ni] = __builtin_amdgcn_mfma_f32_16x16x32_bf16(af[mi], bu[ni], au[mi][ni], 0,0,0);
                }
        }
        __builtin_amdgcn_s_setprio(0);
        __builtin_amdgcn_s_barrier();
    }
    const int obase = offs[e];
    #pragma unroll
    for (int mi = 0; mi < 4; ++mi)
        #pragma unroll
        for (int ni = 0; ni < 2; ++ni)
            #pragma unroll
            for (int rr = 0; rr < 4; ++rr){
                int slot = bm0 + wr*64 + mi*16 + (l>>4)*4 + rr;
                if (slot < ne){
                    int col = bn0 + wc*32 + ni*16 + (l&15);
                    float g = ag[mi][ni][rr], uu = au[mi][ni][rr];
                    float val = (g/(1.f+__expf(-g)))*uu;
                    inter[(size_t)(obase+slot)*INTER_C + col] = f2b(val);
                }
            }
}

// ============ MoE down: XCD panel-grouped, dbuf gload16, A-source swizzle, setprio; atomics into out ============
__global__ __launch_bounds__(256) void moe2g3_k(const bf16* __restrict__ inter,
                                                const short* __restrict__ down_t,
                                                float* __restrict__ outp,
                                                const float* __restrict__ wl,
                                                const int* __restrict__ lists,
                                                const int* __restrict__ cnt,
                                                const int* __restrict__ offs){
    const int b = blockIdx.x;
    const int r = b & 7, j = b >> 3;
    const int G = r + ((j >> 5) << 3);
    const int e = G >> 3, bnG = G & 7;
    const int bm0 = (j & 31) * 128;
    const int ne = cnt[e];
    if (bm0 >= ne) return;
    const int bn0 = bnG * 128;
    __shared__ __align__(16) short lA[2][128*64];
    __shared__ __align__(16) short lB[2][128*64];
    const int tid = threadIdx.x;
    const int l = tid & 63, w = tid >> 6, wr = w >> 1, wc = w & 1;
    const int lr = l >> 3, lc8 = (l & 7)*8;
    const int lcs = (((l & 7) ^ lr) << 3);          // A-source swizzled chunk offset
    const int obase = offs[e];
    const short* Db = down_t + (size_t)e*HID_C*INTER_C;
    const short* As = (const short*)inter;
    int rowA[4];
    #pragma unroll
    for (int jj = 0; jj < 4; ++jj){
        int slot = bm0 + w*32 + jj*8 + lr;
        if (slot >= ne) slot = ne - 1;
        rowA[jj] = obase + slot;
    }
    auto STAGE = [&](int buf, int kt){
        #pragma unroll
        for (int jj = 0; jj < 4; ++jj){
            gload16(As + (size_t)rowA[jj]*INTER_C + kt*64 + lcs, &lA[buf][(w*32 + jj*8)*64]);
            int n = w*32 + jj*8 + lr;
            gload16(Db + (size_t)(bn0 + n)*INTER_C + kt*64 + lc8, &lB[buf][(w*32 + jj*8)*64]);
        }
    };
    f32x4 acc[4][4] = {};
    STAGE(0, 0);
    for (int kt = 0; kt < 44; ++kt){
        const int cur = kt & 1;
        if (kt + 1 < 44){
            STAGE(cur ^ 1, kt + 1);
            asm volatile("s_waitcnt vmcnt(8)" ::: "memory");
        } else {
            asm volatile("s_waitcnt vmcnt(0)" ::: "memory");
        }
        __builtin_amdgcn_s_barrier();
        __builtin_amdgcn_sched_barrier(0);
        __builtin_amdgcn_s_setprio(1);
        #pragma unroll
        for (int kk = 0; kk < 64; kk += 32){
            s16x8 af[4], bfr[4];
            #pragma unroll
            for (int mi = 0; mi < 4; ++mi){
                int ra = wr*64 + mi*16 + (l&15);
                int keyA = ra & 7;
                int chA = (kk>>3) + (l>>4);
                af[mi] = *(const s16x8*)(&lA[cur][ra*64 + ((chA ^ keyA)<<3)]);
            }
            #pragma unroll
            for (int ni = 0; ni < 4; ++ni){
                int n = wc*64 + ni*16 + (l&15);
                int key = n & 7;
                int ch = (kk>>3) + (l>>4);
                bfr[ni] = *(const s16x8*)(&lB[cur][n*64 + ((ch ^ key)<<3)]);
            }
            #pragma unroll
            for (int mi = 0; mi < 4; ++mi)
                #pragma unroll
                for (int ni = 0; ni < 4; ++ni)
                    acc[mi][ni] = __builtin_amdgcn_mfma_f32_16x16x32_bf16(af[mi], bfr[ni], acc[mi][ni], 0,0,0);
        }
        __builtin_amdgcn_s_setprio(0);
        __builtin_amdgcn_s_barrier();
    }
    #pragma unroll
    for (int mi = 0; mi < 4; ++mi)
        #pragma unroll
        for (int ni = 0; ni < 4; ++ni)
            #pragma unroll
            for (int rr = 0; rr < 4; ++rr){
                int slot = bm0 + wr*64 + mi*16 + (l>>4)*4 + rr;
                if (slot < ne){
                    int col = bn0 + wc*64 + ni*16 + (l&15);
                    int tok = lists[e*CAP + slot];
                    float wgt = wl[e*CAP + slot];
                    atomicAdd(&outp[(size_t)tok*HID_C + col], acc[mi][ni][rr]*wgt);
                }
            }
}

__global__ __launch_bounds__(256) void final_k(const float* __restrict__ hres,
                                               float* __restrict__ out){
    const int t = blockIdx.x, c = threadIdx.x*4;
    float4 hv = *(const float4*)(hres + (size_t)t*HID_C + c);
    *(float4*)(out + (size_t)t*HID_C + c) = hv;
}

// ======================= HOST =======================
extern "C" void kernel_launch(void* const* d_in, const int* in_sizes, int n_in,
                              void* d_out, int out_size, void* d_ws, size_t ws_size,
                              hipStream_t stream){
    const float* hidden  = (const float*)d_in[0];
    const float* fcos    = (const float*)d_in[1];
    const float* fsin    = (const float*)d_in[2];
    const float* wq      = (const float*)d_in[3];
    const float* wk      = (const float*)d_in[4];
    const float* wv      = (const float*)d_in[5];
    const float* wo      = (const float*)d_in[6];
    const float* routerw = (const float*)d_in[7];
    const float* gatew   = (const float*)d_in[8];
    const float* upw     = (const float*)d_in[9];
    const float* downw   = (const float*)d_in[10];
    const float* n1w     = (const float*)d_in[11];
    const float* n2w     = (const float*)d_in[12];

    char* p = (char*)d_ws;
    size_t off = 0;
    auto alloc = [&](size_t b)->void*{ void* r = p + off; off = (off + b + 255) & ~(size_t)255; return r; };

    int*   cnt    = (int*)alloc(64);
    float* psum   = (float*)alloc(64);
    int*   offs   = (int*)alloc(64);
    int*   lists  = (int*)alloc((size_t)E_C*CAP*4);
    float* wl     = (float*)alloc((size_t)E_C*CAP*4);
    short* wqkv2  = (short*)alloc((size_t)NQKV*K2C*2);
    short* wo2    = (short*)alloc((size_t)HID_C*K2C*2);
    short* gate_t = (short*)alloc((size_t)E_C*INTER_C*HID_C*2);
    short* up_t   = (short*)alloc((size_t)E_C*INTER_C*HID_C*2);
    short* down_t = (short*)alloc((size_t)E_C*HID_C*INTER_C*2);
    short* h1c    = (short*)alloc((size_t)NTOK*K2C*2);
    float* qkvf   = (float*)alloc((size_t)NTOK*NQKV*4);
    float* hres   = (float*)alloc((size_t)NTOK*HID_C*4);
    bf16*  inter  = (bf16*)alloc((size_t)2*NTOK*INTER_C*2);

    short* oc  = h1c;
    float* h2f = qkvf;
    bf16*  h2b = (bf16*)(qkvf + (size_t)NTOK*HID_C);
    float* outp = (float*)d_out;

    (void)hipMemsetAsync(cnt, 0, 64, stream);
    (void)hipMemsetAsync(psum, 0, 64, stream);

    // prepass transposes (swizzled)
    tsplit2s_k<<<dim3(32,32), 256, 0, stream>>>(wq, wqkv2, 1024, 0);
    tsplit2s_k<<<dim3(8,32),  256, 0, stream>>>(wk, wqkv2, 256, 1024);
    tsplit2s_k<<<dim3(8,32),  256, 0, stream>>>(wv, wqkv2, 256, 1280);
    tsplit2s_k<<<dim3(32,32), 256, 0, stream>>>(wo, wo2, 1024, 0);
    tbf16s_k<<<dim3(88,32,8), 256, 0, stream>>>(gatew, gate_t, 1024, 2816);
    tbf16s_k<<<dim3(88,32,8), 256, 0, stream>>>(upw,   up_t,   1024, 2816);
    tbf16s_k<<<dim3(32,88,8), 256, 0, stream>>>(downw, down_t, 2816, 1024);

    rmsn1c_k<<<NTOK, 256, 0, stream>>>(hidden, n1w, h1c);
    sgemm4_k<false><<<dim3(32,12), 256, 0, stream>>>(h1c, wqkv2, qkvf, nullptr, NQKV);
    rope2_k<<<10240, 256, 0, stream>>>(qkvf, fcos, fsin);
    attn3_k<<<dim3(NTOK/ATILE, 4), 256, 0, stream>>>(qkvf, oc);
    sgemm4_k<true><<<dim3(32,8), 256, 0, stream>>>(oc, wo2, hres, hidden, 1024);
    rmsn2_k<<<NTOK, 256, 0, stream>>>(hres, n2w, h2f, h2b);
    router2_k<<<256, 256, 0, stream>>>(h2f, routerw, lists, wl, cnt, psum);
    finalize_k<<<1, 64, 0, stream>>>(cnt, psum, offs, outp);
    final_k<<<NTOK, 256, 0, stream>>>(hres, outp);
    moe1g3_k<<<11264, 256, 0, stream>>>((const short*)h2b, gate_t, up_t, inter, lists, cnt, offs);
    moe2g3_k<<<2048, 256, 0, stream>>>(inter, down_t, outp, wl, lists, cnt, offs);
}